// Round 2
// baseline (6471.347 us; speedup 1.0000x reference)
//
#include <hip/hip_runtime.h>
#include <hip/hip_bf16.h>
#include <math.h>

#define NB   4
#define NC   32
#define SVT  262144      // 64^3
#define VT   4096        // 64*64
#define NLAY 4
#define TWOPI_64 0.09817477042468103f

__device__ __forceinline__ float gelu_f(float x){
    return 0.5f * x * (1.0f + erff(x * 0.70710678118654752f));
}

#define TWIDDLE_INIT(ctab, stab)                                     \
    if (threadIdx.x < 64){                                           \
        float sn, cs;                                                \
        sincosf((float)threadIdx.x * TWOPI_64, &sn, &cs);            \
        ctab[threadIdx.x] = cs; stab[threadIdx.x] = sn;              \
    }

// ---------------- lift: x = z @ lift_w + lift_b, layout [B,C,S,V,T] -------
__global__ __launch_bounds__(256) void k_lift(
    const float* __restrict__ coords, const float* __restrict__ params,
    const float* __restrict__ lw, const float* __restrict__ lb,
    float* __restrict__ x)
{
    size_t g = (size_t)blockIdx.x * 256 + threadIdx.x;   // 0..1048575
    int b = (int)(g >> 18);
    size_t p = g & (size_t)(SVT - 1);
    float z[9];
    z[0] = coords[g*3+0]; z[1] = coords[g*3+1]; z[2] = coords[g*3+2];
    #pragma unroll
    for (int j = 0; j < 6; ++j) z[3+j] = params[b*6+j];
    #pragma unroll
    for (int c = 0; c < 32; ++c){
        float acc = lb[c];
        #pragma unroll
        for (int j = 0; j < 9; ++j) acc += z[j] * lw[j*32 + c];
        x[(size_t)(b*32 + c) * SVT + p] = acc;
    }
}

// ------- fused forward DFT over t then v: x[bc][s][v][t] -> X2[bc][kz][ky][s]
__global__ __launch_bounds__(256) void k_fwdTV(
    const float* __restrict__ x, float2* __restrict__ X2)
{
    __shared__ float xin[64][65];
    __shared__ float are[12][65], aim[12][65];
    __shared__ float ctab[64], stab[64];
    int tid = threadIdx.x;
    int bc = blockIdx.x >> 6;
    int s  = blockIdx.x & 63;
    TWIDDLE_INIT(ctab, stab)
    const float* src = x + (size_t)bc * SVT + (size_t)s * VT;
    for (int i = tid; i < 4096; i += 256)
        xin[i >> 6][i & 63] = src[i];
    __syncthreads();
    // stage 1: DFT over t -> a[kz][v]
    #pragma unroll
    for (int j = 0; j < 3; ++j){
        int task = tid + j * 256;        // < 768
        int v = task & 63, kz = task >> 6;
        float re = 0.f, im = 0.f;
        for (int t = 0; t < 64; ++t){
            float xv = xin[v][t];
            int m = (kz * t) & 63;
            re += xv * ctab[m];
            im -= xv * stab[m];
        }
        are[kz][v] = re; aim[kz][v] = im;
    }
    __syncthreads();
    // stage 2: DFT over v -> X2[bc][kz][ky][s]
    for (int task = tid; task < 288; task += 256){
        int kz = task % 12;
        int ky = task / 12;
        int kya = (ky < 12) ? ky : ky + 40;
        float re = 0.f, im = 0.f;
        for (int v = 0; v < 64; ++v){
            int m = (kya * v) & 63;
            float cw = ctab[m], sw = stab[m];
            float ar = are[kz][v], ai = aim[kz][v];
            re += ar * cw + ai * sw;
            im += ai * cw - ar * sw;
        }
        X2[((size_t)(bc*12 + kz) * 24 + ky) * 64 + s] = make_float2(re, im);
    }
}

// ---------------- forward DFT over s: X2[bc][kz][ky][s] -> X3[bc][kx][ky][kz]
__global__ __launch_bounds__(256) void k_fwdS(
    const float2* __restrict__ X2, float2* __restrict__ X3)
{
    __shared__ float2 cin[32][65];
    __shared__ float ctab[64], stab[64];
    int tid = threadIdx.x;
    TWIDDLE_INIT(ctab, stab)
    int rbase = blockIdx.x * 32;   // rows (bc,kz,ky), 36864 total
    for (int i = tid; i < 2048; i += 256){
        int row = i >> 6, s = i & 63;
        cin[row][s] = X2[(size_t)(rbase + row) * 64 + s];
    }
    __syncthreads();
    int row = tid & 31;
    int r = rbase + row;
    int kxg = tid >> 5;       // 0..7 -> 3 kx each
    int kxs[3];
    #pragma unroll
    for (int j = 0; j < 3; ++j){ int kxi = kxg*3 + j; kxs[j] = (kxi < 12) ? kxi : kxi + 40; }
    float re[3] = {0,0,0}, im[3] = {0,0,0};
    for (int s = 0; s < 64; ++s){
        float2 cv = cin[row][s];
        #pragma unroll
        for (int j = 0; j < 3; ++j){
            int m = (kxs[j] * s) & 63;
            float cw = ctab[m], sw = stab[m];
            re[j] += cv.x * cw + cv.y * sw;
            im[j] += cv.y * cw - cv.x * sw;
        }
    }
    int bc = r / 288; int kz = (r / 24) % 12; int ky = r % 24;
    #pragma unroll
    for (int j = 0; j < 3; ++j){
        int kxi = kxg*3 + j;
        X3[(size_t)bc * 6912 + (size_t)kxi * 288 + ky * 12 + kz] = make_float2(re[j], im[j]);
    }
}

// ---------------- per-mode channel mixing: Y[b,o,mode] = sum_i X3[b,i,mode]*W
__global__ __launch_bounds__(256) void k_modemix(
    const float2* __restrict__ X3,
    const float* __restrict__ w1, const float* __restrict__ w2,
    const float* __restrict__ w3, const float* __restrict__ w4,
    int layer, float2* __restrict__ Y)
{
    int mode = blockIdx.x * 256 + threadIdx.x;   // 0..6911
    int bo = blockIdx.y;
    int b = bo >> 5, o = bo & 31;
    int kx = mode / 288;
    int ky = (mode / 12) % 24;
    int kz = mode % 12;
    const float* w; int m1, m2;
    if (kx < 12){ m1 = kx;      if (ky < 12){ w = w1; m2 = ky; } else { w = w3; m2 = ky - 12; } }
    else        { m1 = kx - 12; if (ky < 12){ w = w2; m2 = ky; } else { w = w4; m2 = ky - 12; } }
    size_t moff = (size_t)m1*144 + m2*12 + kz;
    const float* wp = w + ((size_t)(layer*1024 + o) * 1728 + moff) * 2;  // + i*110592
    const float2* xp = X3 + (size_t)b * 32 * 6912 + mode;
    float re = 0.f, im = 0.f;
    for (int i = 0; i < 32; ++i){
        float2 a = xp[(size_t)i * 6912];
        float wr = wp[(size_t)i * 110592];
        float wi = wp[(size_t)i * 110592 + 1];
        re += a.x * wr - a.y * wi;
        im += a.x * wi + a.y * wr;
    }
    Y[(size_t)bo * 6912 + mode] = make_float2(re, im);
}

// ---------------- inverse over s: Y[bo][kx][ky][kz] -> Z1[bo][kz][s][ky] ---
__global__ __launch_bounds__(256) void k_invS(
    const float2* __restrict__ Y, float2* __restrict__ Z1)
{
    __shared__ float2 yin[24][24];
    __shared__ float ctab[64], stab[64];
    int tid = threadIdx.x;
    TWIDDLE_INIT(ctab, stab)
    int bo = blockIdx.x / 12;
    int kz = blockIdx.x % 12;
    for (int i = tid; i < 576; i += 256){
        int kx = i / 24, ky = i % 24;
        yin[kx][ky] = Y[(size_t)bo * 6912 + (size_t)kx * 288 + ky * 12 + kz];
    }
    __syncthreads();
    int s = tid & 63;
    int kyg = tid >> 6;   // 0..3 -> 6 ky each
    float re[6] = {0,0,0,0,0,0}, im[6] = {0,0,0,0,0,0};
    for (int kxi = 0; kxi < 24; ++kxi){
        int kxa = (kxi < 12) ? kxi : kxi + 40;
        int m = (kxa * s) & 63;
        float cw = ctab[m], sw = stab[m];     // e^{+i theta}
        #pragma unroll
        for (int j = 0; j < 6; ++j){
            float2 a = yin[kxi][kyg*6 + j];
            re[j] += a.x * cw - a.y * sw;
            im[j] += a.x * sw + a.y * cw;
        }
    }
    #pragma unroll
    for (int j = 0; j < 6; ++j){
        int ky = kyg*6 + j;
        Z1[((size_t)(bo*12 + kz) * 64 + s) * 24 + ky] = make_float2(re[j], im[j]);
    }
}

// ---------------- pointwise conv IN-PLACE: x[b,:,p] <- W x[b,:,p] + b ------
__global__ __launch_bounds__(256) void k_conv(
    float* x, const float* __restrict__ cw,
    const float* __restrict__ cb, int layer)
{
    __shared__ float wsh[32][32];   // [o][i]
    __shared__ float bsh[32];
    int tid = threadIdx.x;
    if (tid < 32) bsh[tid] = cb[layer*32 + tid];
    for (int i = tid; i < 1024; i += 256) wsh[i >> 5][i & 31] = cw[layer*1024 + i];
    __syncthreads();
    size_t g = (size_t)blockIdx.x * 256 + tid;
    int b = (int)(g >> 18);
    size_t p = g & (size_t)(SVT - 1);
    float acc[32];
    #pragma unroll
    for (int o = 0; o < 32; ++o) acc[o] = bsh[o];
    for (int i = 0; i < 32; ++i){
        float xv = x[(size_t)(b*32 + i) * SVT + p];
        #pragma unroll
        for (int o = 0; o < 32; ++o) acc[o] += xv * wsh[o][i];
    }
    #pragma unroll
    for (int o = 0; o < 32; ++o) x[(size_t)(b*32 + o) * SVT + p] = acc[o];
}

// -- fused inverse over v then t (+ gelu(x1+x2)): Z1 -> xio = gelu(x1+xio) --
__global__ __launch_bounds__(256) void k_invVT(
    const float2* __restrict__ Z1, float* xio)
{
    __shared__ float2 zin[12][24];
    __shared__ float cre[12][65], cim[12][65];
    __shared__ float ctab[64], stab[64];
    int tid = threadIdx.x;
    int bo = blockIdx.x >> 6;
    int s  = blockIdx.x & 63;
    TWIDDLE_INIT(ctab, stab)
    // Z1 layout: [bo][kz][s][ky]
    for (int i = tid; i < 288; i += 256){
        int kz = i / 24, ky = i % 24;
        zin[kz][ky] = Z1[((size_t)(bo*12 + kz) * 64 + s) * 24 + ky];
    }
    __syncthreads();
    // stage 1: inverse DFT over ky -> c[kz][v]
    #pragma unroll
    for (int j = 0; j < 3; ++j){
        int task = tid + j * 256;        // < 768
        int v = task & 63, kz = task >> 6;
        float re = 0.f, im = 0.f;
        #pragma unroll
        for (int ky = 0; ky < 24; ++ky){
            int kya = (ky < 12) ? ky : ky + 40;
            int m = (kya * v) & 63;
            float cw = ctab[m], sw = stab[m];
            float2 a = zin[kz][ky];
            re += a.x * cw - a.y * sw;
            im += a.x * sw + a.y * cw;
        }
        cre[kz][v] = re; cim[kz][v] = im;
    }
    __syncthreads();
    // stage 2: real inverse over kz, combine with conv-out (in xio), gelu
    int v  = tid & 63;
    int tb = (tid >> 6) << 4;   // 0,16,32,48
    float sum[16];
    #pragma unroll
    for (int j = 0; j < 16; ++j) sum[j] = 0.f;
    float dc = cre[0][v];
    #pragma unroll
    for (int kz = 1; kz < 12; ++kz){
        float ar = cre[kz][v], ai = cim[kz][v];
        #pragma unroll
        for (int j = 0; j < 16; ++j){
            int m = (kz * (tb + j)) & 63;
            sum[j] += ar * ctab[m] - ai * stab[m];
        }
    }
    const float norm = 1.0f / 262144.0f;
    size_t base = (size_t)bo * SVT + (size_t)s * VT + (size_t)v * 64 + tb;
    #pragma unroll
    for (int j = 0; j < 16; j += 4){
        float4 xv = *(const float4*)&xio[base + j];
        float4 r;
        r.x = gelu_f((dc + 2.f*sum[j+0]) * norm + xv.x);
        r.y = gelu_f((dc + 2.f*sum[j+1]) * norm + xv.y);
        r.z = gelu_f((dc + 2.f*sum[j+2]) * norm + xv.z);
        r.w = gelu_f((dc + 2.f*sum[j+3]) * norm + xv.w);
        *(float4*)&xio[base + j] = r;
    }
}

// ---------------- fused skip MLP, adds into xio ---------------------------
__global__ __launch_bounds__(512) void k_skip(
    const float* __restrict__ coords, const float* __restrict__ params,
    const float* __restrict__ s1w, const float* __restrict__ s1b,
    const float* __restrict__ s2w, const float* __restrict__ s2b,
    const float* __restrict__ s3w, const float* __restrict__ s3b,
    int layer, float* __restrict__ xio)
{
    __shared__ float w3s[128][32];
    __shared__ float w1s[9][128];
    __shared__ float pb[128];
    __shared__ float b2s[128];
    __shared__ float b3s[32];
    __shared__ float ht[128][132];   // [k][p], transposed
    int tid = threadIdx.x;
    size_t g0 = (size_t)blockIdx.x * 128;
    int b = (int)(g0 >> 18);
    const float* w2g = s2w + (size_t)layer * 16384;

    for (int i = tid; i < 4096;  i += 512) w3s[i >> 5][i & 31]  = s3w[(size_t)layer*4096  + i];
    for (int i = tid; i < 1152;  i += 512) w1s[i >> 7][i & 127] = s1w[(size_t)layer*1152  + i];
    if (tid < 128) b2s[tid] = s2b[layer*128 + tid];
    if (tid < 32)  b3s[tid] = s3b[layer*32  + tid];
    __syncthreads();
    if (tid < 128){
        float acc = s1b[layer*128 + tid];
        #pragma unroll
        for (int j = 0; j < 6; ++j) acc += params[b*6 + j] * w1s[3 + j][tid];
        pb[tid] = acc;
    }
    __syncthreads();

    // phase B: h1 = gelu(coords @ w1 + pb), stored transposed ht[h][p]
    {
        int p  = tid >> 2;
        int hb = (tid & 3) << 5;
        size_t g = g0 + p;
        float z0 = coords[g*3+0], z1 = coords[g*3+1], z2 = coords[g*3+2];
        #pragma unroll
        for (int h = 0; h < 32; ++h){
            int hh = hb + h;
            float acc = pb[hh] + z0*w1s[0][hh] + z1*w1s[1][hh] + z2*w1s[2][hh];
            ht[hh][p] = gelu_f(acc);
        }
    }
    __syncthreads();

    // phase C: h2 = gelu(h1 @ w2 + b2), tile 4p x 8c per thread; w2 via L1/L2
    int pg = tid >> 4;        // 0..31 -> p = pg*4 + i
    int cg = tid & 15;        // c = cg*8 + j
    float a2[4][8];
    #pragma unroll
    for (int i = 0; i < 4; ++i)
        #pragma unroll
        for (int j = 0; j < 8; ++j) a2[i][j] = b2s[cg*8 + j];
    #pragma unroll 2
    for (int k = 0; k < 128; ++k){
        float4 hv = *(const float4*)&ht[k][pg << 2];
        float4 wa = *(const float4*)&w2g[k*128 + (cg << 3)];
        float4 wb = *(const float4*)&w2g[k*128 + (cg << 3) + 4];
        float wv[8] = {wa.x, wa.y, wa.z, wa.w, wb.x, wb.y, wb.z, wb.w};
        #pragma unroll
        for (int j = 0; j < 8; ++j){
            a2[0][j] += hv.x * wv[j];
            a2[1][j] += hv.y * wv[j];
            a2[2][j] += hv.z * wv[j];
            a2[3][j] += hv.w * wv[j];
        }
    }
    __syncthreads();
    #pragma unroll
    for (int i = 0; i < 4; ++i)
        #pragma unroll
        for (int j = 0; j < 8; ++j)
            ht[cg*8 + j][pg*4 + i] = gelu_f(a2[i][j]);
    __syncthreads();

    // phase D: out = h2 @ w3 + b3, add into xio
    {
        int p  = tid >> 2;
        int ob = (tid & 3) << 3;
        float acc3[8];
        #pragma unroll
        for (int j = 0; j < 8; ++j) acc3[j] = b3s[ob + j];
        for (int k = 0; k < 128; ++k){
            float hv = ht[k][p];
            #pragma unroll
            for (int j = 0; j < 8; ++j) acc3[j] += hv * w3s[k][ob + j];
        }
        size_t prel = (g0 & (size_t)(SVT - 1)) + p;
        #pragma unroll
        for (int j = 0; j < 8; ++j){
            size_t idx = (size_t)(b*32 + ob + j) * SVT + prel;
            xio[idx] += acc3[j];
        }
    }
}

// ---------------- projection head --------------------------------------
__global__ __launch_bounds__(256) void k_proj(
    const float* __restrict__ x, const float* __restrict__ p1w,
    const float* __restrict__ p1b, const float* __restrict__ p2w,
    const float* __restrict__ p2b, float* __restrict__ out)
{
    __shared__ float w1s[32][16];
    __shared__ float b1s[16];
    __shared__ float w2s[16];
    int tid = threadIdx.x;
    for (int i = tid; i < 512; i += 256) w1s[i >> 4][i & 15] = p1w[i];
    if (tid < 16){ b1s[tid] = p1b[tid]; w2s[tid] = p2w[tid]; }
    __syncthreads();
    size_t g = (size_t)blockIdx.x * 256 + tid;
    int b = (int)(g >> 18);
    size_t p = g & (size_t)(SVT - 1);
    float h[16];
    #pragma unroll
    for (int j = 0; j < 16; ++j) h[j] = b1s[j];
    for (int c = 0; c < 32; ++c){
        float xv = x[(size_t)(b*32 + c) * SVT + p];
        #pragma unroll
        for (int j = 0; j < 16; ++j) h[j] += xv * w1s[c][j];
    }
    float acc = p2b[0];
    #pragma unroll
    for (int j = 0; j < 16; ++j) acc += gelu_f(h[j]) * w2s[j];
    out[g] = acc;
}

extern "C" void kernel_launch(void* const* d_in, const int* in_sizes, int n_in,
                              void* d_out, int out_size, void* d_ws, size_t ws_size,
                              hipStream_t stream)
{
    (void)in_sizes; (void)n_in; (void)out_size; (void)ws_size;
    const float* coords = (const float*)d_in[0];
    const float* params = (const float*)d_in[1];
    const float* lift_w = (const float*)d_in[2];
    const float* lift_b = (const float*)d_in[3];
    const float* sw1    = (const float*)d_in[4];
    const float* sw2    = (const float*)d_in[5];
    const float* sw3    = (const float*)d_in[6];
    const float* sw4    = (const float*)d_in[7];
    const float* conv_w = (const float*)d_in[8];
    const float* conv_b = (const float*)d_in[9];
    const float* s1w    = (const float*)d_in[10];
    const float* s1b    = (const float*)d_in[11];
    const float* s2w    = (const float*)d_in[12];
    const float* s2b    = (const float*)d_in[13];
    const float* s3w    = (const float*)d_in[14];
    const float* s3b    = (const float*)d_in[15];
    const float* p1w    = (const float*)d_in[16];
    const float* p1b    = (const float*)d_in[17];
    const float* p2w    = (const float*)d_in[18];
    const float* p2b    = (const float*)d_in[19];
    float* out = (float*)d_out;

    // workspace: 134,217,728 + 18,874,368 + 7,077,888 + 7,077,888 = 167,247,872 B
    char* ws = (char*)d_ws;
    float*  xA = (float*)(ws);
    float2* X2 = (float2*)(ws + 134217728ull);                 // also Z1
    float2* X3 = (float2*)(ws + 134217728ull + 18874368ull);
    float2* Yb = (float2*)(ws + 134217728ull + 25952256ull);

    k_lift<<<4096, 256, 0, stream>>>(coords, params, lift_w, lift_b, xA);

    for (int l = 0; l < NLAY; ++l){
        k_fwdTV<<<8192, 256, 0, stream>>>(xA, X2);
        k_fwdS<<<1152, 256, 0, stream>>>(X2, X3);
        dim3 gmm(27, 128);
        k_modemix<<<gmm, 256, 0, stream>>>(X3, sw1, sw2, sw3, sw4, l, Yb);
        k_invS<<<1536, 256, 0, stream>>>(Yb, X2);          // Z1 overlays X2
        k_conv<<<4096, 256, 0, stream>>>(xA, conv_w, conv_b, l);   // in place
        k_invVT<<<8192, 256, 0, stream>>>(X2, xA);         // xA = gelu(x1 + x2)
        k_skip<<<8192, 512, 0, stream>>>(coords, params, s1w, s1b, s2w, s2b,
                                         s3w, s3b, l, xA);
    }

    k_proj<<<4096, 256, 0, stream>>>(xA, p1w, p1b, p2w, p2b, out);
}

// Round 3
// 4047.206 us; speedup vs baseline: 1.5990x; 1.5990x over previous
//
#include <hip/hip_runtime.h>
#include <hip/hip_bf16.h>
#include <math.h>

#define NB   4
#define NC   32
#define SVT  262144      // 64^3
#define VT   4096        // 64*64
#define NLAY 4
#define TWOPI_64 0.09817477042468103f

typedef __attribute__((ext_vector_type(8))) short bf16x8;
typedef __attribute__((ext_vector_type(4))) float f32x4;

__device__ __forceinline__ float gelu_f(float x){
    return 0.5f * x * (1.0f + erff(x * 0.70710678118654752f));
}

__device__ __forceinline__ unsigned short f2bf(float f){
    union { __hip_bfloat16 h; unsigned short u; } cv;
    cv.h = __float2bfloat16(f);
    return cv.u;
}
__device__ __forceinline__ float bf2f(unsigned short u){
    return __uint_as_float(((unsigned int)u) << 16);
}

#define TWIDDLE_INIT(ctab, stab)                                     \
    if (threadIdx.x < 64){                                           \
        float sn, cs;                                                \
        sincosf((float)threadIdx.x * TWOPI_64, &sn, &cs);            \
        ctab[threadIdx.x] = cs; stab[threadIdx.x] = sn;              \
    }

// ---------------- lift: x = z @ lift_w + lift_b, layout [B,C,S,V,T] -------
__global__ __launch_bounds__(256) void k_lift(
    const float* __restrict__ coords, const float* __restrict__ params,
    const float* __restrict__ lw, const float* __restrict__ lb,
    float* __restrict__ x)
{
    size_t g = (size_t)blockIdx.x * 256 + threadIdx.x;   // 0..1048575
    int b = (int)(g >> 18);
    size_t p = g & (size_t)(SVT - 1);
    float z[9];
    z[0] = coords[g*3+0]; z[1] = coords[g*3+1]; z[2] = coords[g*3+2];
    #pragma unroll
    for (int j = 0; j < 6; ++j) z[3+j] = params[b*6+j];
    #pragma unroll
    for (int c = 0; c < 32; ++c){
        float acc = lb[c];
        #pragma unroll
        for (int j = 0; j < 9; ++j) acc += z[j] * lw[j*32 + c];
        x[(size_t)(b*32 + c) * SVT + p] = acc;
    }
}

// ------- fused forward DFT over t then v: x[bc][s][v][t] -> X2[bc][kz][ky][s]
__global__ __launch_bounds__(256) void k_fwdTV(
    const float* __restrict__ x, float2* __restrict__ X2)
{
    __shared__ float xin[64][65];
    __shared__ float are[12][65], aim[12][65];
    __shared__ float ctab[64], stab[64];
    int tid = threadIdx.x;
    int bc = blockIdx.x >> 6;
    int s  = blockIdx.x & 63;
    TWIDDLE_INIT(ctab, stab)
    const float* src = x + (size_t)bc * SVT + (size_t)s * VT;
    for (int i = tid; i < 4096; i += 256)
        xin[i >> 6][i & 63] = src[i];
    __syncthreads();
    // stage 1: DFT over t -> a[kz][v]
    #pragma unroll
    for (int j = 0; j < 3; ++j){
        int task = tid + j * 256;        // < 768
        int v = task & 63, kz = task >> 6;
        float re = 0.f, im = 0.f;
        for (int t = 0; t < 64; ++t){
            float xv = xin[v][t];
            int m = (kz * t) & 63;
            re += xv * ctab[m];
            im -= xv * stab[m];
        }
        are[kz][v] = re; aim[kz][v] = im;
    }
    __syncthreads();
    // stage 2: DFT over v -> X2[bc][kz][ky][s]
    for (int task = tid; task < 288; task += 256){
        int kz = task % 12;
        int ky = task / 12;
        int kya = (ky < 12) ? ky : ky + 40;
        float re = 0.f, im = 0.f;
        for (int v = 0; v < 64; ++v){
            int m = (kya * v) & 63;
            float cw = ctab[m], sw = stab[m];
            float ar = are[kz][v], ai = aim[kz][v];
            re += ar * cw + ai * sw;
            im += ai * cw - ar * sw;
        }
        X2[((size_t)(bc*12 + kz) * 24 + ky) * 64 + s] = make_float2(re, im);
    }
}

// ---------------- forward DFT over s: X2[bc][kz][ky][s] -> X3[bc][kx][ky][kz]
__global__ __launch_bounds__(256) void k_fwdS(
    const float2* __restrict__ X2, float2* __restrict__ X3)
{
    __shared__ float2 cin[32][65];
    __shared__ float ctab[64], stab[64];
    int tid = threadIdx.x;
    TWIDDLE_INIT(ctab, stab)
    int rbase = blockIdx.x * 32;   // rows (bc,kz,ky), 36864 total
    for (int i = tid; i < 2048; i += 256){
        int row = i >> 6, s = i & 63;
        cin[row][s] = X2[(size_t)(rbase + row) * 64 + s];
    }
    __syncthreads();
    int row = tid & 31;
    int r = rbase + row;
    int kxg = tid >> 5;       // 0..7 -> 3 kx each
    int kxs[3];
    #pragma unroll
    for (int j = 0; j < 3; ++j){ int kxi = kxg*3 + j; kxs[j] = (kxi < 12) ? kxi : kxi + 40; }
    float re[3] = {0,0,0}, im[3] = {0,0,0};
    for (int s = 0; s < 64; ++s){
        float2 cv = cin[row][s];
        #pragma unroll
        for (int j = 0; j < 3; ++j){
            int m = (kxs[j] * s) & 63;
            float cw = ctab[m], sw = stab[m];
            re[j] += cv.x * cw + cv.y * sw;
            im[j] += cv.y * cw - cv.x * sw;
        }
    }
    int bc = r / 288; int kz = (r / 24) % 12; int ky = r % 24;
    #pragma unroll
    for (int j = 0; j < 3; ++j){
        int kxi = kxg*3 + j;
        X3[(size_t)bc * 6912 + (size_t)kxi * 288 + ky * 12 + kz] = make_float2(re[j], im[j]);
    }
}

// ---------------- per-mode channel mixing: Y[b,o,mode] = sum_i X3[b,i,mode]*W
__global__ __launch_bounds__(256) void k_modemix(
    const float2* __restrict__ X3,
    const float* __restrict__ w1, const float* __restrict__ w2,
    const float* __restrict__ w3, const float* __restrict__ w4,
    int layer, float2* __restrict__ Y)
{
    int mode = blockIdx.x * 256 + threadIdx.x;   // 0..6911
    int bo = blockIdx.y;
    int b = bo >> 5, o = bo & 31;
    int kx = mode / 288;
    int ky = (mode / 12) % 24;
    int kz = mode % 12;
    const float* w; int m1, m2;
    if (kx < 12){ m1 = kx;      if (ky < 12){ w = w1; m2 = ky; } else { w = w3; m2 = ky - 12; } }
    else        { m1 = kx - 12; if (ky < 12){ w = w2; m2 = ky; } else { w = w4; m2 = ky - 12; } }
    size_t moff = (size_t)m1*144 + m2*12 + kz;
    const float* wp = w + ((size_t)(layer*1024 + o) * 1728 + moff) * 2;  // + i*110592
    const float2* xp = X3 + (size_t)b * 32 * 6912 + mode;
    float re = 0.f, im = 0.f;
    for (int i = 0; i < 32; ++i){
        float2 a = xp[(size_t)i * 6912];
        float wr = wp[(size_t)i * 110592];
        float wi = wp[(size_t)i * 110592 + 1];
        re += a.x * wr - a.y * wi;
        im += a.x * wi + a.y * wr;
    }
    Y[(size_t)bo * 6912 + mode] = make_float2(re, im);
}

// ---------------- inverse over s: Y[bo][kx][ky][kz] -> Z1[bo][kz][s][ky] ---
__global__ __launch_bounds__(256) void k_invS(
    const float2* __restrict__ Y, float2* __restrict__ Z1)
{
    __shared__ float2 yin[24][24];
    __shared__ float ctab[64], stab[64];
    int tid = threadIdx.x;
    TWIDDLE_INIT(ctab, stab)
    int bo = blockIdx.x / 12;
    int kz = blockIdx.x % 12;
    for (int i = tid; i < 576; i += 256){
        int kx = i / 24, ky = i % 24;
        yin[kx][ky] = Y[(size_t)bo * 6912 + (size_t)kx * 288 + ky * 12 + kz];
    }
    __syncthreads();
    int s = tid & 63;
    int kyg = tid >> 6;   // 0..3 -> 6 ky each
    float re[6] = {0,0,0,0,0,0}, im[6] = {0,0,0,0,0,0};
    for (int kxi = 0; kxi < 24; ++kxi){
        int kxa = (kxi < 12) ? kxi : kxi + 40;
        int m = (kxa * s) & 63;
        float cw = ctab[m], sw = stab[m];     // e^{+i theta}
        #pragma unroll
        for (int j = 0; j < 6; ++j){
            float2 a = yin[kxi][kyg*6 + j];
            re[j] += a.x * cw - a.y * sw;
            im[j] += a.x * sw + a.y * cw;
        }
    }
    #pragma unroll
    for (int j = 0; j < 6; ++j){
        int ky = kyg*6 + j;
        Z1[((size_t)(bo*12 + kz) * 64 + s) * 24 + ky] = make_float2(re[j], im[j]);
    }
}

// ---------------- pointwise conv IN-PLACE: x[b,:,p] <- W x[b,:,p] + b ------
__global__ __launch_bounds__(256) void k_conv(
    float* x, const float* __restrict__ cw,
    const float* __restrict__ cb, int layer)
{
    __shared__ float wsh[32][32];   // [o][i]
    __shared__ float bsh[32];
    int tid = threadIdx.x;
    if (tid < 32) bsh[tid] = cb[layer*32 + tid];
    for (int i = tid; i < 1024; i += 256) wsh[i >> 5][i & 31] = cw[layer*1024 + i];
    __syncthreads();
    size_t g = (size_t)blockIdx.x * 256 + tid;
    int b = (int)(g >> 18);
    size_t p = g & (size_t)(SVT - 1);
    float acc[32];
    #pragma unroll
    for (int o = 0; o < 32; ++o) acc[o] = bsh[o];
    for (int i = 0; i < 32; ++i){
        float xv = x[(size_t)(b*32 + i) * SVT + p];
        #pragma unroll
        for (int o = 0; o < 32; ++o) acc[o] += xv * wsh[o][i];
    }
    #pragma unroll
    for (int o = 0; o < 32; ++o) x[(size_t)(b*32 + o) * SVT + p] = acc[o];
}

// -- fused inverse over v then t (+ gelu(x1+x2)): Z1 -> xio = gelu(x1+xio) --
__global__ __launch_bounds__(256) void k_invVT(
    const float2* __restrict__ Z1, float* xio)
{
    __shared__ float2 zin[12][24];
    __shared__ float cre[12][65], cim[12][65];
    __shared__ float ctab[64], stab[64];
    int tid = threadIdx.x;
    int bo = blockIdx.x >> 6;
    int s  = blockIdx.x & 63;
    TWIDDLE_INIT(ctab, stab)
    // Z1 layout: [bo][kz][s][ky]
    for (int i = tid; i < 288; i += 256){
        int kz = i / 24, ky = i % 24;
        zin[kz][ky] = Z1[((size_t)(bo*12 + kz) * 64 + s) * 24 + ky];
    }
    __syncthreads();
    // stage 1: inverse DFT over ky -> c[kz][v]
    #pragma unroll
    for (int j = 0; j < 3; ++j){
        int task = tid + j * 256;        // < 768
        int v = task & 63, kz = task >> 6;
        float re = 0.f, im = 0.f;
        #pragma unroll
        for (int ky = 0; ky < 24; ++ky){
            int kya = (ky < 12) ? ky : ky + 40;
            int m = (kya * v) & 63;
            float cw = ctab[m], sw = stab[m];
            float2 a = zin[kz][ky];
            re += a.x * cw - a.y * sw;
            im += a.x * sw + a.y * cw;
        }
        cre[kz][v] = re; cim[kz][v] = im;
    }
    __syncthreads();
    // stage 2: real inverse over kz, combine with conv-out (in xio), gelu
    int v  = tid & 63;
    int tb = (tid >> 6) << 4;   // 0,16,32,48
    float sum[16];
    #pragma unroll
    for (int j = 0; j < 16; ++j) sum[j] = 0.f;
    float dc = cre[0][v];
    #pragma unroll
    for (int kz = 1; kz < 12; ++kz){
        float ar = cre[kz][v], ai = cim[kz][v];
        #pragma unroll
        for (int j = 0; j < 16; ++j){
            int m = (kz * (tb + j)) & 63;
            sum[j] += ar * ctab[m] - ai * stab[m];
        }
    }
    const float norm = 1.0f / 262144.0f;
    size_t base = (size_t)bo * SVT + (size_t)s * VT + (size_t)v * 64 + tb;
    #pragma unroll
    for (int j = 0; j < 16; j += 4){
        float4 xv = *(const float4*)&xio[base + j];
        float4 r;
        r.x = gelu_f((dc + 2.f*sum[j+0]) * norm + xv.x);
        r.y = gelu_f((dc + 2.f*sum[j+1]) * norm + xv.y);
        r.z = gelu_f((dc + 2.f*sum[j+2]) * norm + xv.z);
        r.w = gelu_f((dc + 2.f*sum[j+3]) * norm + xv.w);
        *(float4*)&xio[base + j] = r;
    }
}

// ---------------- fused skip MLP via MFMA (bf16 in / fp32 acc) -------------
// block: 256 thr = 4 waves, 128 points. wave w owns rows [32w, 32w+32).
__global__ __launch_bounds__(256) void k_skip(
    const float* __restrict__ coords, const float* __restrict__ params,
    const float* __restrict__ s1w, const float* __restrict__ s1b,
    const float* __restrict__ s2w, const float* __restrict__ s2b,
    const float* __restrict__ s3w, const float* __restrict__ s3b,
    int layer, float* __restrict__ xio)
{
    __shared__ __align__(16) unsigned short A1[128][136];   // h1 then h2 (bf16)
    __shared__ __align__(16) unsigned short w2T[128][136];  // [c][k]; later outsT
    __shared__ __align__(16) unsigned short w3T[32][136];   // [c2][k]
    __shared__ unsigned short w1s[9][128];                  // bf16
    __shared__ float pb[128];
    __shared__ float b2s[128];
    __shared__ float b3s[32];

    int tid = threadIdx.x;
    size_t g0 = (size_t)blockIdx.x * 128;
    int b = (int)(g0 >> 18);

    // ---- preamble: stage weights (transposed, bf16) ----
    {
        const float* w2g = s2w + (size_t)layer * 16384;
        int c  = tid >> 1;
        int kh = (tid & 1) << 6;
        #pragma unroll
        for (int gq = 0; gq < 8; ++gq){
            bf16x8 pk;
            #pragma unroll
            for (int j = 0; j < 8; ++j)
                pk[j] = (short)f2bf(w2g[(kh + gq*8 + j)*128 + c]);
            *(bf16x8*)&w2T[c][kh + gq*8] = pk;
        }
        const float* w3g = s3w + (size_t)layer * 4096;
        int c2 = tid >> 3;
        int ks = (tid & 7) << 4;
        #pragma unroll
        for (int gq = 0; gq < 2; ++gq){
            bf16x8 pk;
            #pragma unroll
            for (int j = 0; j < 8; ++j)
                pk[j] = (short)f2bf(w3g[(ks + gq*8 + j)*32 + c2]);
            *(bf16x8*)&w3T[c2][ks + gq*8] = pk;
        }
        for (int i = tid; i < 1152; i += 256)
            w1s[i >> 7][i & 127] = f2bf(s1w[(size_t)layer*1152 + i]);
        if (tid < 128) b2s[tid] = s2b[layer*128 + tid];
        if (tid < 32)  b3s[tid] = s3b[layer*32  + tid];
    }
    __syncthreads();
    if (tid < 128){
        float acc = s1b[layer*128 + tid];
        #pragma unroll
        for (int j = 0; j < 6; ++j) acc += params[b*6 + j] * bf2f(w1s[3 + j][tid]);
        pb[tid] = acc;
    }
    __syncthreads();

    // ---- phase B: h1 = gelu(coords@w1 + pb) -> A1 (bf16), wave-local rows --
    {
        int p  = tid >> 1;
        int hb = (tid & 1) << 6;
        size_t g = g0 + p;
        float z0 = coords[g*3+0], z1 = coords[g*3+1], z2 = coords[g*3+2];
        #pragma unroll
        for (int gq = 0; gq < 8; ++gq){
            bf16x8 pk;
            #pragma unroll
            for (int j = 0; j < 8; ++j){
                int hh = hb + gq*8 + j;
                float a = pb[hh] + z0*bf2f(w1s[0][hh]) + z1*bf2f(w1s[1][hh])
                                 + z2*bf2f(w1s[2][hh]);
                pk[j] = (short)f2bf(gelu_f(a));
            }
            *(bf16x8*)&A1[p][hb + gq*8] = pk;
        }
    }
    // no barrier: wave reads only rows its own lanes wrote (LDS in-order per wave)

    int l  = tid & 63;
    int w  = tid >> 6;
    int r0 = w << 5;
    int lr = l & 15;
    int kg = l >> 4;

    // ---- phase C: h2 = gelu(h1 @ w2 + b2)  (MFMA, overlay into A1) --------
    {
        f32x4 acc[2][8];
        #pragma unroll
        for (int m = 0; m < 2; ++m)
            #pragma unroll
            for (int n = 0; n < 8; ++n) acc[m][n] = (f32x4){0.f,0.f,0.f,0.f};
        #pragma unroll
        for (int kc = 0; kc < 4; ++kc){
            int ko = kc*32 + kg*8;
            bf16x8 a0 = *(const bf16x8*)&A1[r0 + lr     ][ko];
            bf16x8 a1 = *(const bf16x8*)&A1[r0 + 16 + lr][ko];
            #pragma unroll
            for (int n = 0; n < 8; ++n){
                bf16x8 bb = *(const bf16x8*)&w2T[n*16 + lr][ko];
                acc[0][n] = __builtin_amdgcn_mfma_f32_16x16x32_bf16(a0, bb, acc[0][n], 0, 0, 0);
                acc[1][n] = __builtin_amdgcn_mfma_f32_16x16x32_bf16(a1, bb, acc[1][n], 0, 0, 0);
            }
        }
        #pragma unroll
        for (int m = 0; m < 2; ++m)
            #pragma unroll
            for (int n = 0; n < 8; ++n){
                int col = n*16 + lr;
                float bv = b2s[col];
                #pragma unroll
                for (int r = 0; r < 4; ++r){
                    int row = r0 + m*16 + kg*4 + r;
                    A1[row][col] = f2bf(gelu_f(acc[m][n][r] + bv));
                }
            }
    }

    // ---- phase D: out = h2 @ w3 + b3 (MFMA) -------------------------------
    f32x4 c3[2][2];
    #pragma unroll
    for (int m = 0; m < 2; ++m)
        #pragma unroll
        for (int n = 0; n < 2; ++n) c3[m][n] = (f32x4){0.f,0.f,0.f,0.f};
    #pragma unroll
    for (int kc = 0; kc < 4; ++kc){
        int ko = kc*32 + kg*8;
        bf16x8 a0 = *(const bf16x8*)&A1[r0 + lr     ][ko];
        bf16x8 a1 = *(const bf16x8*)&A1[r0 + 16 + lr][ko];
        bf16x8 b0 = *(const bf16x8*)&w3T[lr     ][ko];
        bf16x8 b1 = *(const bf16x8*)&w3T[16 + lr][ko];
        c3[0][0] = __builtin_amdgcn_mfma_f32_16x16x32_bf16(a0, b0, c3[0][0], 0, 0, 0);
        c3[0][1] = __builtin_amdgcn_mfma_f32_16x16x32_bf16(a0, b1, c3[0][1], 0, 0, 0);
        c3[1][0] = __builtin_amdgcn_mfma_f32_16x16x32_bf16(a1, b0, c3[1][0], 0, 0, 0);
        c3[1][1] = __builtin_amdgcn_mfma_f32_16x16x32_bf16(a1, b1, c3[1][1], 0, 0, 0);
    }
    __syncthreads();   // all waves done reading w2T -> safe to overlay outsT

    float* outsT = (float*)&w2T[0][0];    // [32][260] fp32, transposed
    #pragma unroll
    for (int m = 0; m < 2; ++m)
        #pragma unroll
        for (int n = 0; n < 2; ++n){
            int c2 = n*16 + lr;
            int rowb = r0 + m*16 + kg*4;
            float bv = b3s[c2];
            float4 v4;
            v4.x = c3[m][n][0] + bv;
            v4.y = c3[m][n][1] + bv;
            v4.z = c3[m][n][2] + bv;
            v4.w = c3[m][n][3] + bv;
            *(float4*)&outsT[c2*260 + rowb] = v4;
        }
    __syncthreads();

    // ---- global rmw: xio[(b,c), g0 + p] += outsT[c][p], coalesced ---------
    {
        int c  = tid >> 3;        // 0..31
        int pg = tid & 7;         // 16 points each
        size_t prel = (g0 & (size_t)(SVT - 1)) + (size_t)pg*16;
        float* gp = xio + (((size_t)(b*32 + c)) << 18) + prel;
        const float* op = &outsT[c*260 + pg*16];
        #pragma unroll
        for (int i = 0; i < 16; i += 4){
            float4 xv = *(const float4*)&gp[i];
            float4 ov = *(const float4*)&op[i];
            xv.x += ov.x; xv.y += ov.y; xv.z += ov.z; xv.w += ov.w;
            *(float4*)&gp[i] = xv;
        }
    }
}

// ---------------- projection head --------------------------------------
__global__ __launch_bounds__(256) void k_proj(
    const float* __restrict__ x, const float* __restrict__ p1w,
    const float* __restrict__ p1b, const float* __restrict__ p2w,
    const float* __restrict__ p2b, float* __restrict__ out)
{
    __shared__ float w1s[32][16];
    __shared__ float b1s[16];
    __shared__ float w2s[16];
    int tid = threadIdx.x;
    for (int i = tid; i < 512; i += 256) w1s[i >> 4][i & 15] = p1w[i];
    if (tid < 16){ b1s[tid] = p1b[tid]; w2s[tid] = p2w[tid]; }
    __syncthreads();
    size_t g = (size_t)blockIdx.x * 256 + tid;
    int b = (int)(g >> 18);
    size_t p = g & (size_t)(SVT - 1);
    float h[16];
    #pragma unroll
    for (int j = 0; j < 16; ++j) h[j] = b1s[j];
    for (int c = 0; c < 32; ++c){
        float xv = x[(size_t)(b*32 + c) * SVT + p];
        #pragma unroll
        for (int j = 0; j < 16; ++j) h[j] += xv * w1s[c][j];
    }
    float acc = p2b[0];
    #pragma unroll
    for (int j = 0; j < 16; ++j) acc += gelu_f(h[j]) * w2s[j];
    out[g] = acc;
}

extern "C" void kernel_launch(void* const* d_in, const int* in_sizes, int n_in,
                              void* d_out, int out_size, void* d_ws, size_t ws_size,
                              hipStream_t stream)
{
    (void)in_sizes; (void)n_in; (void)out_size; (void)ws_size;
    const float* coords = (const float*)d_in[0];
    const float* params = (const float*)d_in[1];
    const float* lift_w = (const float*)d_in[2];
    const float* lift_b = (const float*)d_in[3];
    const float* sw1    = (const float*)d_in[4];
    const float* sw2    = (const float*)d_in[5];
    const float* sw3    = (const float*)d_in[6];
    const float* sw4    = (const float*)d_in[7];
    const float* conv_w = (const float*)d_in[8];
    const float* conv_b = (const float*)d_in[9];
    const float* s1w    = (const float*)d_in[10];
    const float* s1b    = (const float*)d_in[11];
    const float* s2w    = (const float*)d_in[12];
    const float* s2b    = (const float*)d_in[13];
    const float* s3w    = (const float*)d_in[14];
    const float* s3b    = (const float*)d_in[15];
    const float* p1w    = (const float*)d_in[16];
    const float* p1b    = (const float*)d_in[17];
    const float* p2w    = (const float*)d_in[18];
    const float* p2b    = (const float*)d_in[19];
    float* out = (float*)d_out;

    // workspace: 134,217,728 + 18,874,368 + 7,077,888 + 7,077,888 = 167,247,872 B
    char* ws = (char*)d_ws;
    float*  xA = (float*)(ws);
    float2* X2 = (float2*)(ws + 134217728ull);                 // also Z1
    float2* X3 = (float2*)(ws + 134217728ull + 18874368ull);
    float2* Yb = (float2*)(ws + 134217728ull + 25952256ull);

    k_lift<<<4096, 256, 0, stream>>>(coords, params, lift_w, lift_b, xA);

    for (int l = 0; l < NLAY; ++l){
        k_fwdTV<<<8192, 256, 0, stream>>>(xA, X2);
        k_fwdS<<<1152, 256, 0, stream>>>(X2, X3);
        dim3 gmm(27, 128);
        k_modemix<<<gmm, 256, 0, stream>>>(X3, sw1, sw2, sw3, sw4, l, Yb);
        k_invS<<<1536, 256, 0, stream>>>(Yb, X2);          // Z1 overlays X2
        k_conv<<<4096, 256, 0, stream>>>(xA, conv_w, conv_b, l);   // in place
        k_invVT<<<8192, 256, 0, stream>>>(X2, xA);         // xA = gelu(x1 + x2)
        k_skip<<<8192, 256, 0, stream>>>(coords, params, s1w, s1b, s2w, s2b,
                                         s3w, s3b, l, xA);
    }

    k_proj<<<4096, 256, 0, stream>>>(xA, p1w, p1b, p2w, p2b, out);
}

// Round 4
// 3859.402 us; speedup vs baseline: 1.6768x; 1.0487x over previous
//
#include <hip/hip_runtime.h>
#include <hip/hip_bf16.h>
#include <math.h>

#define NB   4
#define NC   32
#define SVT  262144      // 64^3
#define VT   4096        // 64*64
#define NLAY 4
#define TWOPI_64 0.09817477042468103f

typedef __attribute__((ext_vector_type(8))) short bf16x8;
typedef __attribute__((ext_vector_type(4))) float f32x4;

__device__ __forceinline__ float gelu_f(float x){
    return 0.5f * x * (1.0f + erff(x * 0.70710678118654752f));
}

__device__ __forceinline__ unsigned short f2bf(float f){
    union { __hip_bfloat16 h; unsigned short u; } cv;
    cv.h = __float2bfloat16(f);
    return cv.u;
}
__device__ __forceinline__ float bf2f(unsigned short u){
    return __uint_as_float(((unsigned int)u) << 16);
}

#define TWIDDLE_INIT(ctab, stab)                                     \
    if (threadIdx.x < 64){                                           \
        float sn, cs;                                                \
        sincosf((float)threadIdx.x * TWOPI_64, &sn, &cs);            \
        ctab[threadIdx.x] = cs; stab[threadIdx.x] = sn;              \
    }

// ---------------- weight prep: fp32 -> bf16 transposed, once per launch ----
__global__ __launch_bounds__(256) void k_prep(
    const float* __restrict__ s1w, const float* __restrict__ s2w,
    const float* __restrict__ s3w,
    unsigned short* __restrict__ w1bf,   // [4][9][128]
    unsigned short* __restrict__ w2bf,   // [4][c 128][k 128]
    unsigned short* __restrict__ w3bf)   // [4][c2 32][k 128]
{
    int g = blockIdx.x * 256 + threadIdx.x;
    if (g < 65536){
        int l = g >> 14, r = g & 16383;
        int c = r >> 7, k = r & 127;
        w2bf[g] = f2bf(s2w[l*16384 + k*128 + c]);
        return;
    }
    int g3 = g - 65536;
    if (g3 < 16384){
        int l = g3 >> 12, r = g3 & 4095;
        int c2 = r >> 7, k = r & 127;
        w3bf[g3] = f2bf(s3w[l*4096 + k*32 + c2]);
        return;
    }
    int g1 = g3 - 16384;
    if (g1 < 4608) w1bf[g1] = f2bf(s1w[g1]);
}

// ---------------- lift: x = z @ lift_w + lift_b, layout [B,C,S,V,T] -------
__global__ __launch_bounds__(256) void k_lift(
    const float* __restrict__ coords, const float* __restrict__ params,
    const float* __restrict__ lw, const float* __restrict__ lb,
    float* __restrict__ x)
{
    size_t g = (size_t)blockIdx.x * 256 + threadIdx.x;   // 0..1048575
    int b = (int)(g >> 18);
    size_t p = g & (size_t)(SVT - 1);
    float z[9];
    z[0] = coords[g*3+0]; z[1] = coords[g*3+1]; z[2] = coords[g*3+2];
    #pragma unroll
    for (int j = 0; j < 6; ++j) z[3+j] = params[b*6+j];
    #pragma unroll
    for (int c = 0; c < 32; ++c){
        float acc = lb[c];
        #pragma unroll
        for (int j = 0; j < 9; ++j) acc += z[j] * lw[j*32 + c];
        x[(size_t)(b*32 + c) * SVT + p] = acc;
    }
}

// ------- fused forward DFT over t then v: x[bc][s][v][t] -> X2[bc][kz][ky][s]
__global__ __launch_bounds__(256) void k_fwdTV(
    const float* __restrict__ x, float2* __restrict__ X2)
{
    __shared__ float xin[64][65];
    __shared__ float are[12][65], aim[12][65];
    __shared__ float ctab[64], stab[64];
    int tid = threadIdx.x;
    int bc = blockIdx.x >> 6;
    int s  = blockIdx.x & 63;
    TWIDDLE_INIT(ctab, stab)
    const float* src = x + (size_t)bc * SVT + (size_t)s * VT;
    for (int i = tid; i < 4096; i += 256)
        xin[i >> 6][i & 63] = src[i];
    __syncthreads();
    // stage 1: DFT over t -> a[kz][v]
    #pragma unroll
    for (int j = 0; j < 3; ++j){
        int task = tid + j * 256;        // < 768
        int v = task & 63, kz = task >> 6;
        float re = 0.f, im = 0.f;
        for (int t = 0; t < 64; ++t){
            float xv = xin[v][t];
            int m = (kz * t) & 63;
            re += xv * ctab[m];
            im -= xv * stab[m];
        }
        are[kz][v] = re; aim[kz][v] = im;
    }
    __syncthreads();
    // stage 2: DFT over v -> X2[bc][kz][ky][s]
    for (int task = tid; task < 288; task += 256){
        int kz = task % 12;
        int ky = task / 12;
        int kya = (ky < 12) ? ky : ky + 40;
        float re = 0.f, im = 0.f;
        for (int v = 0; v < 64; ++v){
            int m = (kya * v) & 63;
            float cw = ctab[m], sw = stab[m];
            float ar = are[kz][v], ai = aim[kz][v];
            re += ar * cw + ai * sw;
            im += ai * cw - ar * sw;
        }
        X2[((size_t)(bc*12 + kz) * 24 + ky) * 64 + s] = make_float2(re, im);
    }
}

// ---------------- forward DFT over s: X2[bc][kz][ky][s] -> X3[bc][kx][ky][kz]
__global__ __launch_bounds__(256) void k_fwdS(
    const float2* __restrict__ X2, float2* __restrict__ X3)
{
    __shared__ float2 cin[32][65];
    __shared__ float ctab[64], stab[64];
    int tid = threadIdx.x;
    TWIDDLE_INIT(ctab, stab)
    int rbase = blockIdx.x * 32;   // rows (bc,kz,ky), 36864 total
    for (int i = tid; i < 2048; i += 256){
        int row = i >> 6, s = i & 63;
        cin[row][s] = X2[(size_t)(rbase + row) * 64 + s];
    }
    __syncthreads();
    int row = tid & 31;
    int r = rbase + row;
    int kxg = tid >> 5;       // 0..7 -> 3 kx each
    int kxs[3];
    #pragma unroll
    for (int j = 0; j < 3; ++j){ int kxi = kxg*3 + j; kxs[j] = (kxi < 12) ? kxi : kxi + 40; }
    float re[3] = {0,0,0}, im[3] = {0,0,0};
    for (int s = 0; s < 64; ++s){
        float2 cv = cin[row][s];
        #pragma unroll
        for (int j = 0; j < 3; ++j){
            int m = (kxs[j] * s) & 63;
            float cw = ctab[m], sw = stab[m];
            re[j] += cv.x * cw + cv.y * sw;
            im[j] += cv.y * cw - cv.x * sw;
        }
    }
    int bc = r / 288; int kz = (r / 24) % 12; int ky = r % 24;
    #pragma unroll
    for (int j = 0; j < 3; ++j){
        int kxi = kxg*3 + j;
        X3[(size_t)bc * 6912 + (size_t)kxi * 288 + ky * 12 + kz] = make_float2(re[j], im[j]);
    }
}

// --------- per-mode channel mixing v2: coalesced W, X3 in registers --------
// block = (corner, chunk of 64 moffs); 256 thr = 64 modes x 4 batches
__global__ __launch_bounds__(256) void k_modemix(
    const float2* __restrict__ X3,
    const float* __restrict__ w1, const float* __restrict__ w2,
    const float* __restrict__ w3, const float* __restrict__ w4,
    int layer, float2* __restrict__ Y)
{
    __shared__ float2 wlds[32][64];   // [i][m], 16 KB
    int tid = threadIdx.x;
    int m   = tid & 63;
    int b   = tid >> 6;
    int corner = blockIdx.y;
    int moff0  = blockIdx.x * 64;
    const float* wsrc = (corner==0 ? w1 : corner==1 ? w2 : corner==2 ? w3 : w4)
                        + (size_t)layer * 3538944;   // 32*32*1728*2
    int moff = moff0 + m;
    int m1  = moff / 144;
    int rem = moff - m1 * 144;
    int kx  = m1 + ((corner == 1 || corner == 3) ? 12 : 0);
    int mode_g = kx * 288 + rem + ((corner >= 2) ? 144 : 0);

    float xr[32], xi[32];
    const float2* xp = X3 + (size_t)b * 32 * 6912 + mode_g;
    #pragma unroll
    for (int i = 0; i < 32; ++i){
        float2 a = xp[(size_t)i * 6912];
        xr[i] = a.x; xi[i] = a.y;
    }
    for (int o = 0; o < 32; ++o){
        __syncthreads();
        for (int j = tid; j < 2048; j += 256){
            int i = j >> 6, mm = j & 63;
            const float* p = wsrc + ((size_t)(i*32 + o) * 1728 + moff0 + mm) * 2;
            wlds[i][mm] = make_float2(p[0], p[1]);
        }
        __syncthreads();
        float re = 0.f, im = 0.f;
        #pragma unroll
        for (int i = 0; i < 32; ++i){
            float2 wv = wlds[i][m];
            re += xr[i]*wv.x - xi[i]*wv.y;
            im += xr[i]*wv.y + xi[i]*wv.x;
        }
        Y[(size_t)(b*32 + o) * 6912 + mode_g] = make_float2(re, im);
    }
}

// ---------------- inverse over s: Y[bo][kx][ky][kz] -> Z1[bo][kz][s][ky] ---
__global__ __launch_bounds__(256) void k_invS(
    const float2* __restrict__ Y, float2* __restrict__ Z1)
{
    __shared__ float2 yin[24][24];
    __shared__ float ctab[64], stab[64];
    int tid = threadIdx.x;
    TWIDDLE_INIT(ctab, stab)
    int bo = blockIdx.x / 12;
    int kz = blockIdx.x % 12;
    for (int i = tid; i < 576; i += 256){
        int kx = i / 24, ky = i % 24;
        yin[kx][ky] = Y[(size_t)bo * 6912 + (size_t)kx * 288 + ky * 12 + kz];
    }
    __syncthreads();
    int s = tid & 63;
    int kyg = tid >> 6;   // 0..3 -> 6 ky each
    float re[6] = {0,0,0,0,0,0}, im[6] = {0,0,0,0,0,0};
    for (int kxi = 0; kxi < 24; ++kxi){
        int kxa = (kxi < 12) ? kxi : kxi + 40;
        int m = (kxa * s) & 63;
        float cw = ctab[m], sw = stab[m];     // e^{+i theta}
        #pragma unroll
        for (int j = 0; j < 6; ++j){
            float2 a = yin[kxi][kyg*6 + j];
            re[j] += a.x * cw - a.y * sw;
            im[j] += a.x * sw + a.y * cw;
        }
    }
    #pragma unroll
    for (int j = 0; j < 6; ++j){
        int ky = kyg*6 + j;
        Z1[((size_t)(bo*12 + kz) * 64 + s) * 24 + ky] = make_float2(re[j], im[j]);
    }
}

// ---------------- pointwise conv IN-PLACE: x[b,:,p] <- W x[b,:,p] + b ------
__global__ __launch_bounds__(256) void k_conv(
    float* x, const float* __restrict__ cw,
    const float* __restrict__ cb, int layer)
{
    __shared__ float wsh[32][32];   // [o][i]
    __shared__ float bsh[32];
    int tid = threadIdx.x;
    if (tid < 32) bsh[tid] = cb[layer*32 + tid];
    for (int i = tid; i < 1024; i += 256) wsh[i >> 5][i & 31] = cw[layer*1024 + i];
    __syncthreads();
    size_t g = (size_t)blockIdx.x * 256 + tid;
    int b = (int)(g >> 18);
    size_t p = g & (size_t)(SVT - 1);
    float acc[32];
    #pragma unroll
    for (int o = 0; o < 32; ++o) acc[o] = bsh[o];
    for (int i = 0; i < 32; ++i){
        float xv = x[(size_t)(b*32 + i) * SVT + p];
        #pragma unroll
        for (int o = 0; o < 32; ++o) acc[o] += xv * wsh[o][i];
    }
    #pragma unroll
    for (int o = 0; o < 32; ++o) x[(size_t)(b*32 + o) * SVT + p] = acc[o];
}

// -- fused inverse over v then t (+ gelu(x1+x2)): Z1 -> xio = gelu(x1+xio) --
__global__ __launch_bounds__(256) void k_invVT(
    const float2* __restrict__ Z1, float* xio)
{
    __shared__ float2 zin[12][24];
    __shared__ float cre[12][65], cim[12][65];
    __shared__ float ctab[64], stab[64];
    int tid = threadIdx.x;
    int bo = blockIdx.x >> 6;
    int s  = blockIdx.x & 63;
    TWIDDLE_INIT(ctab, stab)
    // Z1 layout: [bo][kz][s][ky]
    for (int i = tid; i < 288; i += 256){
        int kz = i / 24, ky = i % 24;
        zin[kz][ky] = Z1[((size_t)(bo*12 + kz) * 64 + s) * 24 + ky];
    }
    __syncthreads();
    // stage 1: inverse DFT over ky -> c[kz][v]
    #pragma unroll
    for (int j = 0; j < 3; ++j){
        int task = tid + j * 256;        // < 768
        int v = task & 63, kz = task >> 6;
        float re = 0.f, im = 0.f;
        #pragma unroll
        for (int ky = 0; ky < 24; ++ky){
            int kya = (ky < 12) ? ky : ky + 40;
            int m = (kya * v) & 63;
            float cw = ctab[m], sw = stab[m];
            float2 a = zin[kz][ky];
            re += a.x * cw - a.y * sw;
            im += a.x * sw + a.y * cw;
        }
        cre[kz][v] = re; cim[kz][v] = im;
    }
    __syncthreads();
    // stage 2: real inverse over kz, combine with conv-out (in xio), gelu
    int v  = tid & 63;
    int tb = (tid >> 6) << 4;   // 0,16,32,48
    float sum[16];
    #pragma unroll
    for (int j = 0; j < 16; ++j) sum[j] = 0.f;
    float dc = cre[0][v];
    #pragma unroll
    for (int kz = 1; kz < 12; ++kz){
        float ar = cre[kz][v], ai = cim[kz][v];
        #pragma unroll
        for (int j = 0; j < 16; ++j){
            int m = (kz * (tb + j)) & 63;
            sum[j] += ar * ctab[m] - ai * stab[m];
        }
    }
    const float norm = 1.0f / 262144.0f;
    size_t base = (size_t)bo * SVT + (size_t)s * VT + (size_t)v * 64 + tb;
    #pragma unroll
    for (int j = 0; j < 16; j += 4){
        float4 xv = *(const float4*)&xio[base + j];
        float4 r;
        r.x = gelu_f((dc + 2.f*sum[j+0]) * norm + xv.x);
        r.y = gelu_f((dc + 2.f*sum[j+1]) * norm + xv.y);
        r.z = gelu_f((dc + 2.f*sum[j+2]) * norm + xv.z);
        r.w = gelu_f((dc + 2.f*sum[j+3]) * norm + xv.w);
        *(float4*)&xio[base + j] = r;
    }
}

// ---------------- fused skip MLP via MFMA (bf16 in / fp32 acc) -------------
// block: 256 thr = 4 waves, 128 points. wave w owns rows [32w, 32w+32).
// weights pre-converted bf16 (k_prep); B-fragments read from global (L2-hot).
__global__ __launch_bounds__(256) void k_skip(
    const float* __restrict__ coords, const float* __restrict__ params,
    const unsigned short* __restrict__ w1bf, const float* __restrict__ s1b,
    const unsigned short* __restrict__ w2bf, const float* __restrict__ s2b,
    const unsigned short* __restrict__ w3bf, const float* __restrict__ s3b,
    int layer, float* __restrict__ xio)
{
    __shared__ __align__(16) unsigned short A1[128][136];   // h1 then h2 (bf16)
    __shared__ unsigned short w1s[9][128];
    __shared__ float pb[128];
    __shared__ float b2s[128];
    __shared__ float b3s[32];

    int tid = threadIdx.x;
    size_t g0 = (size_t)blockIdx.x * 128;
    int b = (int)(g0 >> 18);
    const unsigned short* w2g = w2bf + (size_t)layer * 16384;   // [c][k]
    const unsigned short* w3g = w3bf + (size_t)layer * 4096;    // [c2][k]

    for (int i = tid; i < 1152; i += 256) w1s[i >> 7][i & 127] = w1bf[layer*1152 + i];
    if (tid < 128) b2s[tid] = s2b[layer*128 + tid];
    if (tid < 32)  b3s[tid] = s3b[layer*32  + tid];
    __syncthreads();
    if (tid < 128){
        float acc = s1b[layer*128 + tid];
        #pragma unroll
        for (int j = 0; j < 6; ++j) acc += params[b*6 + j] * bf2f(w1s[3 + j][tid]);
        pb[tid] = acc;
    }
    __syncthreads();

    // ---- phase B: h1 = gelu(coords@w1 + pb) -> A1 (bf16), wave-local rows --
    {
        int p  = tid >> 1;
        int hb = (tid & 1) << 6;
        size_t g = g0 + p;
        float z0 = coords[g*3+0], z1 = coords[g*3+1], z2 = coords[g*3+2];
        #pragma unroll
        for (int gq = 0; gq < 8; ++gq){
            bf16x8 pk;
            #pragma unroll
            for (int j = 0; j < 8; ++j){
                int hh = hb + gq*8 + j;
                float a = pb[hh] + z0*bf2f(w1s[0][hh]) + z1*bf2f(w1s[1][hh])
                                 + z2*bf2f(w1s[2][hh]);
                pk[j] = (short)f2bf(gelu_f(a));
            }
            *(bf16x8*)&A1[p][hb + gq*8] = pk;
        }
    }
    // no barrier: wave reads only rows its own lanes wrote

    int l  = tid & 63;
    int w  = tid >> 6;
    int r0 = w << 5;
    int lr = l & 15;
    int kg = l >> 4;

    // ---- phase C: h2 = gelu(h1 @ w2 + b2)  (MFMA, B from global) ----------
    {
        f32x4 acc[2][8];
        #pragma unroll
        for (int m = 0; m < 2; ++m)
            #pragma unroll
            for (int n = 0; n < 8; ++n) acc[m][n] = (f32x4){0.f,0.f,0.f,0.f};
        #pragma unroll
        for (int kc = 0; kc < 4; ++kc){
            int ko = kc*32 + kg*8;
            bf16x8 a0 = *(const bf16x8*)&A1[r0 + lr     ][ko];
            bf16x8 a1 = *(const bf16x8*)&A1[r0 + 16 + lr][ko];
            #pragma unroll
            for (int n = 0; n < 8; ++n){
                bf16x8 bb = *(const bf16x8*)&w2g[(n*16 + lr)*128 + ko];
                acc[0][n] = __builtin_amdgcn_mfma_f32_16x16x32_bf16(a0, bb, acc[0][n], 0, 0, 0);
                acc[1][n] = __builtin_amdgcn_mfma_f32_16x16x32_bf16(a1, bb, acc[1][n], 0, 0, 0);
            }
        }
        #pragma unroll
        for (int m = 0; m < 2; ++m)
            #pragma unroll
            for (int n = 0; n < 8; ++n){
                int col = n*16 + lr;
                float bv = b2s[col];
                #pragma unroll
                for (int r = 0; r < 4; ++r){
                    int row = r0 + m*16 + kg*4 + r;
                    A1[row][col] = f2bf(gelu_f(acc[m][n][r] + bv));
                }
            }
    }

    // ---- phase D: out = h2 @ w3 + b3 (MFMA, B from global) ----------------
    f32x4 c3[2][2];
    #pragma unroll
    for (int m = 0; m < 2; ++m)
        #pragma unroll
        for (int n = 0; n < 2; ++n) c3[m][n] = (f32x4){0.f,0.f,0.f,0.f};
    #pragma unroll
    for (int kc = 0; kc < 4; ++kc){
        int ko = kc*32 + kg*8;
        bf16x8 a0 = *(const bf16x8*)&A1[r0 + lr     ][ko];
        bf16x8 a1 = *(const bf16x8*)&A1[r0 + 16 + lr][ko];
        bf16x8 b0 = *(const bf16x8*)&w3g[(lr     )*128 + ko];
        bf16x8 b1 = *(const bf16x8*)&w3g[(16 + lr)*128 + ko];
        c3[0][0] = __builtin_amdgcn_mfma_f32_16x16x32_bf16(a0, b0, c3[0][0], 0, 0, 0);
        c3[0][1] = __builtin_amdgcn_mfma_f32_16x16x32_bf16(a0, b1, c3[0][1], 0, 0, 0);
        c3[1][0] = __builtin_amdgcn_mfma_f32_16x16x32_bf16(a1, b0, c3[1][0], 0, 0, 0);
        c3[1][1] = __builtin_amdgcn_mfma_f32_16x16x32_bf16(a1, b1, c3[1][1], 0, 0, 0);
    }
    __syncthreads();   // all phase-D reads of A1 done -> safe to overlay outsT

    float* outsT = (float*)&A1[0][0];    // [32][132] fp32, transposed
    #pragma unroll
    for (int m = 0; m < 2; ++m)
        #pragma unroll
        for (int n = 0; n < 2; ++n){
            int c2 = n*16 + lr;
            int rowb = r0 + m*16 + kg*4;
            float bv = b3s[c2];
            float4 v4;
            v4.x = c3[m][n][0] + bv;
            v4.y = c3[m][n][1] + bv;
            v4.z = c3[m][n][2] + bv;
            v4.w = c3[m][n][3] + bv;
            *(float4*)&outsT[c2*132 + rowb] = v4;
        }
    __syncthreads();

    // ---- global rmw: xio[(b,c), g0 + p] += outsT[c][p], coalesced ---------
    {
        int c  = tid >> 3;        // 0..31
        int pg = tid & 7;         // 16 points each
        size_t prel = (g0 & (size_t)(SVT - 1)) + (size_t)pg*16;
        float* gp = xio + (((size_t)(b*32 + c)) << 18) + prel;
        const float* op = &outsT[c*132 + pg*16];
        #pragma unroll
        for (int i = 0; i < 16; i += 4){
            float4 xv = *(const float4*)&gp[i];
            float4 ov = *(const float4*)&op[i];
            xv.x += ov.x; xv.y += ov.y; xv.z += ov.z; xv.w += ov.w;
            *(float4*)&gp[i] = xv;
        }
    }
}

// ---------------- projection head --------------------------------------
__global__ __launch_bounds__(256) void k_proj(
    const float* __restrict__ x, const float* __restrict__ p1w,
    const float* __restrict__ p1b, const float* __restrict__ p2w,
    const float* __restrict__ p2b, float* __restrict__ out)
{
    __shared__ float w1s[32][16];
    __shared__ float b1s[16];
    __shared__ float w2s[16];
    int tid = threadIdx.x;
    for (int i = tid; i < 512; i += 256) w1s[i >> 4][i & 15] = p1w[i];
    if (tid < 16){ b1s[tid] = p1b[tid]; w2s[tid] = p2w[tid]; }
    __syncthreads();
    size_t g = (size_t)blockIdx.x * 256 + tid;
    int b = (int)(g >> 18);
    size_t p = g & (size_t)(SVT - 1);
    float h[16];
    #pragma unroll
    for (int j = 0; j < 16; ++j) h[j] = b1s[j];
    for (int c = 0; c < 32; ++c){
        float xv = x[(size_t)(b*32 + c) * SVT + p];
        #pragma unroll
        for (int j = 0; j < 16; ++j) h[j] += xv * w1s[c][j];
    }
    float acc = p2b[0];
    #pragma unroll
    for (int j = 0; j < 16; ++j) acc += gelu_f(h[j]) * w2s[j];
    out[g] = acc;
}

extern "C" void kernel_launch(void* const* d_in, const int* in_sizes, int n_in,
                              void* d_out, int out_size, void* d_ws, size_t ws_size,
                              hipStream_t stream)
{
    (void)in_sizes; (void)n_in; (void)out_size; (void)ws_size;
    const float* coords = (const float*)d_in[0];
    const float* params = (const float*)d_in[1];
    const float* lift_w = (const float*)d_in[2];
    const float* lift_b = (const float*)d_in[3];
    const float* sw1    = (const float*)d_in[4];
    const float* sw2    = (const float*)d_in[5];
    const float* sw3    = (const float*)d_in[6];
    const float* sw4    = (const float*)d_in[7];
    const float* conv_w = (const float*)d_in[8];
    const float* conv_b = (const float*)d_in[9];
    const float* s1w    = (const float*)d_in[10];
    const float* s1b    = (const float*)d_in[11];
    const float* s2w    = (const float*)d_in[12];
    const float* s2b    = (const float*)d_in[13];
    const float* s3w    = (const float*)d_in[14];
    const float* s3b    = (const float*)d_in[15];
    const float* p1w    = (const float*)d_in[16];
    const float* p1b    = (const float*)d_in[17];
    const float* p2w    = (const float*)d_in[18];
    const float* p2b    = (const float*)d_in[19];
    float* out = (float*)d_out;

    char* ws = (char*)d_ws;
    float*  xA = (float*)(ws);                                  // 134,217,728
    float2* X2 = (float2*)(ws + 134217728ull);                  //  18,874,368 (also Z1)
    float2* X3 = (float2*)(ws + 153092096ull);                  //   7,077,888
    float2* Yb = (float2*)(ws + 160169984ull);                  //   7,077,888
    unsigned short* w2bf = (unsigned short*)(ws + 167247872ull);//     131,072
    unsigned short* w3bf = (unsigned short*)(ws + 167378944ull);//      32,768
    unsigned short* w1bf = (unsigned short*)(ws + 167411712ull);//       9,216
    // total 167,420,928 B

    k_prep<<<338, 256, 0, stream>>>(s1w, s2w, s3w, w1bf, w2bf, w3bf);
    k_lift<<<4096, 256, 0, stream>>>(coords, params, lift_w, lift_b, xA);

    for (int l = 0; l < NLAY; ++l){
        k_fwdTV<<<8192, 256, 0, stream>>>(xA, X2);
        k_fwdS<<<1152, 256, 0, stream>>>(X2, X3);
        dim3 gmm(27, 4);
        k_modemix<<<gmm, 256, 0, stream>>>(X3, sw1, sw2, sw3, sw4, l, Yb);
        k_invS<<<1536, 256, 0, stream>>>(Yb, X2);          // Z1 overlays X2
        k_conv<<<4096, 256, 0, stream>>>(xA, conv_w, conv_b, l);   // in place
        k_invVT<<<8192, 256, 0, stream>>>(X2, xA);         // xA = gelu(x1 + x2)
        k_skip<<<8192, 256, 0, stream>>>(coords, params, w1bf, s1b, w2bf, s2b,
                                         w3bf, s3b, l, xA);
    }

    k_proj<<<4096, 256, 0, stream>>>(xA, p1w, p1b, p2w, p2b, out);
}

// Round 5
// 2143.987 us; speedup vs baseline: 3.0184x; 1.8001x over previous
//
#include <hip/hip_runtime.h>
#include <hip/hip_bf16.h>
#include <math.h>

#define NB   4
#define NC   32
#define SVT  262144      // 64^3
#define VT   4096        // 64*64
#define NLAY 4
#define TWOPI_64 0.09817477042468103f

typedef __attribute__((ext_vector_type(8))) short bf16x8;
typedef __attribute__((ext_vector_type(4))) float f32x4;

// tanh-form GELU via hw exp2/rcp: x * sigmoid(1.5957691(x + 0.044715 x^3))
// |err| vs exact erf-GELU < ~2.5e-4; correct +-inf saturation.
__device__ __forceinline__ float gelu_f(float x){
    float x2 = x * x;
    float u  = x * __builtin_fmaf(-0.10294322f, x2, -2.30220795f);
    float e  = __builtin_amdgcn_exp2f(u);
    return x * __builtin_amdgcn_rcpf(1.0f + e);
}

__device__ __forceinline__ unsigned short f2bf(float f){
    union { __hip_bfloat16 h; unsigned short u; } cv;
    cv.h = __float2bfloat16(f);
    return cv.u;
}
__device__ __forceinline__ float bf2f(unsigned short u){
    return __uint_as_float(((unsigned int)u) << 16);
}

// ---------------- weight prep: fp32 -> bf16 (transposed) + twiddle tables --
__global__ __launch_bounds__(256) void k_prep(
    const float* __restrict__ s1w, const float* __restrict__ s2w,
    const float* __restrict__ s3w,
    unsigned short* __restrict__ w1bf,   // [4][9][128]
    unsigned short* __restrict__ w2bf,   // [4][c 128][k 128]
    unsigned short* __restrict__ w3bf,   // [4][c2 32][k 128]
    unsigned short* __restrict__ tdft)   // [2(hi,lo)][32 o][64 t]
{
    int g = blockIdx.x * 256 + threadIdx.x;
    if (g < 65536){
        int l = g >> 14, r = g & 16383;
        int c = r >> 7, k = r & 127;
        w2bf[g] = f2bf(s2w[l*16384 + k*128 + c]);
        return;
    }
    int g3 = g - 65536;
    if (g3 < 16384){
        int l = g3 >> 12, r = g3 & 4095;
        int c2 = r >> 7, k = r & 127;
        w3bf[g3] = f2bf(s3w[l*4096 + k*32 + c2]);
        return;
    }
    int g1 = g3 - 16384;
    if (g1 < 4608){ w1bf[g1] = f2bf(s1w[g1]); return; }
    int g4 = g1 - 4608;
    if (g4 < 2048){
        int o = g4 >> 6, t = g4 & 63;
        float val = 0.f;
        if (o < 24){
            int kz = o >> 1;
            float ang = (float)((kz * t) & 63) * TWOPI_64;
            float sn, cs; sincosf(ang, &sn, &cs);
            val = (o & 1) ? -sn : cs;      // forward DFT: e^{-i theta}
        }
        unsigned short h = f2bf(val);
        tdft[g4]        = h;
        tdft[2048 + g4] = f2bf(val - bf2f(h));
    }
}

// ---------------- lift: x = z @ lift_w + lift_b, layout [B,C,S,V,T] -------
__global__ __launch_bounds__(256) void k_lift(
    const float* __restrict__ coords, const float* __restrict__ params,
    const float* __restrict__ lw, const float* __restrict__ lb,
    float* __restrict__ x)
{
    size_t g = (size_t)blockIdx.x * 256 + threadIdx.x;   // 0..1048575
    int b = (int)(g >> 18);
    size_t p = g & (size_t)(SVT - 1);
    float z[9];
    z[0] = coords[g*3+0]; z[1] = coords[g*3+1]; z[2] = coords[g*3+2];
    #pragma unroll
    for (int j = 0; j < 6; ++j) z[3+j] = params[b*6+j];
    #pragma unroll
    for (int c = 0; c < 32; ++c){
        float acc = lb[c];
        #pragma unroll
        for (int j = 0; j < 9; ++j) acc += z[j] * lw[j*32 + c];
        x[(size_t)(b*32 + c) * SVT + p] = acc;
    }
}

// ------- fused forward DFT t (MFMA split-bf16) then v: x -> X2[bc][kz][ky][s]
__global__ __launch_bounds__(256) void k_fwdTV(
    const float* __restrict__ x, const unsigned short* __restrict__ tdft,
    float2* __restrict__ X2)
{
    __shared__ __align__(16) unsigned short Ahi[64][72], Alo[64][72];
    __shared__ __align__(16) unsigned short Bhi[32][72], Blo[32][72];
    __shared__ float2 a2[12][66];
    __shared__ float2 wtab[64];
    int tid = threadIdx.x;
    int bc = blockIdx.x >> 6;
    int s  = blockIdx.x & 63;
    if (tid < 64){
        float sn, cs;
        sincosf((float)tid * TWOPI_64, &sn, &cs);
        wtab[tid] = make_float2(cs, sn);
    }
    for (int i = tid; i < 2048; i += 256){
        int o = i >> 6, t = i & 63;
        Bhi[o][t] = tdft[i];
        Blo[o][t] = tdft[2048 + i];
    }
    // stage x -> hi/lo bf16; wave-local rows (wave w writes rows 16w..16w+15)
    {
        int row = tid >> 2, c0 = (tid & 3) << 4;
        const float* src = x + (size_t)bc * SVT + (size_t)s * VT + row*64 + c0;
        #pragma unroll
        for (int q = 0; q < 4; ++q){
            float4 v4 = *(const float4*)&src[q*4];
            float vv[4] = {v4.x, v4.y, v4.z, v4.w};
            #pragma unroll
            for (int e = 0; e < 4; ++e){
                unsigned short h = f2bf(vv[e]);
                Ahi[row][c0 + q*4 + e] = h;
                Alo[row][c0 + q*4 + e] = f2bf(vv[e] - bf2f(h));
            }
        }
    }
    __syncthreads();
    // stage 1: wave w computes v-rows 16w..16w+15, 24 outputs (kz x re/im)
    int l = tid & 63, w = tid >> 6;
    int lr = l & 15, kg = l >> 4;
    int r0 = w << 4;
    f32x4 acc[2];
    acc[0] = (f32x4){0.f,0.f,0.f,0.f}; acc[1] = (f32x4){0.f,0.f,0.f,0.f};
    #pragma unroll
    for (int kc = 0; kc < 2; ++kc){
        int ko = kc*32 + kg*8;
        bf16x8 ah = *(const bf16x8*)&Ahi[r0 + lr][ko];
        bf16x8 al = *(const bf16x8*)&Alo[r0 + lr][ko];
        #pragma unroll
        for (int n = 0; n < 2; ++n){
            bf16x8 bh = *(const bf16x8*)&Bhi[n*16 + lr][ko];
            bf16x8 bl = *(const bf16x8*)&Blo[n*16 + lr][ko];
            acc[n] = __builtin_amdgcn_mfma_f32_16x16x32_bf16(ah, bh, acc[n], 0, 0, 0);
            acc[n] = __builtin_amdgcn_mfma_f32_16x16x32_bf16(ah, bl, acc[n], 0, 0, 0);
            acc[n] = __builtin_amdgcn_mfma_f32_16x16x32_bf16(al, bh, acc[n], 0, 0, 0);
        }
    }
    #pragma unroll
    for (int n = 0; n < 2; ++n){
        int o = n*16 + lr;
        if (o < 24){
            int kz = o >> 1;
            #pragma unroll
            for (int r = 0; r < 4; ++r){
                int v = r0 + kg*4 + r;
                if (o & 1) a2[kz][v].y = acc[n][r];
                else       a2[kz][v].x = acc[n][r];
            }
        }
    }
    __syncthreads();
    // stage 2: DFT over v -> X2[bc][kz][ky][s]
    for (int task = tid; task < 288; task += 256){
        int kz = task % 12;
        int ky = task / 12;
        int kya = (ky < 12) ? ky : ky + 40;
        float re = 0.f, im = 0.f;
        for (int v = 0; v < 64; ++v){
            float2 wv = wtab[(kya * v) & 63];
            float2 a  = a2[kz][v];
            re += a.x * wv.x + a.y * wv.y;
            im += a.y * wv.x - a.x * wv.y;
        }
        X2[((size_t)(bc*12 + kz) * 24 + ky) * 64 + s] = make_float2(re, im);
    }
}

// ---------------- forward DFT over s: X2[bc][kz][ky][s] -> X3[bc][kx][ky][kz]
__global__ __launch_bounds__(256) void k_fwdS(
    const float2* __restrict__ X2, float2* __restrict__ X3)
{
    __shared__ float2 cin[32][65];
    __shared__ float2 wtab[64];
    int tid = threadIdx.x;
    if (tid < 64){
        float sn, cs; sincosf((float)tid * TWOPI_64, &sn, &cs);
        wtab[tid] = make_float2(cs, sn);
    }
    int rbase = blockIdx.x * 32;   // rows (bc,kz,ky), 36864 total
    for (int i = tid; i < 2048; i += 256){
        int row = i >> 6, s = i & 63;
        cin[row][s] = X2[(size_t)(rbase + row) * 64 + s];
    }
    __syncthreads();
    int row = tid & 31;
    int r = rbase + row;
    int kxg = tid >> 5;       // 0..7 -> 3 kx each
    int kxs[3];
    #pragma unroll
    for (int j = 0; j < 3; ++j){ int kxi = kxg*3 + j; kxs[j] = (kxi < 12) ? kxi : kxi + 40; }
    float re[3] = {0,0,0}, im[3] = {0,0,0};
    for (int s = 0; s < 64; ++s){
        float2 cv = cin[row][s];
        #pragma unroll
        for (int j = 0; j < 3; ++j){
            float2 wv = wtab[(kxs[j] * s) & 63];
            re[j] += cv.x * wv.x + cv.y * wv.y;
            im[j] += cv.y * wv.x - cv.x * wv.y;
        }
    }
    int bc = r / 288; int kz = (r / 24) % 12; int ky = r % 24;
    #pragma unroll
    for (int j = 0; j < 3; ++j){
        int kxi = kxg*3 + j;
        X3[(size_t)bc * 6912 + (size_t)kxi * 288 + ky * 12 + kz] = make_float2(re[j], im[j]);
    }
}

// --------- per-mode channel mixing: coalesced W, X3 in regs, 4 o per block -
__global__ __launch_bounds__(256) void k_modemix(
    const float2* __restrict__ X3,
    const float* __restrict__ w1, const float* __restrict__ w2,
    const float* __restrict__ w3, const float* __restrict__ w4,
    int layer, float2* __restrict__ Y)
{
    __shared__ float2 wlds[32][64];   // [i][m], 16 KB
    int tid = threadIdx.x;
    int m   = tid & 63;
    int b   = tid >> 6;
    int corner = blockIdx.y >> 3;
    int o0     = (blockIdx.y & 7) * 4;
    int moff0  = blockIdx.x * 64;
    const float* wsrc = (corner==0 ? w1 : corner==1 ? w2 : corner==2 ? w3 : w4)
                        + (size_t)layer * 3538944;   // 32*32*1728*2
    int moff = moff0 + m;
    int m1  = moff / 144;
    int rem = moff - m1 * 144;
    int kx  = m1 + ((corner == 1 || corner == 3) ? 12 : 0);
    int mode_g = kx * 288 + rem + ((corner >= 2) ? 144 : 0);

    float xr[32], xi[32];
    const float2* xp = X3 + (size_t)b * 32 * 6912 + mode_g;
    #pragma unroll
    for (int i = 0; i < 32; ++i){
        float2 a = xp[(size_t)i * 6912];
        xr[i] = a.x; xi[i] = a.y;
    }
    for (int oo = 0; oo < 4; ++oo){
        int o = o0 + oo;
        __syncthreads();
        for (int j = tid; j < 2048; j += 256){
            int i = j >> 6, mm = j & 63;
            wlds[i][mm] = *(const float2*)&wsrc[((size_t)(i*32 + o) * 1728 + moff0 + mm) * 2];
        }
        __syncthreads();
        float re = 0.f, im = 0.f;
        #pragma unroll
        for (int i = 0; i < 32; ++i){
            float2 wv = wlds[i][m];
            re += xr[i]*wv.x - xi[i]*wv.y;
            im += xr[i]*wv.y + xi[i]*wv.x;
        }
        Y[(size_t)(b*32 + o) * 6912 + mode_g] = make_float2(re, im);
    }
}

// ---------------- inverse over s: Y[bo][kx][ky][kz] -> Z1[bo][kz][s][ky] ---
__global__ __launch_bounds__(256) void k_invS(
    const float2* __restrict__ Y, float2* __restrict__ Z1)
{
    __shared__ float2 yin[24][24];
    __shared__ float2 wtab[64];
    int tid = threadIdx.x;
    if (tid < 64){
        float sn, cs; sincosf((float)tid * TWOPI_64, &sn, &cs);
        wtab[tid] = make_float2(cs, sn);
    }
    int bo = blockIdx.x / 12;
    int kz = blockIdx.x % 12;
    for (int i = tid; i < 576; i += 256){
        int kx = i / 24, ky = i % 24;
        yin[kx][ky] = Y[(size_t)bo * 6912 + (size_t)kx * 288 + ky * 12 + kz];
    }
    __syncthreads();
    int s = tid & 63;
    int kyg = tid >> 6;   // 0..3 -> 6 ky each
    float re[6] = {0,0,0,0,0,0}, im[6] = {0,0,0,0,0,0};
    for (int kxi = 0; kxi < 24; ++kxi){
        int kxa = (kxi < 12) ? kxi : kxi + 40;
        float2 wv = wtab[(kxa * s) & 63];     // e^{+i theta}
        #pragma unroll
        for (int j = 0; j < 6; ++j){
            float2 a = yin[kxi][kyg*6 + j];
            re[j] += a.x * wv.x - a.y * wv.y;
            im[j] += a.x * wv.y + a.y * wv.x;
        }
    }
    #pragma unroll
    for (int j = 0; j < 6; ++j){
        int ky = kyg*6 + j;
        Z1[((size_t)(bo*12 + kz) * 64 + s) * 24 + ky] = make_float2(re[j], im[j]);
    }
}

// ---------------- pointwise conv IN-PLACE: x[b,:,p] <- W x[b,:,p] + b ------
__global__ __launch_bounds__(256) void k_conv(
    float* x, const float* __restrict__ cw,
    const float* __restrict__ cb, int layer)
{
    __shared__ float wsh[32][32];   // [o][i]
    __shared__ float bsh[32];
    int tid = threadIdx.x;
    if (tid < 32) bsh[tid] = cb[layer*32 + tid];
    for (int i = tid; i < 1024; i += 256) wsh[i >> 5][i & 31] = cw[layer*1024 + i];
    __syncthreads();
    size_t g = (size_t)blockIdx.x * 256 + tid;
    int b = (int)(g >> 18);
    size_t p = g & (size_t)(SVT - 1);
    float acc[32];
    #pragma unroll
    for (int o = 0; o < 32; ++o) acc[o] = bsh[o];
    for (int i = 0; i < 32; ++i){
        float xv = x[(size_t)(b*32 + i) * SVT + p];
        #pragma unroll
        for (int o = 0; o < 32; ++o) acc[o] += xv * wsh[o][i];
    }
    #pragma unroll
    for (int o = 0; o < 32; ++o) x[(size_t)(b*32 + o) * SVT + p] = acc[o];
}

// -- fused inverse over v then t (+ gelu(x1+x2)): Z1 -> xio = gelu(x1+xio) --
__global__ __launch_bounds__(256) void k_invVT(
    const float2* __restrict__ Z1, float* xio)
{
    __shared__ float2 zin[12][24];
    __shared__ float2 c2[12][66];
    __shared__ float2 wtab[64];
    int tid = threadIdx.x;
    int bo = blockIdx.x >> 6;
    int s  = blockIdx.x & 63;
    if (tid < 64){
        float sn, cs; sincosf((float)tid * TWOPI_64, &sn, &cs);
        wtab[tid] = make_float2(cs, sn);
    }
    for (int i = tid; i < 288; i += 256){
        int kz = i / 24, ky = i % 24;
        zin[kz][ky] = Z1[((size_t)(bo*12 + kz) * 64 + s) * 24 + ky];
    }
    __syncthreads();
    // stage 1: inverse DFT over ky -> c2[kz][v]
    #pragma unroll
    for (int j = 0; j < 3; ++j){
        int task = tid + j * 256;        // < 768
        int v = task & 63, kz = task >> 6;
        float re = 0.f, im = 0.f;
        #pragma unroll
        for (int ky = 0; ky < 24; ++ky){
            int kya = (ky < 12) ? ky : ky + 40;
            float2 wv = wtab[(kya * v) & 63];
            float2 a = zin[kz][ky];
            re += a.x * wv.x - a.y * wv.y;
            im += a.x * wv.y + a.y * wv.x;
        }
        c2[kz][v] = make_float2(re, im);
    }
    __syncthreads();
    // stage 2: real inverse over kz, combine with conv-out (in xio), gelu
    int v  = tid & 63;
    int tb = (tid >> 6) << 4;   // 0,16,32,48
    float sum[16];
    #pragma unroll
    for (int j = 0; j < 16; ++j) sum[j] = 0.f;
    float dc = c2[0][v].x;
    #pragma unroll
    for (int kz = 1; kz < 12; ++kz){
        float2 a = c2[kz][v];
        #pragma unroll
        for (int j = 0; j < 16; ++j){
            float2 wv = wtab[(kz * (tb + j)) & 63];
            sum[j] += a.x * wv.x - a.y * wv.y;
        }
    }
    const float norm = 1.0f / 262144.0f;
    size_t base = (size_t)bo * SVT + (size_t)s * VT + (size_t)v * 64 + tb;
    #pragma unroll
    for (int j = 0; j < 16; j += 4){
        float4 xv = *(const float4*)&xio[base + j];
        float4 r;
        r.x = gelu_f((dc + 2.f*sum[j+0]) * norm + xv.x);
        r.y = gelu_f((dc + 2.f*sum[j+1]) * norm + xv.y);
        r.z = gelu_f((dc + 2.f*sum[j+2]) * norm + xv.z);
        r.w = gelu_f((dc + 2.f*sum[j+3]) * norm + xv.w);
        *(float4*)&xio[base + j] = r;
    }
}

// ---------------- fused skip MLP via MFMA (bf16 in / fp32 acc) -------------
__global__ __launch_bounds__(256) void k_skip(
    const float* __restrict__ coords, const float* __restrict__ params,
    const unsigned short* __restrict__ w1bf, const float* __restrict__ s1b,
    const unsigned short* __restrict__ w2bf, const float* __restrict__ s2b,
    const unsigned short* __restrict__ w3bf, const float* __restrict__ s3b,
    int layer, float* __restrict__ xio)
{
    __shared__ __align__(16) unsigned short A1[128][136];   // h1 then h2 (bf16)
    __shared__ unsigned short w1s[9][128];
    __shared__ float pb[128];
    __shared__ float b2s[128];
    __shared__ float b3s[32];

    int tid = threadIdx.x;
    size_t g0 = (size_t)blockIdx.x * 128;
    int b = (int)(g0 >> 18);
    const unsigned short* w2g = w2bf + (size_t)layer * 16384;   // [c][k]
    const unsigned short* w3g = w3bf + (size_t)layer * 4096;    // [c2][k]

    for (int i = tid; i < 1152; i += 256) w1s[i >> 7][i & 127] = w1bf[layer*1152 + i];
    if (tid < 128) b2s[tid] = s2b[layer*128 + tid];
    if (tid < 32)  b3s[tid] = s3b[layer*32  + tid];
    __syncthreads();
    if (tid < 128){
        float acc = s1b[layer*128 + tid];
        #pragma unroll
        for (int j = 0; j < 6; ++j) acc += params[b*6 + j] * bf2f(w1s[3 + j][tid]);
        pb[tid] = acc;
    }
    __syncthreads();

    // ---- phase B: h1 = gelu(coords@w1 + pb) -> A1 (bf16), wave-local rows --
    {
        int p  = tid >> 1;
        int hb = (tid & 1) << 6;
        size_t g = g0 + p;
        float z0 = coords[g*3+0], z1 = coords[g*3+1], z2 = coords[g*3+2];
        #pragma unroll
        for (int gq = 0; gq < 8; ++gq){
            bf16x8 pk;
            #pragma unroll
            for (int j = 0; j < 8; ++j){
                int hh = hb + gq*8 + j;
                float a = pb[hh] + z0*bf2f(w1s[0][hh]) + z1*bf2f(w1s[1][hh])
                                 + z2*bf2f(w1s[2][hh]);
                pk[j] = (short)f2bf(gelu_f(a));
            }
            *(bf16x8*)&A1[p][hb + gq*8] = pk;
        }
    }
    // no barrier: wave reads only rows its own lanes wrote

    int l  = tid & 63;
    int w  = tid >> 6;
    int r0 = w << 5;
    int lr = l & 15;
    int kg = l >> 4;

    // ---- phase C: h2 = gelu(h1 @ w2 + b2)  (MFMA, B from global) ----------
    {
        f32x4 acc[2][8];
        #pragma unroll
        for (int m = 0; m < 2; ++m)
            #pragma unroll
            for (int n = 0; n < 8; ++n) acc[m][n] = (f32x4){0.f,0.f,0.f,0.f};
        #pragma unroll
        for (int kc = 0; kc < 4; ++kc){
            int ko = kc*32 + kg*8;
            bf16x8 a0 = *(const bf16x8*)&A1[r0 + lr     ][ko];
            bf16x8 a1 = *(const bf16x8*)&A1[r0 + 16 + lr][ko];
            #pragma unroll
            for (int n = 0; n < 8; ++n){
                bf16x8 bb = *(const bf16x8*)&w2g[(n*16 + lr)*128 + ko];
                acc[0][n] = __builtin_amdgcn_mfma_f32_16x16x32_bf16(a0, bb, acc[0][n], 0, 0, 0);
                acc[1][n] = __builtin_amdgcn_mfma_f32_16x16x32_bf16(a1, bb, acc[1][n], 0, 0, 0);
            }
        }
        #pragma unroll
        for (int m = 0; m < 2; ++m)
            #pragma unroll
            for (int n = 0; n < 8; ++n){
                int col = n*16 + lr;
                float bv = b2s[col];
                #pragma unroll
                for (int r = 0; r < 4; ++r){
                    int row = r0 + m*16 + kg*4 + r;
                    A1[row][col] = f2bf(gelu_f(acc[m][n][r] + bv));
                }
            }
    }

    // ---- phase D: out = h2 @ w3 + b3 (MFMA, B from global) ----------------
    f32x4 c3[2][2];
    #pragma unroll
    for (int m = 0; m < 2; ++m)
        #pragma unroll
        for (int n = 0; n < 2; ++n) c3[m][n] = (f32x4){0.f,0.f,0.f,0.f};
    #pragma unroll
    for (int kc = 0; kc < 4; ++kc){
        int ko = kc*32 + kg*8;
        bf16x8 a0 = *(const bf16x8*)&A1[r0 + lr     ][ko];
        bf16x8 a1 = *(const bf16x8*)&A1[r0 + 16 + lr][ko];
        bf16x8 b0 = *(const bf16x8*)&w3g[(lr     )*128 + ko];
        bf16x8 b1 = *(const bf16x8*)&w3g[(16 + lr)*128 + ko];
        c3[0][0] = __builtin_amdgcn_mfma_f32_16x16x32_bf16(a0, b0, c3[0][0], 0, 0, 0);
        c3[0][1] = __builtin_amdgcn_mfma_f32_16x16x32_bf16(a0, b1, c3[0][1], 0, 0, 0);
        c3[1][0] = __builtin_amdgcn_mfma_f32_16x16x32_bf16(a1, b0, c3[1][0], 0, 0, 0);
        c3[1][1] = __builtin_amdgcn_mfma_f32_16x16x32_bf16(a1, b1, c3[1][1], 0, 0, 0);
    }
    __syncthreads();   // all phase-D reads of A1 done -> safe to overlay outsT

    float* outsT = (float*)&A1[0][0];    // [32][132] fp32, transposed
    #pragma unroll
    for (int m = 0; m < 2; ++m)
        #pragma unroll
        for (int n = 0; n < 2; ++n){
            int c2 = n*16 + lr;
            int rowb = r0 + m*16 + kg*4;
            float bv = b3s[c2];
            float4 v4;
            v4.x = c3[m][n][0] + bv;
            v4.y = c3[m][n][1] + bv;
            v4.z = c3[m][n][2] + bv;
            v4.w = c3[m][n][3] + bv;
            *(float4*)&outsT[c2*132 + rowb] = v4;
        }
    __syncthreads();

    // ---- global rmw: xio[(b,c), g0 + p] += outsT[c][p], coalesced ---------
    {
        int c  = tid >> 3;        // 0..31
        int pg = tid & 7;         // 16 points each
        size_t prel = (g0 & (size_t)(SVT - 1)) + (size_t)pg*16;
        float* gp = xio + (((size_t)(b*32 + c)) << 18) + prel;
        const float* op = &outsT[c*132 + pg*16];
        #pragma unroll
        for (int i = 0; i < 16; i += 4){
            float4 xv = *(const float4*)&gp[i];
            float4 ov = *(const float4*)&op[i];
            xv.x += ov.x; xv.y += ov.y; xv.z += ov.z; xv.w += ov.w;
            *(float4*)&gp[i] = xv;
        }
    }
}

// ---------------- projection head --------------------------------------
__global__ __launch_bounds__(256) void k_proj(
    const float* __restrict__ x, const float* __restrict__ p1w,
    const float* __restrict__ p1b, const float* __restrict__ p2w,
    const float* __restrict__ p2b, float* __restrict__ out)
{
    __shared__ float w1s[32][16];
    __shared__ float b1s[16];
    __shared__ float w2s[16];
    int tid = threadIdx.x;
    for (int i = tid; i < 512; i += 256) w1s[i >> 4][i & 15] = p1w[i];
    if (tid < 16){ b1s[tid] = p1b[tid]; w2s[tid] = p2w[tid]; }
    __syncthreads();
    size_t g = (size_t)blockIdx.x * 256 + tid;
    int b = (int)(g >> 18);
    size_t p = g & (size_t)(SVT - 1);
    float h[16];
    #pragma unroll
    for (int j = 0; j < 16; ++j) h[j] = b1s[j];
    for (int c = 0; c < 32; ++c){
        float xv = x[(size_t)(b*32 + c) * SVT + p];
        #pragma unroll
        for (int j = 0; j < 16; ++j) h[j] += xv * w1s[c][j];
    }
    float acc = p2b[0];
    #pragma unroll
    for (int j = 0; j < 16; ++j) acc += gelu_f(h[j]) * w2s[j];
    out[g] = acc;
}

extern "C" void kernel_launch(void* const* d_in, const int* in_sizes, int n_in,
                              void* d_out, int out_size, void* d_ws, size_t ws_size,
                              hipStream_t stream)
{
    (void)in_sizes; (void)n_in; (void)out_size; (void)ws_size;
    const float* coords = (const float*)d_in[0];
    const float* params = (const float*)d_in[1];
    const float* lift_w = (const float*)d_in[2];
    const float* lift_b = (const float*)d_in[3];
    const float* sw1    = (const float*)d_in[4];
    const float* sw2    = (const float*)d_in[5];
    const float* sw3    = (const float*)d_in[6];
    const float* sw4    = (const float*)d_in[7];
    const float* conv_w = (const float*)d_in[8];
    const float* conv_b = (const float*)d_in[9];
    const float* s1w    = (const float*)d_in[10];
    const float* s1b    = (const float*)d_in[11];
    const float* s2w    = (const float*)d_in[12];
    const float* s2b    = (const float*)d_in[13];
    const float* s3w    = (const float*)d_in[14];
    const float* s3b    = (const float*)d_in[15];
    const float* p1w    = (const float*)d_in[16];
    const float* p1b    = (const float*)d_in[17];
    const float* p2w    = (const float*)d_in[18];
    const float* p2b    = (const float*)d_in[19];
    float* out = (float*)d_out;

    char* ws = (char*)d_ws;
    float*  xA = (float*)(ws);                                   // 134,217,728
    float2* X2 = (float2*)(ws + 134217728ull);                   //  18,874,368 (also Z1)
    float2* X3 = (float2*)(ws + 153092096ull);                   //   7,077,888
    float2* Yb = (float2*)(ws + 160169984ull);                   //   7,077,888
    unsigned short* w2bf = (unsigned short*)(ws + 167247872ull); //     131,072
    unsigned short* w3bf = (unsigned short*)(ws + 167378944ull); //      32,768
    unsigned short* w1bf = (unsigned short*)(ws + 167411712ull); //       9,216
    unsigned short* tdft = (unsigned short*)(ws + 167420928ull); //       8,192
    // total 167,429,120 B

    k_prep<<<346, 256, 0, stream>>>(s1w, s2w, s3w, w1bf, w2bf, w3bf, tdft);
    k_lift<<<4096, 256, 0, stream>>>(coords, params, lift_w, lift_b, xA);

    for (int l = 0; l < NLAY; ++l){
        k_fwdTV<<<8192, 256, 0, stream>>>(xA, tdft, X2);
        k_fwdS<<<1152, 256, 0, stream>>>(X2, X3);
        dim3 gmm(27, 32);
        k_modemix<<<gmm, 256, 0, stream>>>(X3, sw1, sw2, sw3, sw4, l, Yb);
        k_invS<<<1536, 256, 0, stream>>>(Yb, X2);          // Z1 overlays X2
        k_conv<<<4096, 256, 0, stream>>>(xA, conv_w, conv_b, l);   // in place
        k_invVT<<<8192, 256, 0, stream>>>(X2, xA);         // xA = gelu(x1 + x2)
        k_skip<<<8192, 256, 0, stream>>>(coords, params, w1bf, s1b, w2bf, s2b,
                                         w3bf, s3b, l, xA);
    }

    k_proj<<<4096, 256, 0, stream>>>(xA, p1w, p1b, p2w, p2b, out);
}

// Round 6
// 1841.232 us; speedup vs baseline: 3.5147x; 1.1644x over previous
//
#include <hip/hip_runtime.h>
#include <hip/hip_bf16.h>
#include <math.h>

#define NB   4
#define NC   32
#define SVT  262144      // 64^3
#define VT   4096        // 64*64
#define NLAY 4
#define TWOPI_64 0.09817477042468103f

typedef __attribute__((ext_vector_type(8))) short bf16x8;
typedef __attribute__((ext_vector_type(4))) float f32x4;
typedef __attribute__((ext_vector_type(4))) unsigned short us4;

// tanh-form GELU via hw exp2/rcp; |err| vs exact erf-GELU < ~2.5e-4
__device__ __forceinline__ float gelu_f(float x){
    float x2 = x * x;
    float u  = x * __builtin_fmaf(-0.10294322f, x2, -2.30220795f);
    float e  = __builtin_amdgcn_exp2f(u);
    return x * __builtin_amdgcn_rcpf(1.0f + e);
}

__device__ __forceinline__ unsigned short f2bf(float f){
    union { __hip_bfloat16 h; unsigned short u; } cv;
    cv.h = __float2bfloat16(f);
    return cv.u;
}
__device__ __forceinline__ float bf2f(unsigned short u){
    return __uint_as_float(((unsigned int)u) << 16);
}

// ---------------- weight prep: fp32 -> bf16 (transposed) + twiddle tables --
__global__ __launch_bounds__(256) void k_prep(
    const float* __restrict__ s1w, const float* __restrict__ s2w,
    const float* __restrict__ s3w,
    unsigned short* __restrict__ w1bf,   // [4][9][128]
    unsigned short* __restrict__ w2bf,   // [4][c 128][k 128]
    unsigned short* __restrict__ w3bf,   // [4][c2 32][k 128]
    unsigned short* __restrict__ tdft)   // [2(hi,lo)][32 o][64 t]
{
    int g = blockIdx.x * 256 + threadIdx.x;
    if (g < 65536){
        int l = g >> 14, r = g & 16383;
        int c = r >> 7, k = r & 127;
        w2bf[g] = f2bf(s2w[l*16384 + k*128 + c]);
        return;
    }
    int g3 = g - 65536;
    if (g3 < 16384){
        int l = g3 >> 12, r = g3 & 4095;
        int c2 = r >> 7, k = r & 127;
        w3bf[g3] = f2bf(s3w[l*4096 + k*32 + c2]);
        return;
    }
    int g1 = g3 - 16384;
    if (g1 < 4608){ w1bf[g1] = f2bf(s1w[g1]); return; }
    int g4 = g1 - 4608;
    if (g4 < 2048){
        int o = g4 >> 6, t = g4 & 63;
        float val = 0.f;
        if (o < 24){
            int kz = o >> 1;
            float ang = (float)((kz * t) & 63) * TWOPI_64;
            float sn, cs; sincosf(ang, &sn, &cs);
            val = (o & 1) ? -sn : cs;      // forward DFT: e^{-i theta}
        }
        unsigned short h = f2bf(val);
        tdft[g4]        = h;
        tdft[2048 + g4] = f2bf(val - bf2f(h));
    }
}

// ---------------- lift: x = z @ lift_w + lift_b, layout [B,C,S,V,T] -------
__global__ __launch_bounds__(256) void k_lift(
    const float* __restrict__ coords, const float* __restrict__ params,
    const float* __restrict__ lw, const float* __restrict__ lb,
    float* __restrict__ x)
{
    size_t g = (size_t)blockIdx.x * 256 + threadIdx.x;   // 0..1048575
    int b = (int)(g >> 18);
    size_t p = g & (size_t)(SVT - 1);
    float z[9];
    z[0] = coords[g*3+0]; z[1] = coords[g*3+1]; z[2] = coords[g*3+2];
    #pragma unroll
    for (int j = 0; j < 6; ++j) z[3+j] = params[b*6+j];
    #pragma unroll
    for (int c = 0; c < 32; ++c){
        float acc = lb[c];
        #pragma unroll
        for (int j = 0; j < 9; ++j) acc += z[j] * lw[j*32 + c];
        x[(size_t)(b*32 + c) * SVT + p] = acc;
    }
}

// ------- fused forward DFT t (MFMA split-bf16) then v: x -> X2[bc][kz][ky][s]
__global__ __launch_bounds__(256) void k_fwdTV(
    const float* __restrict__ x, const unsigned short* __restrict__ tdft,
    float2* __restrict__ X2)
{
    __shared__ __align__(16) unsigned short Ahi[64][72], Alo[64][72];
    __shared__ __align__(16) unsigned short Bhi[32][72], Blo[32][72];
    __shared__ float2 a2[12][66];
    __shared__ float2 wtab[64];
    int tid = threadIdx.x;
    int bc = blockIdx.x >> 6;
    int s  = blockIdx.x & 63;
    if (tid < 64){
        float sn, cs;
        sincosf((float)tid * TWOPI_64, &sn, &cs);
        wtab[tid] = make_float2(cs, sn);
    }
    for (int i = tid; i < 2048; i += 256){
        int o = i >> 6, t = i & 63;
        Bhi[o][t] = tdft[i];
        Blo[o][t] = tdft[2048 + i];
    }
    // stage x -> hi/lo bf16
    {
        int row = tid >> 2, c0 = (tid & 3) << 4;
        const float* src = x + (size_t)bc * SVT + (size_t)s * VT + row*64 + c0;
        #pragma unroll
        for (int q = 0; q < 4; ++q){
            float4 v4 = *(const float4*)&src[q*4];
            float vv[4] = {v4.x, v4.y, v4.z, v4.w};
            #pragma unroll
            for (int e = 0; e < 4; ++e){
                unsigned short h = f2bf(vv[e]);
                Ahi[row][c0 + q*4 + e] = h;
                Alo[row][c0 + q*4 + e] = f2bf(vv[e] - bf2f(h));
            }
        }
    }
    __syncthreads();
    // stage 1: wave w computes v-rows 16w..16w+15, 24 outputs (kz x re/im)
    int l = tid & 63, w = tid >> 6;
    int lr = l & 15, kg = l >> 4;
    int r0 = w << 4;
    f32x4 acc[2];
    acc[0] = (f32x4){0.f,0.f,0.f,0.f}; acc[1] = (f32x4){0.f,0.f,0.f,0.f};
    #pragma unroll
    for (int kc = 0; kc < 2; ++kc){
        int ko = kc*32 + kg*8;
        bf16x8 ah = *(const bf16x8*)&Ahi[r0 + lr][ko];
        bf16x8 al = *(const bf16x8*)&Alo[r0 + lr][ko];
        #pragma unroll
        for (int n = 0; n < 2; ++n){
            bf16x8 bh = *(const bf16x8*)&Bhi[n*16 + lr][ko];
            bf16x8 bl = *(const bf16x8*)&Blo[n*16 + lr][ko];
            acc[n] = __builtin_amdgcn_mfma_f32_16x16x32_bf16(ah, bh, acc[n], 0, 0, 0);
            acc[n] = __builtin_amdgcn_mfma_f32_16x16x32_bf16(ah, bl, acc[n], 0, 0, 0);
            acc[n] = __builtin_amdgcn_mfma_f32_16x16x32_bf16(al, bh, acc[n], 0, 0, 0);
        }
    }
    #pragma unroll
    for (int n = 0; n < 2; ++n){
        int o = n*16 + lr;
        if (o < 24){
            int kz = o >> 1;
            #pragma unroll
            for (int r = 0; r < 4; ++r){
                int v = r0 + kg*4 + r;
                if (o & 1) a2[kz][v].y = acc[n][r];
                else       a2[kz][v].x = acc[n][r];
            }
        }
    }
    __syncthreads();
    // stage 2: DFT over v -> X2[bc][kz][ky][s]
    for (int task = tid; task < 288; task += 256){
        int kz = task % 12;
        int ky = task / 12;
        int kya = (ky < 12) ? ky : ky + 40;
        float re = 0.f, im = 0.f;
        for (int v = 0; v < 64; ++v){
            float2 wv = wtab[(kya * v) & 63];
            float2 a  = a2[kz][v];
            re += a.x * wv.x + a.y * wv.y;
            im += a.y * wv.x - a.x * wv.y;
        }
        X2[((size_t)(bc*12 + kz) * 24 + ky) * 64 + s] = make_float2(re, im);
    }
}

// ---------------- forward DFT over s: X2[bc][kz][ky][s] -> X3[bc][kx][ky][kz]
__global__ __launch_bounds__(256) void k_fwdS(
    const float2* __restrict__ X2, float2* __restrict__ X3)
{
    __shared__ float2 cin[32][65];
    __shared__ float2 wtab[64];
    int tid = threadIdx.x;
    if (tid < 64){
        float sn, cs; sincosf((float)tid * TWOPI_64, &sn, &cs);
        wtab[tid] = make_float2(cs, sn);
    }
    int rbase = blockIdx.x * 32;   // rows (bc,kz,ky), 36864 total
    for (int i = tid; i < 2048; i += 256){
        int row = i >> 6, s = i & 63;
        cin[row][s] = X2[(size_t)(rbase + row) * 64 + s];
    }
    __syncthreads();
    int row = tid & 31;
    int r = rbase + row;
    int kxg = tid >> 5;       // 0..7 -> 3 kx each
    int kxs[3];
    #pragma unroll
    for (int j = 0; j < 3; ++j){ int kxi = kxg*3 + j; kxs[j] = (kxi < 12) ? kxi : kxi + 40; }
    float re[3] = {0,0,0}, im[3] = {0,0,0};
    for (int s = 0; s < 64; ++s){
        float2 cv = cin[row][s];
        #pragma unroll
        for (int j = 0; j < 3; ++j){
            float2 wv = wtab[(kxs[j] * s) & 63];
            re[j] += cv.x * wv.x + cv.y * wv.y;
            im[j] += cv.y * wv.x - cv.x * wv.y;
        }
    }
    int bc = r / 288; int kz = (r / 24) % 12; int ky = r % 24;
    #pragma unroll
    for (int j = 0; j < 3; ++j){
        int kxi = kxg*3 + j;
        X3[(size_t)bc * 6912 + (size_t)kxi * 288 + ky * 12 + kz] = make_float2(re[j], im[j]);
    }
}

// --------- per-mode channel mixing: coalesced W, X3 in regs, 4 o per block -
__global__ __launch_bounds__(256) void k_modemix(
    const float2* __restrict__ X3,
    const float* __restrict__ w1, const float* __restrict__ w2,
    const float* __restrict__ w3, const float* __restrict__ w4,
    int layer, float2* __restrict__ Y)
{
    __shared__ float2 wlds[32][64];   // [i][m], 16 KB
    int tid = threadIdx.x;
    int m   = tid & 63;
    int b   = tid >> 6;
    int corner = blockIdx.y >> 3;
    int o0     = (blockIdx.y & 7) * 4;
    int moff0  = blockIdx.x * 64;
    const float* wsrc = (corner==0 ? w1 : corner==1 ? w2 : corner==2 ? w3 : w4)
                        + (size_t)layer * 3538944;   // 32*32*1728*2
    int moff = moff0 + m;
    int m1  = moff / 144;
    int rem = moff - m1 * 144;
    int kx  = m1 + ((corner == 1 || corner == 3) ? 12 : 0);
    int mode_g = kx * 288 + rem + ((corner >= 2) ? 144 : 0);

    float xr[32], xi[32];
    const float2* xp = X3 + (size_t)b * 32 * 6912 + mode_g;
    #pragma unroll
    for (int i = 0; i < 32; ++i){
        float2 a = xp[(size_t)i * 6912];
        xr[i] = a.x; xi[i] = a.y;
    }
    for (int oo = 0; oo < 4; ++oo){
        int o = o0 + oo;
        __syncthreads();
        for (int j = tid; j < 2048; j += 256){
            int i = j >> 6, mm = j & 63;
            wlds[i][mm] = *(const float2*)&wsrc[((size_t)(i*32 + o) * 1728 + moff0 + mm) * 2];
        }
        __syncthreads();
        float re = 0.f, im = 0.f;
        #pragma unroll
        for (int i = 0; i < 32; ++i){
            float2 wv = wlds[i][m];
            re += xr[i]*wv.x - xi[i]*wv.y;
            im += xr[i]*wv.y + xi[i]*wv.x;
        }
        Y[(size_t)(b*32 + o) * 6912 + mode_g] = make_float2(re, im);
    }
}

// ---------------- inverse over s: Y[bo][kx][ky][kz] -> Z1[bo][kz][s][ky] ---
__global__ __launch_bounds__(256) void k_invS(
    const float2* __restrict__ Y, float2* __restrict__ Z1)
{
    __shared__ float2 yin[24][24];
    __shared__ float2 wtab[64];
    int tid = threadIdx.x;
    if (tid < 64){
        float sn, cs; sincosf((float)tid * TWOPI_64, &sn, &cs);
        wtab[tid] = make_float2(cs, sn);
    }
    int bo = blockIdx.x / 12;
    int kz = blockIdx.x % 12;
    for (int i = tid; i < 576; i += 256){
        int kx = i / 24, ky = i % 24;
        yin[kx][ky] = Y[(size_t)bo * 6912 + (size_t)kx * 288 + ky * 12 + kz];
    }
    __syncthreads();
    int s = tid & 63;
    int kyg = tid >> 6;   // 0..3 -> 6 ky each
    float re[6] = {0,0,0,0,0,0}, im[6] = {0,0,0,0,0,0};
    for (int kxi = 0; kxi < 24; ++kxi){
        int kxa = (kxi < 12) ? kxi : kxi + 40;
        float2 wv = wtab[(kxa * s) & 63];     // e^{+i theta}
        #pragma unroll
        for (int j = 0; j < 6; ++j){
            float2 a = yin[kxi][kyg*6 + j];
            re[j] += a.x * wv.x - a.y * wv.y;
            im[j] += a.x * wv.y + a.y * wv.x;
        }
    }
    #pragma unroll
    for (int j = 0; j < 6; ++j){
        int ky = kyg*6 + j;
        Z1[((size_t)(bo*12 + kz) * 64 + s) * 24 + ky] = make_float2(re[j], im[j]);
    }
}

// ---------------- pointwise conv IN-PLACE: x[b,:,p] <- W x[b,:,p] + b ------
__global__ __launch_bounds__(256) void k_conv(
    float* x, const float* __restrict__ cw,
    const float* __restrict__ cb, int layer)
{
    __shared__ float wsh[32][32];   // [o][i]
    __shared__ float bsh[32];
    int tid = threadIdx.x;
    if (tid < 32) bsh[tid] = cb[layer*32 + tid];
    for (int i = tid; i < 1024; i += 256) wsh[i >> 5][i & 31] = cw[layer*1024 + i];
    __syncthreads();
    size_t g = (size_t)blockIdx.x * 256 + tid;
    int b = (int)(g >> 18);
    size_t p = g & (size_t)(SVT - 1);
    float acc[32];
    #pragma unroll
    for (int o = 0; o < 32; ++o) acc[o] = bsh[o];
    for (int i = 0; i < 32; ++i){
        float xv = x[(size_t)(b*32 + i) * SVT + p];
        #pragma unroll
        for (int o = 0; o < 32; ++o) acc[o] += xv * wsh[o][i];
    }
    #pragma unroll
    for (int o = 0; o < 32; ++o) x[(size_t)(b*32 + o) * SVT + p] = acc[o];
}

// -- fused inverse over v then t (+ gelu(x1+x2)): Z1 -> xio = gelu(x1+xio) --
__global__ __launch_bounds__(256) void k_invVT(
    const float2* __restrict__ Z1, float* xio)
{
    __shared__ float2 zin[12][24];
    __shared__ float2 c2[12][66];
    __shared__ float2 wtab[64];
    int tid = threadIdx.x;
    int bo = blockIdx.x >> 6;
    int s  = blockIdx.x & 63;
    if (tid < 64){
        float sn, cs; sincosf((float)tid * TWOPI_64, &sn, &cs);
        wtab[tid] = make_float2(cs, sn);
    }
    for (int i = tid; i < 288; i += 256){
        int kz = i / 24, ky = i % 24;
        zin[kz][ky] = Z1[((size_t)(bo*12 + kz) * 64 + s) * 24 + ky];
    }
    __syncthreads();
    // stage 1: inverse DFT over ky -> c2[kz][v]
    #pragma unroll
    for (int j = 0; j < 3; ++j){
        int task = tid + j * 256;        // < 768
        int v = task & 63, kz = task >> 6;
        float re = 0.f, im = 0.f;
        #pragma unroll
        for (int ky = 0; ky < 24; ++ky){
            int kya = (ky < 12) ? ky : ky + 40;
            float2 wv = wtab[(kya * v) & 63];
            float2 a = zin[kz][ky];
            re += a.x * wv.x - a.y * wv.y;
            im += a.x * wv.y + a.y * wv.x;
        }
        c2[kz][v] = make_float2(re, im);
    }
    __syncthreads();
    // stage 2: real inverse over kz, combine with conv-out (in xio), gelu
    int v  = tid & 63;
    int tb = (tid >> 6) << 4;   // 0,16,32,48
    float sum[16];
    #pragma unroll
    for (int j = 0; j < 16; ++j) sum[j] = 0.f;
    float dc = c2[0][v].x;
    #pragma unroll
    for (int kz = 1; kz < 12; ++kz){
        float2 a = c2[kz][v];
        #pragma unroll
        for (int j = 0; j < 16; ++j){
            float2 wv = wtab[(kz * (tb + j)) & 63];
            sum[j] += a.x * wv.x - a.y * wv.y;
        }
    }
    const float norm = 1.0f / 262144.0f;
    size_t base = (size_t)bo * SVT + (size_t)s * VT + (size_t)v * 64 + tb;
    #pragma unroll
    for (int j = 0; j < 16; j += 4){
        float4 xv = *(const float4*)&xio[base + j];
        float4 r;
        r.x = gelu_f((dc + 2.f*sum[j+0]) * norm + xv.x);
        r.y = gelu_f((dc + 2.f*sum[j+1]) * norm + xv.y);
        r.z = gelu_f((dc + 2.f*sum[j+2]) * norm + xv.z);
        r.w = gelu_f((dc + 2.f*sum[j+3]) * norm + xv.w);
        *(float4*)&xio[base + j] = r;
    }
}

// ------- fused skip MLP v3: 64-pt blocks, MFMA B/C/D, optional proj fusion --
// 256 thr = 4 waves; wave w owns p-tile w (points 16w..16w+15).
template<int LAST>
__global__ __launch_bounds__(256) void k_skip(
    const float* __restrict__ coords, const float* __restrict__ params,
    const unsigned short* __restrict__ w1bf, const float* __restrict__ s1b,
    const unsigned short* __restrict__ w2bf, const float* __restrict__ s2b,
    const unsigned short* __restrict__ w3bf, const float* __restrict__ s3b,
    int layer, float* __restrict__ xio,
    const float* __restrict__ p1w, const float* __restrict__ p1b,
    const float* __restrict__ p2w, const float* __restrict__ p2b,
    float* __restrict__ out)
{
    __shared__ __align__(16) unsigned short A1[64][136];   // h1/h2 bf16; later overlay
    __shared__ __align__(16) unsigned short zst[4][16][8];
    __shared__ __align__(16) unsigned short w1pk[128][8];
    __shared__ unsigned short w1s[9][128];
    __shared__ float pb[128];
    __shared__ float b2s[128];
    __shared__ float b3s[32];

    int tid = threadIdx.x;
    size_t g0 = (size_t)blockIdx.x * 64;
    int b = (int)(g0 >> 18);
    const unsigned short* w2g = w2bf + (size_t)layer * 16384;   // [c][k]
    const unsigned short* w3g = w3bf + (size_t)layer * 4096;    // [c2][k]

    for (int i = tid; i < 1152; i += 256) w1s[i >> 7][i & 127] = w1bf[layer*1152 + i];
    if (tid < 128) b2s[tid] = s2b[layer*128 + tid];
    if (tid < 32)  b3s[tid] = s3b[layer*32  + tid];
    __syncthreads();
    if (tid < 128){
        float acc = s1b[layer*128 + tid];
        #pragma unroll
        for (int j = 0; j < 6; ++j) acc += params[b*6 + j] * bf2f(w1s[3 + j][tid]);
        pb[tid] = acc;
        bf16x8 pk;
        pk[0] = (short)w1s[0][tid]; pk[1] = (short)w1s[1][tid];
        pk[2] = (short)w1s[2][tid]; pk[3] = 0;
        pk[4] = pk[0]; pk[5] = pk[1]; pk[6] = pk[2]; pk[7] = 0;
        *(bf16x8*)&w1pk[tid][0] = pk;
    }
    __syncthreads();

    int l  = tid & 63;
    int w  = tid >> 6;
    int lr = l & 15;
    int kg = l >> 4;

    // ---- stage z (hi/lo bf16) for wave's 16 points; wave-local ------------
    if (l < 16){
        size_t g = g0 + w*16 + l;
        float z0 = coords[g*3+0], z1 = coords[g*3+1], z2 = coords[g*3+2];
        unsigned short h0 = f2bf(z0), h1 = f2bf(z1), h2 = f2bf(z2);
        bf16x8 pk;
        pk[0] = (short)h0; pk[1] = (short)h1; pk[2] = (short)h2; pk[3] = 0;
        pk[4] = (short)f2bf(z0 - bf2f(h0));
        pk[5] = (short)f2bf(z1 - bf2f(h1));
        pk[6] = (short)f2bf(z2 - bf2f(h2));
        pk[7] = 0;
        *(bf16x8*)&zst[w][l][0] = pk;
    }
    bf16x8 bz;
    if (kg == 0) bz = *(const bf16x8*)&zst[w][lr][0];
    else         bz = (bf16x8){0,0,0,0,0,0,0,0};

    // ---- phase B: h1 = gelu(z@w1 + pb) via MFMA, D[h][p] ------------------
    {
        f32x4 accB[8];
        #pragma unroll
        for (int m = 0; m < 8; ++m) accB[m] = (f32x4){0.f,0.f,0.f,0.f};
        #pragma unroll
        for (int m = 0; m < 8; ++m){
            bf16x8 af = *(const bf16x8*)&w1pk[m*16 + lr][0];
            accB[m] = __builtin_amdgcn_mfma_f32_16x16x32_bf16(af, bz, accB[m], 0, 0, 0);
        }
        #pragma unroll
        for (int m = 0; m < 8; ++m){
            int c0 = m*16 + kg*4;
            float4 bb = *(const float4*)&pb[c0];
            us4 pk4;
            pk4[0] = f2bf(gelu_f(accB[m][0] + bb.x));
            pk4[1] = f2bf(gelu_f(accB[m][1] + bb.y));
            pk4[2] = f2bf(gelu_f(accB[m][2] + bb.z));
            pk4[3] = f2bf(gelu_f(accB[m][3] + bb.w));
            *(us4*)&A1[w*16 + lr][c0] = pk4;
        }
    }
    __syncthreads();   // h1 visible to all waves

    // ---- phase C: h2pre = h1 @ w2 (MFMA, swapped -> D[c][p]) --------------
    // wave w computes c-tiles {2w, 2w+1} over all 4 p-tiles
    f32x4 accC[2][4];
    #pragma unroll
    for (int mi = 0; mi < 2; ++mi)
        #pragma unroll
        for (int pt = 0; pt < 4; ++pt) accC[mi][pt] = (f32x4){0.f,0.f,0.f,0.f};
    #pragma unroll
    for (int kc = 0; kc < 4; ++kc){
        int ko = kc*32 + kg*8;
        bf16x8 a0 = *(const bf16x8*)&w2g[((2*w    )*16 + lr)*128 + ko];
        bf16x8 a1 = *(const bf16x8*)&w2g[((2*w + 1)*16 + lr)*128 + ko];
        #pragma unroll
        for (int pt = 0; pt < 4; ++pt){
            bf16x8 bb = *(const bf16x8*)&A1[pt*16 + lr][ko];
            accC[0][pt] = __builtin_amdgcn_mfma_f32_16x16x32_bf16(a0, bb, accC[0][pt], 0, 0, 0);
            accC[1][pt] = __builtin_amdgcn_mfma_f32_16x16x32_bf16(a1, bb, accC[1][pt], 0, 0, 0);
        }
    }
    __syncthreads();   // all h1 reads done -> safe to overwrite A1 with h2
    #pragma unroll
    for (int mi = 0; mi < 2; ++mi)
        #pragma unroll
        for (int pt = 0; pt < 4; ++pt){
            int c0 = (2*w + mi)*16 + kg*4;
            float4 bb = *(const float4*)&b2s[c0];
            us4 pk4;
            pk4[0] = f2bf(gelu_f(accC[mi][pt][0] + bb.x));
            pk4[1] = f2bf(gelu_f(accC[mi][pt][1] + bb.y));
            pk4[2] = f2bf(gelu_f(accC[mi][pt][2] + bb.z));
            pk4[3] = f2bf(gelu_f(accC[mi][pt][3] + bb.w));
            *(us4*)&A1[pt*16 + lr][c0] = pk4;
        }
    __syncthreads();   // h2 visible

    // ---- phase D: out = h2 @ w3 (MFMA, unswapped -> D[p][c2]) -------------
    // wave w: n-tile = w&1, p-tiles {(w>>1)*2, (w>>1)*2+1}
    int nD  = w & 1;
    int pt0 = (w >> 1) * 2;
    f32x4 c3[2];
    c3[0] = (f32x4){0.f,0.f,0.f,0.f}; c3[1] = (f32x4){0.f,0.f,0.f,0.f};
    #pragma unroll
    for (int kc = 0; kc < 4; ++kc){
        int ko = kc*32 + kg*8;
        bf16x8 bw3 = *(const bf16x8*)&w3g[(nD*16 + lr)*128 + ko];
        bf16x8 aa0 = *(const bf16x8*)&A1[(pt0    )*16 + lr][ko];
        bf16x8 aa1 = *(const bf16x8*)&A1[(pt0 + 1)*16 + lr][ko];
        c3[0] = __builtin_amdgcn_mfma_f32_16x16x32_bf16(aa0, bw3, c3[0], 0, 0, 0);
        c3[1] = __builtin_amdgcn_mfma_f32_16x16x32_bf16(aa1, bw3, c3[1], 0, 0, 0);
    }
    __syncthreads();   // all h2 reads done -> A1 free for overlay

    // overlay region (floats) inside A1: outsT[32][68] + (LAST: hs/p1w/smalls)
    float* outsT = (float*)&A1[0][0];
    {
        int c2 = nD*16 + lr;
        float bv = b3s[c2];
        #pragma unroll
        for (int q = 0; q < 2; ++q){
            int p0 = (pt0 + q)*16 + kg*4;
            float4 v4;
            v4.x = c3[q][0] + bv; v4.y = c3[q][1] + bv;
            v4.z = c3[q][2] + bv; v4.w = c3[q][3] + bv;
            *(float4*)&outsT[c2*68 + p0] = v4;
        }
    }
    float* hs   = outsT + 2176;   // [64][17]
    float* p1wS = outsT + 3264;   // [512]
    float* smB  = outsT + 3776;   // 16 b1 | 16 p2w | 1 p2b
    if (LAST){
        for (int i = tid; i < 512; i += 256) p1wS[i] = p1w[i];
        if (tid < 16){ smB[tid] = p1b[tid]; smB[16 + tid] = p2w[tid]; }
        if (tid == 32) smB[32] = p2b[0];
    }
    __syncthreads();

    // ---- rmw: xsum = xio + skip ------------------------------------------
    {
        int c  = tid >> 3;        // 0..31
        int pg = tid & 7;         // 8 floats each
        size_t prel = (g0 & (size_t)(SVT - 1)) + (size_t)pg*8;
        float* gp = xio + (((size_t)(b*32 + c)) << 18) + prel;
        float* op = &outsT[c*68 + pg*8];
        #pragma unroll
        for (int i = 0; i < 8; i += 4){
            float4 xv = *(const float4*)&gp[i];
            float4 ov = *(const float4*)&op[i];
            ov.x += xv.x; ov.y += xv.y; ov.z += xv.z; ov.w += xv.w;
            if (LAST) *(float4*)&op[i] = ov;     // keep xsum in LDS
            else      *(float4*)&gp[i] = ov;     // write back to global
        }
    }
    if (LAST){
        __syncthreads();
        // proj layer 1: h[p][j] = b1[j] + sum_c xsum[c][p] * p1w[c][j]
        {
            int p  = tid & 63;
            int jq = tid >> 6;    // 4 j's each
            float h[4];
            #pragma unroll
            for (int j = 0; j < 4; ++j) h[j] = smB[jq*4 + j];
            for (int c = 0; c < 32; ++c){
                float xv = outsT[c*68 + p];
                #pragma unroll
                for (int j = 0; j < 4; ++j) h[j] += xv * p1wS[c*16 + jq*4 + j];
            }
            #pragma unroll
            for (int j = 0; j < 4; ++j) hs[p*17 + jq*4 + j] = h[j];
        }
        __syncthreads();
        if (tid < 64){
            float acc = smB[32];
            #pragma unroll
            for (int j = 0; j < 16; ++j) acc += gelu_f(hs[tid*17 + j]) * smB[16 + j];
            out[g0 + tid] = acc;
        }
    }
}

extern "C" void kernel_launch(void* const* d_in, const int* in_sizes, int n_in,
                              void* d_out, int out_size, void* d_ws, size_t ws_size,
                              hipStream_t stream)
{
    (void)in_sizes; (void)n_in; (void)out_size; (void)ws_size;
    const float* coords = (const float*)d_in[0];
    const float* params = (const float*)d_in[1];
    const float* lift_w = (const float*)d_in[2];
    const float* lift_b = (const float*)d_in[3];
    const float* sw1    = (const float*)d_in[4];
    const float* sw2    = (const float*)d_in[5];
    const float* sw3    = (const float*)d_in[6];
    const float* sw4    = (const float*)d_in[7];
    const float* conv_w = (const float*)d_in[8];
    const float* conv_b = (const float*)d_in[9];
    const float* s1w    = (const float*)d_in[10];
    const float* s1b    = (const float*)d_in[11];
    const float* s2w    = (const float*)d_in[12];
    const float* s2b    = (const float*)d_in[13];
    const float* s3w    = (const float*)d_in[14];
    const float* s3b    = (const float*)d_in[15];
    const float* p1w    = (const float*)d_in[16];
    const float* p1b    = (const float*)d_in[17];
    const float* p2w    = (const float*)d_in[18];
    const float* p2b    = (const float*)d_in[19];
    float* out = (float*)d_out;

    char* ws = (char*)d_ws;
    float*  xA = (float*)(ws);                                   // 134,217,728
    float2* X2 = (float2*)(ws + 134217728ull);                   //  18,874,368 (also Z1)
    float2* X3 = (float2*)(ws + 153092096ull);                   //   7,077,888
    float2* Yb = (float2*)(ws + 160169984ull);                   //   7,077,888
    unsigned short* w2bf = (unsigned short*)(ws + 167247872ull); //     131,072
    unsigned short* w3bf = (unsigned short*)(ws + 167378944ull); //      32,768
    unsigned short* w1bf = (unsigned short*)(ws + 167411712ull); //       9,216
    unsigned short* tdft = (unsigned short*)(ws + 167420928ull); //       8,192
    // total 167,429,120 B

    k_prep<<<346, 256, 0, stream>>>(s1w, s2w, s3w, w1bf, w2bf, w3bf, tdft);
    k_lift<<<4096, 256, 0, stream>>>(coords, params, lift_w, lift_b, xA);

    for (int l = 0; l < NLAY; ++l){
        k_fwdTV<<<8192, 256, 0, stream>>>(xA, tdft, X2);
        k_fwdS<<<1152, 256, 0, stream>>>(X2, X3);
        dim3 gmm(27, 32);
        k_modemix<<<gmm, 256, 0, stream>>>(X3, sw1, sw2, sw3, sw4, l, Yb);
        k_invS<<<1536, 256, 0, stream>>>(Yb, X2);          // Z1 overlays X2
        k_conv<<<4096, 256, 0, stream>>>(xA, conv_w, conv_b, l);   // in place
        k_invVT<<<8192, 256, 0, stream>>>(X2, xA);         // xA = gelu(x1 + x2)
        if (l < NLAY - 1)
            k_skip<0><<<16384, 256, 0, stream>>>(coords, params, w1bf, s1b,
                w2bf, s2b, w3bf, s3b, l, xA, p1w, p1b, p2w, p2b, out);
        else
            k_skip<1><<<16384, 256, 0, stream>>>(coords, params, w1bf, s1b,
                w2bf, s2b, w3bf, s3b, l, xA, p1w, p1b, p2w, p2b, out);
    }
}

// Round 7
// 1701.471 us; speedup vs baseline: 3.8034x; 1.0821x over previous
//
#include <hip/hip_runtime.h>
#include <hip/hip_bf16.h>
#include <math.h>

#define NB   4
#define NC   32
#define SVT  262144      // 64^3
#define VT   4096        // 64*64
#define NLAY 4
#define TWOPI_64 0.09817477042468103f

typedef __attribute__((ext_vector_type(8))) short bf16x8;
typedef __attribute__((ext_vector_type(4))) float f32x4;
typedef __attribute__((ext_vector_type(4))) unsigned short us4;

// tanh-form GELU via hw exp2/rcp; |err| vs exact erf-GELU < ~2.5e-4
__device__ __forceinline__ float gelu_f(float x){
    float x2 = x * x;
    float u  = x * __builtin_fmaf(-0.10294322f, x2, -2.30220795f);
    float e  = __builtin_amdgcn_exp2f(u);
    return x * __builtin_amdgcn_rcpf(1.0f + e);
}

__device__ __forceinline__ unsigned short f2bf(float f){
    union { __hip_bfloat16 h; unsigned short u; } cv;
    cv.h = __float2bfloat16(f);
    return cv.u;
}
__device__ __forceinline__ float bf2f(unsigned short u){
    return __uint_as_float(((unsigned int)u) << 16);
}

// ------------- weight prep: bf16 transposes + twiddle tables + pb ---------
__global__ __launch_bounds__(256) void k_prep(
    const float* __restrict__ params,
    const float* __restrict__ s1w, const float* __restrict__ s1b,
    const float* __restrict__ s2w, const float* __restrict__ s3w,
    unsigned short* __restrict__ w2bf,   // [4][c 128][k 128]
    unsigned short* __restrict__ w3bf,   // [4][c2 32][k 128]
    unsigned short* __restrict__ tdft,   // [2(hi,lo)][32 o][64 t]
    unsigned short* __restrict__ T1h, unsigned short* __restrict__ T1l, // [128][64]
    unsigned short* __restrict__ T2h, unsigned short* __restrict__ T2l, // [64][32]
    float* __restrict__ pbq,             // [4 l][4 b][128]
    unsigned short* __restrict__ w1dup)  // [4 l][128][8]
{
    int g = blockIdx.x * 256 + threadIdx.x;
    if (g < 65536){
        int l = g >> 14, r = g & 16383;
        int c = r >> 7, k = r & 127;
        w2bf[g] = f2bf(s2w[l*16384 + k*128 + c]);
        return;
    }
    g -= 65536;
    if (g < 16384){
        int l = g >> 12, r = g & 4095;
        int c2 = r >> 7, k = r & 127;
        w3bf[g] = f2bf(s3w[l*4096 + k*32 + c2]);
        return;
    }
    g -= 16384;
    if (g < 2048){
        int o = g >> 6, t = g & 63;
        float val = 0.f;
        if (o < 24){
            int kz = o >> 1;
            float ang = (float)((kz * t) & 63) * TWOPI_64;
            float sn, cs; sincosf(ang, &sn, &cs);
            val = (o & 1) ? -sn : cs;      // forward DFT: e^{-i theta}
        }
        unsigned short h = f2bf(val);
        tdft[g]        = h;
        tdft[2048 + g] = f2bf(val - bf2f(h));
        return;
    }
    g -= 2048;
    if (g < 8192){           // T1: inverse over ky -> v. col=2v+pout, k1=2ky+pin
        int col = g >> 6, k1 = g & 63;
        int v = col >> 1, pout = col & 1;
        float val = 0.f;
        if (k1 < 48){
            int ky = k1 >> 1, pin = k1 & 1;
            int kya = (ky < 12) ? ky : ky + 40;
            float ang = (float)((kya * v) & 63) * TWOPI_64;
            float sn, cs; sincosf(ang, &sn, &cs);
            val = pout == 0 ? (pin == 0 ? cs : -sn) : (pin == 0 ? sn : cs);
        }
        unsigned short h = f2bf(val);
        T1h[g] = h;
        T1l[g] = f2bf(val - bf2f(h));
        return;
    }
    g -= 8192;
    if (g < 2048){           // T2: real inverse over kz -> t (norm + x2 folded)
        int t = g >> 5, k2 = g & 31;
        float val = 0.f;
        if (k2 < 24){
            int kz = k2 >> 1, part = k2 & 1;
            float wk = (kz == 0) ? 1.f : 2.f;
            float ang = (float)((kz * t) & 63) * TWOPI_64;
            float sn, cs; sincosf(ang, &sn, &cs);
            val = (part ? -sn : cs) * wk * (1.f / 262144.f);
        }
        unsigned short h = f2bf(val);
        T2h[g] = h;
        T2l[g] = f2bf(val - bf2f(h));
        return;
    }
    g -= 2048;
    if (g < 2048){           // pbq[l][b][h]
        int l = g >> 9, b = (g >> 7) & 3, h = g & 127;
        float acc = s1b[l*128 + h];
        #pragma unroll
        for (int j = 0; j < 6; ++j)
            acc += params[b*6 + j] * bf2f(f2bf(s1w[l*1152 + (3 + j)*128 + h]));
        pbq[g] = acc;
        return;
    }
    g -= 2048;
    if (g < 4096){           // w1dup[l][h][slot]: rows 0-2 dup in 0-2 & 4-6
        int l = g >> 10, rem = g & 1023;
        int h = rem >> 3, slot = rem & 7;
        float val = 0.f;
        if (slot != 3 && slot != 7){
            int row = (slot < 3) ? slot : slot - 4;
            val = bf2f(f2bf(s1w[l*1152 + row*128 + h]));
        }
        w1dup[g] = f2bf(val);
    }
}

// ---------------- lift: x = z @ lift_w + lift_b, layout [B,C,S,V,T] -------
__global__ __launch_bounds__(256) void k_lift(
    const float* __restrict__ coords, const float* __restrict__ params,
    const float* __restrict__ lw, const float* __restrict__ lb,
    float* __restrict__ x)
{
    size_t g = (size_t)blockIdx.x * 256 + threadIdx.x;   // 0..1048575
    int b = (int)(g >> 18);
    size_t p = g & (size_t)(SVT - 1);
    float z[9];
    z[0] = coords[g*3+0]; z[1] = coords[g*3+1]; z[2] = coords[g*3+2];
    #pragma unroll
    for (int j = 0; j < 6; ++j) z[3+j] = params[b*6+j];
    #pragma unroll
    for (int c = 0; c < 32; ++c){
        float acc = lb[c];
        #pragma unroll
        for (int j = 0; j < 9; ++j) acc += z[j] * lw[j*32 + c];
        x[(size_t)(b*32 + c) * SVT + p] = acc;
    }
}

// ------- fused forward DFT t (MFMA split-bf16) then v: x -> X2[bc][kz][ky][s]
__global__ __launch_bounds__(256) void k_fwdTV(
    const float* __restrict__ x, const unsigned short* __restrict__ tdft,
    float2* __restrict__ X2)
{
    __shared__ __align__(16) unsigned short Ahi[64][72], Alo[64][72];
    __shared__ __align__(16) unsigned short Bhi[32][72], Blo[32][72];
    __shared__ float2 a2[12][66];
    __shared__ float2 wtab[64];
    int tid = threadIdx.x;
    int bc = blockIdx.x >> 6;
    int s  = blockIdx.x & 63;
    if (tid < 64){
        float sn, cs;
        sincosf((float)tid * TWOPI_64, &sn, &cs);
        wtab[tid] = make_float2(cs, sn);
    }
    for (int i = tid; i < 2048; i += 256){
        int o = i >> 6, t = i & 63;
        Bhi[o][t] = tdft[i];
        Blo[o][t] = tdft[2048 + i];
    }
    // stage x -> hi/lo bf16
    {
        int row = tid >> 2, c0 = (tid & 3) << 4;
        const float* src = x + (size_t)bc * SVT + (size_t)s * VT + row*64 + c0;
        #pragma unroll
        for (int q = 0; q < 4; ++q){
            float4 v4 = *(const float4*)&src[q*4];
            float vv[4] = {v4.x, v4.y, v4.z, v4.w};
            #pragma unroll
            for (int e = 0; e < 4; ++e){
                unsigned short h = f2bf(vv[e]);
                Ahi[row][c0 + q*4 + e] = h;
                Alo[row][c0 + q*4 + e] = f2bf(vv[e] - bf2f(h));
            }
        }
    }
    __syncthreads();
    // stage 1: wave w computes v-rows 16w..16w+15, 24 outputs (kz x re/im)
    int l = tid & 63, w = tid >> 6;
    int lr = l & 15, kg = l >> 4;
    int r0 = w << 4;
    f32x4 acc[2];
    acc[0] = (f32x4){0.f,0.f,0.f,0.f}; acc[1] = (f32x4){0.f,0.f,0.f,0.f};
    #pragma unroll
    for (int kc = 0; kc < 2; ++kc){
        int ko = kc*32 + kg*8;
        bf16x8 ah = *(const bf16x8*)&Ahi[r0 + lr][ko];
        bf16x8 al = *(const bf16x8*)&Alo[r0 + lr][ko];
        #pragma unroll
        for (int n = 0; n < 2; ++n){
            bf16x8 bh = *(const bf16x8*)&Bhi[n*16 + lr][ko];
            bf16x8 bl = *(const bf16x8*)&Blo[n*16 + lr][ko];
            acc[n] = __builtin_amdgcn_mfma_f32_16x16x32_bf16(ah, bh, acc[n], 0, 0, 0);
            acc[n] = __builtin_amdgcn_mfma_f32_16x16x32_bf16(ah, bl, acc[n], 0, 0, 0);
            acc[n] = __builtin_amdgcn_mfma_f32_16x16x32_bf16(al, bh, acc[n], 0, 0, 0);
        }
    }
    #pragma unroll
    for (int n = 0; n < 2; ++n){
        int o = n*16 + lr;
        if (o < 24){
            int kz = o >> 1;
            #pragma unroll
            for (int r = 0; r < 4; ++r){
                int v = r0 + kg*4 + r;
                if (o & 1) a2[kz][v].y = acc[n][r];
                else       a2[kz][v].x = acc[n][r];
            }
        }
    }
    __syncthreads();
    // stage 2: DFT over v -> X2[bc][kz][ky][s]
    for (int task = tid; task < 288; task += 256){
        int kz = task % 12;
        int ky = task / 12;
        int kya = (ky < 12) ? ky : ky + 40;
        float re = 0.f, im = 0.f;
        for (int v = 0; v < 64; ++v){
            float2 wv = wtab[(kya * v) & 63];
            float2 a  = a2[kz][v];
            re += a.x * wv.x + a.y * wv.y;
            im += a.y * wv.x - a.x * wv.y;
        }
        X2[((size_t)(bc*12 + kz) * 24 + ky) * 64 + s] = make_float2(re, im);
    }
}

// ---------------- forward DFT over s: X2[bc][kz][ky][s] -> X3[bc][kx][ky][kz]
__global__ __launch_bounds__(256) void k_fwdS(
    const float2* __restrict__ X2, float2* __restrict__ X3)
{
    __shared__ float2 cin[32][65];
    __shared__ float2 wtab[64];
    int tid = threadIdx.x;
    if (tid < 64){
        float sn, cs; sincosf((float)tid * TWOPI_64, &sn, &cs);
        wtab[tid] = make_float2(cs, sn);
    }
    int rbase = blockIdx.x * 32;   // rows (bc,kz,ky), 36864 total
    for (int i = tid; i < 2048; i += 256){
        int row = i >> 6, s = i & 63;
        cin[row][s] = X2[(size_t)(rbase + row) * 64 + s];
    }
    __syncthreads();
    int row = tid & 31;
    int r = rbase + row;
    int kxg = tid >> 5;       // 0..7 -> 3 kx each
    int kxs[3];
    #pragma unroll
    for (int j = 0; j < 3; ++j){ int kxi = kxg*3 + j; kxs[j] = (kxi < 12) ? kxi : kxi + 40; }
    float re[3] = {0,0,0}, im[3] = {0,0,0};
    for (int s = 0; s < 64; ++s){
        float2 cv = cin[row][s];
        #pragma unroll
        for (int j = 0; j < 3; ++j){
            float2 wv = wtab[(kxs[j] * s) & 63];
            re[j] += cv.x * wv.x + cv.y * wv.y;
            im[j] += cv.y * wv.x - cv.x * wv.y;
        }
    }
    int bc = r / 288; int kz = (r / 24) % 12; int ky = r % 24;
    #pragma unroll
    for (int j = 0; j < 3; ++j){
        int kxi = kxg*3 + j;
        X3[(size_t)bc * 6912 + (size_t)kxi * 288 + ky * 12 + kz] = make_float2(re[j], im[j]);
    }
}

// --------- per-mode channel mixing: coalesced W, X3 in regs, 4 o per block -
__global__ __launch_bounds__(256) void k_modemix(
    const float2* __restrict__ X3,
    const float* __restrict__ w1, const float* __restrict__ w2,
    const float* __restrict__ w3, const float* __restrict__ w4,
    int layer, float2* __restrict__ Y)
{
    __shared__ float2 wlds[32][64];   // [i][m], 16 KB
    int tid = threadIdx.x;
    int m   = tid & 63;
    int b   = tid >> 6;
    int corner = blockIdx.y >> 3;
    int o0     = (blockIdx.y & 7) * 4;
    int moff0  = blockIdx.x * 64;
    const float* wsrc = (corner==0 ? w1 : corner==1 ? w2 : corner==2 ? w3 : w4)
                        + (size_t)layer * 3538944;   // 32*32*1728*2
    int moff = moff0 + m;
    int m1  = moff / 144;
    int rem = moff - m1 * 144;
    int kx  = m1 + ((corner == 1 || corner == 3) ? 12 : 0);
    int mode_g = kx * 288 + rem + ((corner >= 2) ? 144 : 0);

    float xr[32], xi[32];
    const float2* xp = X3 + (size_t)b * 32 * 6912 + mode_g;
    #pragma unroll
    for (int i = 0; i < 32; ++i){
        float2 a = xp[(size_t)i * 6912];
        xr[i] = a.x; xi[i] = a.y;
    }
    for (int oo = 0; oo < 4; ++oo){
        int o = o0 + oo;
        __syncthreads();
        for (int j = tid; j < 2048; j += 256){
            int i = j >> 6, mm = j & 63;
            wlds[i][mm] = *(const float2*)&wsrc[((size_t)(i*32 + o) * 1728 + moff0 + mm) * 2];
        }
        __syncthreads();
        float re = 0.f, im = 0.f;
        #pragma unroll
        for (int i = 0; i < 32; ++i){
            float2 wv = wlds[i][m];
            re += xr[i]*wv.x - xi[i]*wv.y;
            im += xr[i]*wv.y + xi[i]*wv.x;
        }
        Y[(size_t)(b*32 + o) * 6912 + mode_g] = make_float2(re, im);
    }
}

// ---------------- inverse over s: Y[bo][kx][ky][kz] -> Z1[bo][kz][s][ky] ---
__global__ __launch_bounds__(256) void k_invS(
    const float2* __restrict__ Y, float2* __restrict__ Z1)
{
    __shared__ float2 yin[24][24];
    __shared__ float2 wtab[64];
    int tid = threadIdx.x;
    if (tid < 64){
        float sn, cs; sincosf((float)tid * TWOPI_64, &sn, &cs);
        wtab[tid] = make_float2(cs, sn);
    }
    int bo = blockIdx.x / 12;
    int kz = blockIdx.x % 12;
    for (int i = tid; i < 576; i += 256){
        int kx = i / 24, ky = i % 24;
        yin[kx][ky] = Y[(size_t)bo * 6912 + (size_t)kx * 288 + ky * 12 + kz];
    }
    __syncthreads();
    int s = tid & 63;
    int kyg = tid >> 6;   // 0..3 -> 6 ky each
    float re[6] = {0,0,0,0,0,0}, im[6] = {0,0,0,0,0,0};
    for (int kxi = 0; kxi < 24; ++kxi){
        int kxa = (kxi < 12) ? kxi : kxi + 40;
        float2 wv = wtab[(kxa * s) & 63];     // e^{+i theta}
        #pragma unroll
        for (int j = 0; j < 6; ++j){
            float2 a = yin[kxi][kyg*6 + j];
            re[j] += a.x * wv.x - a.y * wv.y;
            im[j] += a.x * wv.y + a.y * wv.x;
        }
    }
    #pragma unroll
    for (int j = 0; j < 6; ++j){
        int ky = kyg*6 + j;
        Z1[((size_t)(bo*12 + kz) * 64 + s) * 24 + ky] = make_float2(re[j], im[j]);
    }
}

// ---------------- pointwise conv IN-PLACE: x[b,:,p] <- W x[b,:,p] + b ------
__global__ __launch_bounds__(256) void k_conv(
    float* x, const float* __restrict__ cw,
    const float* __restrict__ cb, int layer)
{
    __shared__ float wsh[32][32];   // [o][i]
    __shared__ float bsh[32];
    int tid = threadIdx.x;
    if (tid < 32) bsh[tid] = cb[layer*32 + tid];
    for (int i = tid; i < 1024; i += 256) wsh[i >> 5][i & 31] = cw[layer*1024 + i];
    __syncthreads();
    size_t g = (size_t)blockIdx.x * 256 + tid;
    int b = (int)(g >> 18);
    size_t p = g & (size_t)(SVT - 1);
    float acc[32];
    #pragma unroll
    for (int o = 0; o < 32; ++o) acc[o] = bsh[o];
    for (int i = 0; i < 32; ++i){
        float xv = x[(size_t)(b*32 + i) * SVT + p];
        #pragma unroll
        for (int o = 0; o < 32; ++o) acc[o] += xv * wsh[o][i];
    }
    #pragma unroll
    for (int o = 0; o < 32; ++o) x[(size_t)(b*32 + o) * SVT + p] = acc[o];
}

// -- inverse v then t via MFMA (split-bf16): Z1 -> xio = gelu(x1 + xio) -----
// block = (bo, s); stage1: D[kz][(v,part)]; stage2: D[v][t] (wave-local A2)
__global__ __launch_bounds__(256) void k_invVT(
    const float2* __restrict__ Z1,
    const unsigned short* __restrict__ T1h, const unsigned short* __restrict__ T1l,
    const unsigned short* __restrict__ T2h, const unsigned short* __restrict__ T2l,
    float* xio)
{
    __shared__ __align__(16) unsigned short A1h[16][72], A1l[16][72];
    __shared__ __align__(16) unsigned short A2h[64][40], A2l[64][40];
    int tid = threadIdx.x;
    int bo = blockIdx.x >> 6;
    int s  = blockIdx.x & 63;
    // zero pads of A1: cols 48-71 all rows; rows 12-15 cols 0-47
    for (int i = tid; i < 384; i += 256){
        int r = i / 24, c = 48 + (i % 24);
        A1h[r][c] = 0; A1l[r][c] = 0;
    }
    for (int i = tid; i < 192; i += 256){
        int r = 12 + i / 48, c = i % 48;
        A1h[r][c] = 0; A1l[r][c] = 0;
    }
    // stage Z1 -> A1[kz][2ky+part] (hi/lo bf16)
    for (int i = tid; i < 288; i += 256){
        int kz = i / 24, ky = i % 24;
        float2 a = Z1[((size_t)(bo*12 + kz) * 64 + s) * 24 + ky];
        unsigned short hx = f2bf(a.x), hy = f2bf(a.y);
        A1h[kz][2*ky  ] = hx; A1l[kz][2*ky  ] = f2bf(a.x - bf2f(hx));
        A1h[kz][2*ky+1] = hy; A1l[kz][2*ky+1] = f2bf(a.y - bf2f(hy));
    }
    __syncthreads();
    int l = tid & 63, w = tid >> 6;
    int lr = l & 15, kg = l >> 4;
    // stage 1: wave w -> cols 32w..32w+31 (v = 16w..16w+15, both parts)
    f32x4 acc1[2];
    acc1[0] = (f32x4){0.f,0.f,0.f,0.f}; acc1[1] = (f32x4){0.f,0.f,0.f,0.f};
    #pragma unroll
    for (int kc = 0; kc < 2; ++kc){
        int ko = kc*32 + kg*8;
        bf16x8 ah = *(const bf16x8*)&A1h[lr][ko];
        bf16x8 al = *(const bf16x8*)&A1l[lr][ko];
        #pragma unroll
        for (int n = 0; n < 2; ++n){
            int col = (2*w + n)*16 + lr;
            bf16x8 bh = *(const bf16x8*)&T1h[col*64 + ko];
            bf16x8 bl = *(const bf16x8*)&T1l[col*64 + ko];
            acc1[n] = __builtin_amdgcn_mfma_f32_16x16x32_bf16(ah, bh, acc1[n], 0, 0, 0);
            acc1[n] = __builtin_amdgcn_mfma_f32_16x16x32_bf16(ah, bl, acc1[n], 0, 0, 0);
            acc1[n] = __builtin_amdgcn_mfma_f32_16x16x32_bf16(al, bh, acc1[n], 0, 0, 0);
        }
    }
    // epilogue (wave-local): A2[v][2kz+part]; rows kz 12-15 write zeros -> pad
    #pragma unroll
    for (int n = 0; n < 2; ++n){
        int col = (2*w + n)*16 + lr;
        int v = col >> 1, part = col & 1;
        #pragma unroll
        for (int r = 0; r < 4; ++r){
            int k2 = 2*(kg*4 + r) + part;
            float val = acc1[n][r];
            unsigned short h = f2bf(val);
            A2h[v][k2] = h;
            A2l[v][k2] = f2bf(val - bf2f(h));
        }
    }
    // no barrier: wave w wrote exactly rows 16w..16w+15 it now reads
    int r0 = w << 4;
    bf16x8 ah2 = *(const bf16x8*)&A2h[r0 + lr][kg*8];
    bf16x8 al2 = *(const bf16x8*)&A2l[r0 + lr][kg*8];
    size_t base = (size_t)bo * SVT + (size_t)s * VT;
    #pragma unroll
    for (int n = 0; n < 4; ++n){
        f32x4 a2c = (f32x4){0.f,0.f,0.f,0.f};
        int colt = n*16 + lr;
        bf16x8 bh = *(const bf16x8*)&T2h[colt*32 + kg*8];
        bf16x8 bl = *(const bf16x8*)&T2l[colt*32 + kg*8];
        a2c = __builtin_amdgcn_mfma_f32_16x16x32_bf16(ah2, bh, a2c, 0, 0, 0);
        a2c = __builtin_amdgcn_mfma_f32_16x16x32_bf16(ah2, bl, a2c, 0, 0, 0);
        a2c = __builtin_amdgcn_mfma_f32_16x16x32_bf16(al2, bh, a2c, 0, 0, 0);
        #pragma unroll
        for (int r = 0; r < 4; ++r){
            int v = r0 + kg*4 + r;
            size_t idx = base + (size_t)v*64 + colt;
            xio[idx] = gelu_f(a2c[r] + xio[idx]);
        }
    }
}

// ------- fused skip MLP v4: lean preamble, VGPR-capped, proj fusion --------
// 256 thr = 4 waves; wave w owns p-tile w (points 16w..16w+15).
template<int LAST>
__global__ __launch_bounds__(256, 8) void k_skip(
    const float* __restrict__ coords,
    const unsigned short* __restrict__ w1dup, const float* __restrict__ pbq,
    const unsigned short* __restrict__ w2bf, const float* __restrict__ s2b,
    const unsigned short* __restrict__ w3bf, const float* __restrict__ s3b,
    int layer, float* __restrict__ xio,
    const float* __restrict__ p1w, const float* __restrict__ p1b,
    const float* __restrict__ p2w, const float* __restrict__ p2b,
    float* __restrict__ out)
{
    __shared__ __align__(16) unsigned short A1[64][136];   // h1/h2 bf16; later overlay
    __shared__ __align__(16) unsigned short zst[4][16][8];

    int tid = threadIdx.x;
    size_t g0 = (size_t)blockIdx.x * 64;
    int b = (int)(g0 >> 18);
    const unsigned short* w2g = w2bf + (size_t)layer * 16384;   // [c][k]
    const unsigned short* w3g = w3bf + (size_t)layer * 4096;    // [c2][k]
    const unsigned short* w1g = w1dup + (size_t)layer * 1024;   // [h][8]
    const float* pbg = pbq + layer*512 + b*128;
    const float* b2g = s2b + layer*128;

    int l  = tid & 63;
    int w  = tid >> 6;
    int lr = l & 15;
    int kg = l >> 4;

    // ---- stage z (hi/lo bf16) for wave's 16 points; wave-local ------------
    if (l < 16){
        size_t g = g0 + (size_t)w*16 + l;
        float z0 = coords[g*3+0], z1 = coords[g*3+1], z2 = coords[g*3+2];
        unsigned short h0 = f2bf(z0), h1 = f2bf(z1), h2 = f2bf(z2);
        bf16x8 pk;
        pk[0] = (short)h0; pk[1] = (short)h1; pk[2] = (short)h2; pk[3] = 0;
        pk[4] = (short)f2bf(z0 - bf2f(h0));
        pk[5] = (short)f2bf(z1 - bf2f(h1));
        pk[6] = (short)f2bf(z2 - bf2f(h2));
        pk[7] = 0;
        *(bf16x8*)&zst[w][l][0] = pk;
    }
    bf16x8 bz;
    if (kg == 0) bz = *(const bf16x8*)&zst[w][lr][0];
    else         bz = (bf16x8){0,0,0,0,0,0,0,0};

    // ---- phase B: h1 = gelu(z@w1 + pb) via MFMA, D[h][p] ------------------
    {
        f32x4 accB[8];
        #pragma unroll
        for (int m = 0; m < 8; ++m) accB[m] = (f32x4){0.f,0.f,0.f,0.f};
        #pragma unroll
        for (int m = 0; m < 8; ++m){
            bf16x8 af = *(const bf16x8*)&w1g[(m*16 + lr)*8];
            accB[m] = __builtin_amdgcn_mfma_f32_16x16x32_bf16(af, bz, accB[m], 0, 0, 0);
        }
        #pragma unroll
        for (int m = 0; m < 8; ++m){
            int c0 = m*16 + kg*4;
            float4 bb = *(const float4*)&pbg[c0];
            us4 pk4;
            pk4[0] = f2bf(gelu_f(accB[m][0] + bb.x));
            pk4[1] = f2bf(gelu_f(accB[m][1] + bb.y));
            pk4[2] = f2bf(gelu_f(accB[m][2] + bb.z));
            pk4[3] = f2bf(gelu_f(accB[m][3] + bb.w));
            *(us4*)&A1[w*16 + lr][c0] = pk4;
        }
    }
    __syncthreads();   // h1 visible to all waves

    // ---- phase C: h2pre = h1 @ w2 (MFMA, swapped -> D[c][p]) --------------
    f32x4 accC[2][4];
    #pragma unroll
    for (int mi = 0; mi < 2; ++mi)
        #pragma unroll
        for (int pt = 0; pt < 4; ++pt) accC[mi][pt] = (f32x4){0.f,0.f,0.f,0.f};
    #pragma unroll
    for (int kc = 0; kc < 4; ++kc){
        int ko = kc*32 + kg*8;
        bf16x8 a0 = *(const bf16x8*)&w2g[((2*w    )*16 + lr)*128 + ko];
        bf16x8 a1 = *(const bf16x8*)&w2g[((2*w + 1)*16 + lr)*128 + ko];
        #pragma unroll
        for (int pt = 0; pt < 4; ++pt){
            bf16x8 bb = *(const bf16x8*)&A1[pt*16 + lr][ko];
            accC[0][pt] = __builtin_amdgcn_mfma_f32_16x16x32_bf16(a0, bb, accC[0][pt], 0, 0, 0);
            accC[1][pt] = __builtin_amdgcn_mfma_f32_16x16x32_bf16(a1, bb, accC[1][pt], 0, 0, 0);
        }
    }
    __syncthreads();   // all h1 reads done -> safe to overwrite A1 with h2
    #pragma unroll
    for (int mi = 0; mi < 2; ++mi)
        #pragma unroll
        for (int pt = 0; pt < 4; ++pt){
            int c0 = (2*w + mi)*16 + kg*4;
            float4 bb = *(const float4*)&b2g[c0];
            us4 pk4;
            pk4[0] = f2bf(gelu_f(accC[mi][pt][0] + bb.x));
            pk4[1] = f2bf(gelu_f(accC[mi][pt][1] + bb.y));
            pk4[2] = f2bf(gelu_f(accC[mi][pt][2] + bb.z));
            pk4[3] = f2bf(gelu_f(accC[mi][pt][3] + bb.w));
            *(us4*)&A1[pt*16 + lr][c0] = pk4;
        }
    __syncthreads();   // h2 visible

    // ---- phase D: out = h2 @ w3 (MFMA, unswapped -> D[p][c2]) -------------
    int nD  = w & 1;
    int pt0 = (w >> 1) * 2;
    float b3v = s3b[layer*32 + nD*16 + lr];
    f32x4 c3[2];
    c3[0] = (f32x4){0.f,0.f,0.f,0.f}; c3[1] = (f32x4){0.f,0.f,0.f,0.f};
    #pragma unroll
    for (int kc = 0; kc < 4; ++kc){
        int ko = kc*32 + kg*8;
        bf16x8 bw3 = *(const bf16x8*)&w3g[(nD*16 + lr)*128 + ko];
        bf16x8 aa0 = *(const bf16x8*)&A1[(pt0    )*16 + lr][ko];
        bf16x8 aa1 = *(const bf16x8*)&A1[(pt0 + 1)*16 + lr][ko];
        c3[0] = __builtin_amdgcn_mfma_f32_16x16x32_bf16(aa0, bw3, c3[0], 0, 0, 0);
        c3[1] = __builtin_amdgcn_mfma_f32_16x16x32_bf16(aa1, bw3, c3[1], 0, 0, 0);
    }
    __syncthreads();   // all h2 reads done -> A1 free for overlay

    float* outsT = (float*)&A1[0][0];    // [32][68] fp32, transposed
    {
        int c2 = nD*16 + lr;
        #pragma unroll
        for (int q = 0; q < 2; ++q){
            int p0 = (pt0 + q)*16 + kg*4;
            float4 v4;
            v4.x = c3[q][0] + b3v; v4.y = c3[q][1] + b3v;
            v4.z = c3[q][2] + b3v; v4.w = c3[q][3] + b3v;
            *(float4*)&outsT[c2*68 + p0] = v4;
        }
    }
    float* hs   = outsT + 2176;   // [64][17]
    float* p1wS = outsT + 3264;   // [512]
    float* smB  = outsT + 3776;   // 16 b1 | 16 p2w | 1 p2b
    if (LAST){
        for (int i = tid; i < 512; i += 256) p1wS[i] = p1w[i];
        if (tid < 16){ smB[tid] = p1b[tid]; smB[16 + tid] = p2w[tid]; }
        if (tid == 32) smB[32] = p2b[0];
    }
    __syncthreads();

    // ---- rmw: xsum = xio + skip ------------------------------------------
    {
        int c  = tid >> 3;        // 0..31
        int pg = tid & 7;         // 8 floats each
        size_t prel = (g0 & (size_t)(SVT - 1)) + (size_t)pg*8;
        float* gp = xio + (((size_t)(b*32 + c)) << 18) + prel;
        float* op = &outsT[c*68 + pg*8];
        #pragma unroll
        for (int i = 0; i < 8; i += 4){
            float4 xv = *(const float4*)&gp[i];
            float4 ov = *(const float4*)&op[i];
            ov.x += xv.x; ov.y += xv.y; ov.z += xv.z; ov.w += xv.w;
            if (LAST) *(float4*)&op[i] = ov;     // keep xsum in LDS
            else      *(float4*)&gp[i] = ov;     // write back to global
        }
    }
    if (LAST){
        __syncthreads();
        {
            int p  = tid & 63;
            int jq = tid >> 6;    // 4 j's each
            float h[4];
            #pragma unroll
            for (int j = 0; j < 4; ++j) h[j] = smB[jq*4 + j];
            for (int c = 0; c < 32; ++c){
                float xv = outsT[c*68 + p];
                #pragma unroll
                for (int j = 0; j < 4; ++j) h[j] += xv * p1wS[c*16 + jq*4 + j];
            }
            #pragma unroll
            for (int j = 0; j < 4; ++j) hs[p*17 + jq*4 + j] = h[j];
        }
        __syncthreads();
        if (tid < 64){
            float acc = smB[32];
            #pragma unroll
            for (int j = 0; j < 16; ++j) acc += gelu_f(hs[tid*17 + j]) * smB[16 + j];
            out[g0 + tid] = acc;
        }
    }
}

extern "C" void kernel_launch(void* const* d_in, const int* in_sizes, int n_in,
                              void* d_out, int out_size, void* d_ws, size_t ws_size,
                              hipStream_t stream)
{
    (void)in_sizes; (void)n_in; (void)out_size; (void)ws_size;
    const float* coords = (const float*)d_in[0];
    const float* params = (const float*)d_in[1];
    const float* lift_w = (const float*)d_in[2];
    const float* lift_b = (const float*)d_in[3];
    const float* sw1    = (const float*)d_in[4];
    const float* sw2    = (const float*)d_in[5];
    const float* sw3    = (const float*)d_in[6];
    const float* sw4    = (const float*)d_in[7];
    const float* conv_w = (const float*)d_in[8];
    const float* conv_b = (const float*)d_in[9];
    const float* s1w    = (const float*)d_in[10];
    const float* s1b    = (const float*)d_in[11];
    const float* s2w    = (const float*)d_in[12];
    const float* s2b    = (const float*)d_in[13];
    const float* s3w    = (const float*)d_in[14];
    const float* s3b    = (const float*)d_in[15];
    const float* p1w    = (const float*)d_in[16];
    const float* p1b    = (const float*)d_in[17];
    const float* p2w    = (const float*)d_in[18];
    const float* p2b    = (const float*)d_in[19];
    float* out = (float*)d_out;

    char* ws = (char*)d_ws;
    float*  xA = (float*)(ws);                                    // 134,217,728
    float2* X2 = (float2*)(ws + 134217728ull);                    //  18,874,368 (also Z1)
    float2* X3 = (float2*)(ws + 153092096ull);                    //   7,077,888
    float2* Yb = (float2*)(ws + 160169984ull);                    //   7,077,888
    unsigned short* w2bf  = (unsigned short*)(ws + 167247872ull); //     131,072
    unsigned short* w3bf  = (unsigned short*)(ws + 167378944ull); //      32,768
    unsigned short* tdft  = (unsigned short*)(ws + 167411712ull); //       8,192
    unsigned short* T1h   = (unsigned short*)(ws + 167419904ull); //      16,384
    unsigned short* T1l   = (unsigned short*)(ws + 167436288ull); //      16,384
    unsigned short* T2h   = (unsigned short*)(ws + 167452672ull); //       4,096
    unsigned short* T2l   = (unsigned short*)(ws + 167456768ull); //       4,096
    float*          pbq   = (float*)(ws + 167460864ull);          //       8,192
    unsigned short* w1dup = (unsigned short*)(ws + 167469056ull); //       8,192
    // total 167,477,248 B

    k_prep<<<392, 256, 0, stream>>>(params, s1w, s1b, s2w, s3w,
                                    w2bf, w3bf, tdft, T1h, T1l, T2h, T2l,
                                    pbq, w1dup);
    k_lift<<<4096, 256, 0, stream>>>(coords, params, lift_w, lift_b, xA);

    for (int l = 0; l < NLAY; ++l){
        k_fwdTV<<<8192, 256, 0, stream>>>(xA, tdft, X2);
        k_fwdS<<<1152, 256, 0, stream>>>(X2, X3);
        dim3 gmm(27, 32);
        k_modemix<<<gmm, 256, 0, stream>>>(X3, sw1, sw2, sw3, sw4, l, Yb);
        k_invS<<<1536, 256, 0, stream>>>(Yb, X2);          // Z1 overlays X2
        k_conv<<<4096, 256, 0, stream>>>(xA, conv_w, conv_b, l);   // in place
        k_invVT<<<8192, 256, 0, stream>>>(X2, T1h, T1l, T2h, T2l, xA);
        if (l < NLAY - 1)
            k_skip<0><<<16384, 256, 0, stream>>>(coords, w1dup, pbq,
                w2bf, s2b, w3bf, s3b, l, xA, p1w, p1b, p2w, p2b, out);
        else
            k_skip<1><<<16384, 256, 0, stream>>>(coords, w1dup, pbq,
                w2bf, s2b, w3bf, s3b, l, xA, p1w, p1b, p2w, p2b, out);
    }
}

// Round 9
// 1581.691 us; speedup vs baseline: 4.0914x; 1.0757x over previous
//
#include <hip/hip_runtime.h>
#include <hip/hip_bf16.h>
#include <math.h>

#define NB   4
#define NC   32
#define SVT  262144      // 64^3
#define VT   4096        // 64*64
#define NLAY 4
#define TWOPI_64 0.09817477042468103f

typedef __attribute__((ext_vector_type(8))) short bf16x8;
typedef __attribute__((ext_vector_type(4))) float f32x4;
typedef __attribute__((ext_vector_type(4))) unsigned short us4;

// tanh-form GELU via hw exp2/rcp; |err| vs exact erf-GELU < ~2.5e-4
__device__ __forceinline__ float gelu_f(float x){
    float x2 = x * x;
    float u  = x * __builtin_fmaf(-0.10294322f, x2, -2.30220795f);
    float e  = __builtin_amdgcn_exp2f(u);
    return x * __builtin_amdgcn_rcpf(1.0f + e);
}

__device__ __forceinline__ unsigned short f2bf(float f){
    union { __hip_bfloat16 h; unsigned short u; } cv;
    cv.h = __float2bfloat16(f);
    return cv.u;
}
__device__ __forceinline__ float bf2f(unsigned short u){
    return __uint_as_float(((unsigned int)u) << 16);
}

// ------------- weight prep: bf16 transposes + twiddle tables + pb ---------
__global__ __launch_bounds__(256) void k_prep(
    const float* __restrict__ params,
    const float* __restrict__ s1w, const float* __restrict__ s1b,
    const float* __restrict__ s2w, const float* __restrict__ s3w,
    const float* __restrict__ conv_w,
    unsigned short* __restrict__ w2bf,   // [4][c 128][k 128]
    unsigned short* __restrict__ w3bf,   // [4][c2 32][k 128]
    unsigned short* __restrict__ tdft,   // [2(hi,lo)][32 o][64 t]
    unsigned short* __restrict__ T1h, unsigned short* __restrict__ T1l, // [128][64]
    unsigned short* __restrict__ T2h, unsigned short* __restrict__ T2l, // [64][32]
    float* __restrict__ pbq,             // [4 l][4 b][128]
    unsigned short* __restrict__ w1dup,  // [4 l][128][8]
    unsigned short* __restrict__ wcvh, unsigned short* __restrict__ wcvl) // [4][32 o][32 i]
{
    int g = blockIdx.x * 256 + threadIdx.x;
    if (g < 65536){
        int l = g >> 14, r = g & 16383;
        int c = r >> 7, k = r & 127;
        w2bf[g] = f2bf(s2w[l*16384 + k*128 + c]);
        return;
    }
    g -= 65536;
    if (g < 16384){
        int l = g >> 12, r = g & 4095;
        int c2 = r >> 7, k = r & 127;
        w3bf[g] = f2bf(s3w[l*4096 + k*32 + c2]);
        return;
    }
    g -= 16384;
    if (g < 2048){
        int o = g >> 6, t = g & 63;
        float val = 0.f;
        if (o < 24){
            int kz = o >> 1;
            float ang = (float)((kz * t) & 63) * TWOPI_64;
            float sn, cs; sincosf(ang, &sn, &cs);
            val = (o & 1) ? -sn : cs;      // forward DFT: e^{-i theta}
        }
        unsigned short h = f2bf(val);
        tdft[g]        = h;
        tdft[2048 + g] = f2bf(val - bf2f(h));
        return;
    }
    g -= 2048;
    if (g < 8192){           // T1: inverse over ky -> v. col=2v+pout, k1=2ky+pin
        int col = g >> 6, k1 = g & 63;
        int v = col >> 1, pout = col & 1;
        float val = 0.f;
        if (k1 < 48){
            int ky = k1 >> 1, pin = k1 & 1;
            int kya = (ky < 12) ? ky : ky + 40;
            float ang = (float)((kya * v) & 63) * TWOPI_64;
            float sn, cs; sincosf(ang, &sn, &cs);
            val = pout == 0 ? (pin == 0 ? cs : -sn) : (pin == 0 ? sn : cs);
        }
        unsigned short h = f2bf(val);
        T1h[g] = h;
        T1l[g] = f2bf(val - bf2f(h));
        return;
    }
    g -= 8192;
    if (g < 2048){           // T2: real inverse over kz -> t (norm + x2 folded)
        int t = g >> 5, k2 = g & 31;
        float val = 0.f;
        if (k2 < 24){
            int kz = k2 >> 1, part = k2 & 1;
            float wk = (kz == 0) ? 1.f : 2.f;
            float ang = (float)((kz * t) & 63) * TWOPI_64;
            float sn, cs; sincosf(ang, &sn, &cs);
            val = (part ? -sn : cs) * wk * (1.f / 262144.f);
        }
        unsigned short h = f2bf(val);
        T2h[g] = h;
        T2l[g] = f2bf(val - bf2f(h));
        return;
    }
    g -= 2048;
    if (g < 2048){           // pbq[l][b][h]
        int l = g >> 9, b = (g >> 7) & 3, h = g & 127;
        float acc = s1b[l*128 + h];
        #pragma unroll
        for (int j = 0; j < 6; ++j)
            acc += params[b*6 + j] * bf2f(f2bf(s1w[l*1152 + (3 + j)*128 + h]));
        pbq[g] = acc;
        return;
    }
    g -= 2048;
    if (g < 4096){           // w1dup[l][h][slot]: rows 0-2 dup in 0-2 & 4-6
        int l = g >> 10, rem = g & 1023;
        int h = rem >> 3, slot = rem & 7;
        float val = 0.f;
        if (slot != 3 && slot != 7){
            int row = (slot < 3) ? slot : slot - 4;
            val = bf2f(f2bf(s1w[l*1152 + row*128 + h]));
        }
        w1dup[g] = f2bf(val);
        return;
    }
    g -= 4096;
    if (g < 4096){           // conv weights hi/lo, [l][o][i]
        float val = conv_w[g];
        unsigned short h = f2bf(val);
        wcvh[g] = h;
        wcvl[g] = f2bf(val - bf2f(h));
    }
}

// ---------------- lift: x = z @ lift_w + lift_b, layout [B,C,S,V,T] -------
__global__ __launch_bounds__(256) void k_lift(
    const float* __restrict__ coords, const float* __restrict__ params,
    const float* __restrict__ lw, const float* __restrict__ lb,
    float* __restrict__ x)
{
    size_t g = (size_t)blockIdx.x * 256 + threadIdx.x;   // 0..1048575
    int b = (int)(g >> 18);
    size_t p = g & (size_t)(SVT - 1);
    float z[9];
    z[0] = coords[g*3+0]; z[1] = coords[g*3+1]; z[2] = coords[g*3+2];
    #pragma unroll
    for (int j = 0; j < 6; ++j) z[3+j] = params[b*6+j];
    #pragma unroll
    for (int c = 0; c < 32; ++c){
        float acc = lb[c];
        #pragma unroll
        for (int j = 0; j < 9; ++j) acc += z[j] * lw[j*32 + c];
        x[(size_t)(b*32 + c) * SVT + p] = acc;
    }
}

// ------- fused forward DFT t (MFMA split-bf16) then v: x -> X2[bc][kz][ky][s]
__global__ __launch_bounds__(256) void k_fwdTV(
    const float* __restrict__ x, const unsigned short* __restrict__ tdft,
    float2* __restrict__ X2)
{
    __shared__ __align__(16) unsigned short Ahi[64][72], Alo[64][72];
    __shared__ __align__(16) unsigned short Bhi[32][72], Blo[32][72];
    __shared__ float2 a2[12][66];
    __shared__ float2 wtab[64];
    int tid = threadIdx.x;
    int bc = blockIdx.x >> 6;
    int s  = blockIdx.x & 63;
    if (tid < 64){
        float sn, cs;
        sincosf((float)tid * TWOPI_64, &sn, &cs);
        wtab[tid] = make_float2(cs, sn);
    }
    for (int i = tid; i < 2048; i += 256){
        int o = i >> 6, t = i & 63;
        Bhi[o][t] = tdft[i];
        Blo[o][t] = tdft[2048 + i];
    }
    // stage x -> hi/lo bf16
    {
        int row = tid >> 2, c0 = (tid & 3) << 4;
        const float* src = x + (size_t)bc * SVT + (size_t)s * VT + row*64 + c0;
        #pragma unroll
        for (int q = 0; q < 4; ++q){
            float4 v4 = *(const float4*)&src[q*4];
            float vv[4] = {v4.x, v4.y, v4.z, v4.w};
            #pragma unroll
            for (int e = 0; e < 4; ++e){
                unsigned short h = f2bf(vv[e]);
                Ahi[row][c0 + q*4 + e] = h;
                Alo[row][c0 + q*4 + e] = f2bf(vv[e] - bf2f(h));
            }
        }
    }
    __syncthreads();
    // stage 1: wave w computes v-rows 16w..16w+15, 24 outputs (kz x re/im)
    int l = tid & 63, w = tid >> 6;
    int lr = l & 15, kg = l >> 4;
    int r0 = w << 4;
    f32x4 acc[2];
    acc[0] = (f32x4){0.f,0.f,0.f,0.f}; acc[1] = (f32x4){0.f,0.f,0.f,0.f};
    #pragma unroll
    for (int kc = 0; kc < 2; ++kc){
        int ko = kc*32 + kg*8;
        bf16x8 ah = *(const bf16x8*)&Ahi[r0 + lr][ko];
        bf16x8 al = *(const bf16x8*)&Alo[r0 + lr][ko];
        #pragma unroll
        for (int n = 0; n < 2; ++n){
            bf16x8 bh = *(const bf16x8*)&Bhi[n*16 + lr][ko];
            bf16x8 bl = *(const bf16x8*)&Blo[n*16 + lr][ko];
            acc[n] = __builtin_amdgcn_mfma_f32_16x16x32_bf16(ah, bh, acc[n], 0, 0, 0);
            acc[n] = __builtin_amdgcn_mfma_f32_16x16x32_bf16(ah, bl, acc[n], 0, 0, 0);
            acc[n] = __builtin_amdgcn_mfma_f32_16x16x32_bf16(al, bh, acc[n], 0, 0, 0);
        }
    }
    #pragma unroll
    for (int n = 0; n < 2; ++n){
        int o = n*16 + lr;
        if (o < 24){
            int kz = o >> 1;
            #pragma unroll
            for (int r = 0; r < 4; ++r){
                int v = r0 + kg*4 + r;
                if (o & 1) a2[kz][v].y = acc[n][r];
                else       a2[kz][v].x = acc[n][r];
            }
        }
    }
    __syncthreads();
    // stage 2: DFT over v -> X2[bc][kz][ky][s]
    for (int task = tid; task < 288; task += 256){
        int kz = task % 12;
        int ky = task / 12;
        int kya = (ky < 12) ? ky : ky + 40;
        float re = 0.f, im = 0.f;
        for (int v = 0; v < 64; ++v){
            float2 wv = wtab[(kya * v) & 63];
            float2 a  = a2[kz][v];
            re += a.x * wv.x + a.y * wv.y;
            im += a.y * wv.x - a.x * wv.y;
        }
        X2[((size_t)(bc*12 + kz) * 24 + ky) * 64 + s] = make_float2(re, im);
    }
}

// ---------------- forward DFT over s: X2[bc][kz][ky][s] -> X3[bc][kx][ky][kz]
__global__ __launch_bounds__(256) void k_fwdS(
    const float2* __restrict__ X2, float2* __restrict__ X3)
{
    __shared__ float2 cin[32][65];
    __shared__ float2 wtab[64];
    int tid = threadIdx.x;
    if (tid < 64){
        float sn, cs; sincosf((float)tid * TWOPI_64, &sn, &cs);
        wtab[tid] = make_float2(cs, sn);
    }
    int rbase = blockIdx.x * 32;   // rows (bc,kz,ky), 36864 total
    for (int i = tid; i < 2048; i += 256){
        int row = i >> 6, s = i & 63;
        cin[row][s] = X2[(size_t)(rbase + row) * 64 + s];
    }
    __syncthreads();
    int row = tid & 31;
    int r = rbase + row;
    int kxg = tid >> 5;       // 0..7 -> 3 kx each
    int kxs[3];
    #pragma unroll
    for (int j = 0; j < 3; ++j){ int kxi = kxg*3 + j; kxs[j] = (kxi < 12) ? kxi : kxi + 40; }
    float re[3] = {0,0,0}, im[3] = {0,0,0};
    for (int s = 0; s < 64; ++s){
        float2 cv = cin[row][s];
        #pragma unroll
        for (int j = 0; j < 3; ++j){
            float2 wv = wtab[(kxs[j] * s) & 63];
            re[j] += cv.x * wv.x + cv.y * wv.y;
            im[j] += cv.y * wv.x - cv.x * wv.y;
        }
    }
    int bc = r / 288; int kz = (r / 24) % 12; int ky = r % 24;
    #pragma unroll
    for (int j = 0; j < 3; ++j){
        int kxi = kxg*3 + j;
        X3[(size_t)bc * 6912 + (size_t)kxi * 288 + ky * 12 + kz] = make_float2(re[j], im[j]);
    }
}

// --------- per-mode channel mixing: coalesced W, X3 in regs, 4 o per block -
__global__ __launch_bounds__(256) void k_modemix(
    const float2* __restrict__ X3,
    const float* __restrict__ w1, const float* __restrict__ w2,
    const float* __restrict__ w3, const float* __restrict__ w4,
    int layer, float2* __restrict__ Y)
{
    __shared__ float2 wlds[32][64];   // [i][m], 16 KB
    int tid = threadIdx.x;
    int m   = tid & 63;
    int b   = tid >> 6;
    int corner = blockIdx.y >> 3;
    int o0     = (blockIdx.y & 7) * 4;
    int moff0  = blockIdx.x * 64;
    const float* wsrc = (corner==0 ? w1 : corner==1 ? w2 : corner==2 ? w3 : w4)
                        + (size_t)layer * 3538944;   // 32*32*1728*2
    int moff = moff0 + m;
    int m1  = moff / 144;
    int rem = moff - m1 * 144;
    int kx  = m1 + ((corner == 1 || corner == 3) ? 12 : 0);
    int mode_g = kx * 288 + rem + ((corner >= 2) ? 144 : 0);

    float xr[32], xi[32];
    const float2* xp = X3 + (size_t)b * 32 * 6912 + mode_g;
    #pragma unroll
    for (int i = 0; i < 32; ++i){
        float2 a = xp[(size_t)i * 6912];
        xr[i] = a.x; xi[i] = a.y;
    }
    for (int oo = 0; oo < 4; ++oo){
        int o = o0 + oo;
        __syncthreads();
        for (int j = tid; j < 2048; j += 256){
            int i = j >> 6, mm = j & 63;
            wlds[i][mm] = *(const float2*)&wsrc[((size_t)(i*32 + o) * 1728 + moff0 + mm) * 2];
        }
        __syncthreads();
        float re = 0.f, im = 0.f;
        #pragma unroll
        for (int i = 0; i < 32; ++i){
            float2 wv = wlds[i][m];
            re += xr[i]*wv.x - xi[i]*wv.y;
            im += xr[i]*wv.y + xi[i]*wv.x;
        }
        Y[(size_t)(b*32 + o) * 6912 + mode_g] = make_float2(re, im);
    }
}

// ---------------- inverse over s: Y[bo][kx][ky][kz] -> Z1[bo][kz][s][ky] ---
__global__ __launch_bounds__(256) void k_invS(
    const float2* __restrict__ Y, float2* __restrict__ Z1)
{
    __shared__ float2 yin[24][24];
    __shared__ float2 wtab[64];
    int tid = threadIdx.x;
    if (tid < 64){
        float sn, cs; sincosf((float)tid * TWOPI_64, &sn, &cs);
        wtab[tid] = make_float2(cs, sn);
    }
    int bo = blockIdx.x / 12;
    int kz = blockIdx.x % 12;
    for (int i = tid; i < 576; i += 256){
        int kx = i / 24, ky = i % 24;
        yin[kx][ky] = Y[(size_t)bo * 6912 + (size_t)kx * 288 + ky * 12 + kz];
    }
    __syncthreads();
    int s = tid & 63;
    int kyg = tid >> 6;   // 0..3 -> 6 ky each
    float re[6] = {0,0,0,0,0,0}, im[6] = {0,0,0,0,0,0};
    for (int kxi = 0; kxi < 24; ++kxi){
        int kxa = (kxi < 12) ? kxi : kxi + 40;
        float2 wv = wtab[(kxa * s) & 63];     // e^{+i theta}
        #pragma unroll
        for (int j = 0; j < 6; ++j){
            float2 a = yin[kxi][kyg*6 + j];
            re[j] += a.x * wv.x - a.y * wv.y;
            im[j] += a.x * wv.y + a.y * wv.x;
        }
    }
    #pragma unroll
    for (int j = 0; j < 6; ++j){
        int ky = kyg*6 + j;
        Z1[((size_t)(bo*12 + kz) * 64 + s) * 24 + ky] = make_float2(re[j], im[j]);
    }
}

// -- fused conv + inverse-v + inverse-t:  xA <- gelu(x1 + W*xA + cb) --------
// block = (b, s, vg); 256 pts (4 v x 64 t), all 32 channels; in-place safe.
__global__ __launch_bounds__(256) void k_cinvVT(
    const float* __restrict__ xin, const float2* __restrict__ Z1,
    const unsigned short* __restrict__ T2h, const unsigned short* __restrict__ T2l,
    const unsigned short* __restrict__ wcvh, const unsigned short* __restrict__ wcvl,
    const float* __restrict__ cb, int layer, float* __restrict__ xout)
{
    __shared__ __align__(16) unsigned short XT[2][256][40];  // [hi/lo][pt][i]; later x2s
    __shared__ __align__(16) unsigned short A2h[128][40], A2l[128][40];
    __shared__ float2 wtab[64];
    int tid = threadIdx.x;
    int vg = blockIdx.x & 15;
    int s  = (blockIdx.x >> 4) & 63;
    int b  = blockIdx.x >> 10;
    if (tid < 64){
        float sn, cs; sincosf((float)tid * TWOPI_64, &sn, &cs);
        wtab[tid] = make_float2(cs, sn);
    }
    {   // zero A2 pad cols 24..31
        int row = tid >> 1, half = tid & 1;
        us4 z = (us4){0,0,0,0};
        *(us4*)&A2h[row][24 + half*4] = z;
        *(us4*)&A2l[row][24 + half*4] = z;
    }
    // ---- phase 0: stage XT[pt][i] hi/lo (thread = pt, coalesced reads) ----
    {
        const float* xp = xin + (size_t)b*32*SVT + (size_t)s*VT + (size_t)vg*256 + tid;
        #pragma unroll
        for (int q = 0; q < 4; ++q){
            bf16x8 ph, pl;
            #pragma unroll
            for (int e = 0; e < 8; ++e){
                float v = xp[(size_t)(q*8 + e) * SVT];
                unsigned short h = f2bf(v);
                ph[e] = (short)h;
                pl[e] = (short)f2bf(v - bf2f(h));
            }
            *(bf16x8*)&XT[0][tid][q*8] = ph;
            *(bf16x8*)&XT[1][tid][q*8] = pl;
        }
    }
    __syncthreads();
    // ---- phase 1: inverse DFT over ky (fp32 VALU) -> A2 hi/lo -------------
    #pragma unroll
    for (int j = 0; j < 6; ++j){
        int task = tid + j*256;          // 1536 = 32o x 12kz x 4v
        int o = task / 48, rem = task % 48;
        int kz = rem >> 2, vloc = rem & 3;
        int v = vg*4 + vloc;
        const float2* zp = Z1 + ((size_t)((b*32 + o)*12 + kz) * 64 + s) * 24;
        float re = 0.f, im = 0.f;
        #pragma unroll
        for (int ky = 0; ky < 24; ++ky){
            int kya = (ky < 12) ? ky : ky + 40;
            float2 wv = wtab[(kya * v) & 63];
            float2 a = zp[ky];
            re += a.x * wv.x - a.y * wv.y;
            im += a.x * wv.y + a.y * wv.x;
        }
        int row = o*4 + vloc;
        unsigned short hr = f2bf(re), hm = f2bf(im);
        A2h[row][2*kz  ] = hr; A2l[row][2*kz  ] = f2bf(re - bf2f(hr));
        A2h[row][2*kz+1] = hm; A2l[row][2*kz+1] = f2bf(im - bf2f(hm));
    }
    __syncthreads();
    int l = tid & 63, w = tid >> 6, lr = l & 15, kg = l >> 4;
    // ---- phase 2: conv MFMA (split-bf16, 3 terms) -------------------------
    f32x4 dcv[2][4];
    #pragma unroll
    for (int ot = 0; ot < 2; ++ot){
        bf16x8 ah = *(const bf16x8*)&wcvh[layer*1024 + (ot*16 + lr)*32 + kg*8];
        bf16x8 al = *(const bf16x8*)&wcvl[layer*1024 + (ot*16 + lr)*32 + kg*8];
        #pragma unroll
        for (int ptt = 0; ptt < 4; ++ptt){
            bf16x8 bh = *(const bf16x8*)&XT[0][w*64 + ptt*16 + lr][kg*8];
            bf16x8 bl = *(const bf16x8*)&XT[1][w*64 + ptt*16 + lr][kg*8];
            f32x4 d = (f32x4){0.f,0.f,0.f,0.f};
            d = __builtin_amdgcn_mfma_f32_16x16x32_bf16(ah, bh, d, 0, 0, 0);
            d = __builtin_amdgcn_mfma_f32_16x16x32_bf16(ah, bl, d, 0, 0, 0);
            d = __builtin_amdgcn_mfma_f32_16x16x32_bf16(al, bh, d, 0, 0, 0);
            dcv[ot][ptt] = d;
        }
    }
    __syncthreads();   // all XT reads done -> overlay x2s
    float* x2s = (float*)&XT[0][0][0];   // [32][266] fp32
    #pragma unroll
    for (int ot = 0; ot < 2; ++ot)
        #pragma unroll
        for (int ptt = 0; ptt < 4; ++ptt)
            #pragma unroll
            for (int r = 0; r < 4; ++r)
                x2s[(ot*16 + kg*4 + r)*266 + w*64 + ptt*16 + lr] = dcv[ot][ptt][r];
    // ---- phase 3: inverse-t MFMA ------------------------------------------
    f32x4 dt[2][4];
    #pragma unroll
    for (int rt = 0; rt < 2; ++rt){
        bf16x8 ah = *(const bf16x8*)&A2h[w*32 + rt*16 + lr][kg*8];
        bf16x8 al = *(const bf16x8*)&A2l[w*32 + rt*16 + lr][kg*8];
        #pragma unroll
        for (int n = 0; n < 4; ++n){
            bf16x8 bh = *(const bf16x8*)&T2h[(n*16 + lr)*32 + kg*8];
            bf16x8 bl = *(const bf16x8*)&T2l[(n*16 + lr)*32 + kg*8];
            f32x4 d = (f32x4){0.f,0.f,0.f,0.f};
            d = __builtin_amdgcn_mfma_f32_16x16x32_bf16(ah, bh, d, 0, 0, 0);
            d = __builtin_amdgcn_mfma_f32_16x16x32_bf16(ah, bl, d, 0, 0, 0);
            d = __builtin_amdgcn_mfma_f32_16x16x32_bf16(al, bh, d, 0, 0, 0);
            dt[rt][n] = d;
        }
    }
    __syncthreads();   // x2s visible
    // ---- phase 4: epilogue gelu(x1 + x2 + cb) -> xout ---------------------
    size_t outb = (size_t)b*32*SVT + (size_t)s*VT + (size_t)vg*256;
    #pragma unroll
    for (int rt = 0; rt < 2; ++rt){
        int o = 8*w + rt*4 + kg;
        float cbv = cb[layer*32 + o];
        #pragma unroll
        for (int n = 0; n < 4; ++n){
            #pragma unroll
            for (int r = 0; r < 4; ++r){
                int pt = r*64 + n*16 + lr;
                float val = dt[rt][n][r] + x2s[o*266 + pt] + cbv;
                xout[outb + (size_t)o*SVT + pt] = gelu_f(val);
            }
        }
    }
}

// ------- fused skip MLP v4: lean preamble, VGPR-capped, proj fusion --------
// 256 thr = 4 waves; wave w owns p-tile w (points 16w..16w+15).
template<int LAST>
__global__ __launch_bounds__(256, 8) void k_skip(
    const float* __restrict__ coords,
    const unsigned short* __restrict__ w1dup, const float* __restrict__ pbq,
    const unsigned short* __restrict__ w2bf, const float* __restrict__ s2b,
    const unsigned short* __restrict__ w3bf, const float* __restrict__ s3b,
    int layer, float* __restrict__ xio,
    const float* __restrict__ p1w, const float* __restrict__ p1b,
    const float* __restrict__ p2w, const float* __restrict__ p2b,
    float* __restrict__ out)
{
    __shared__ __align__(16) unsigned short A1[64][136];   // h1/h2 bf16; later overlay
    __shared__ __align__(16) unsigned short zst[4][16][8];

    int tid = threadIdx.x;
    size_t g0 = (size_t)blockIdx.x * 64;
    int b = (int)(g0 >> 18);
    const unsigned short* w2g = w2bf + (size_t)layer * 16384;   // [c][k]
    const unsigned short* w3g = w3bf + (size_t)layer * 4096;    // [c2][k]
    const unsigned short* w1g = w1dup + (size_t)layer * 1024;   // [h][8]
    const float* pbg = pbq + layer*512 + b*128;
    const float* b2g = s2b + layer*128;

    int l  = tid & 63;
    int w  = tid >> 6;
    int lr = l & 15;
    int kg = l >> 4;

    // ---- stage z (hi/lo bf16) for wave's 16 points; wave-local ------------
    if (l < 16){
        size_t g = g0 + (size_t)w*16 + l;
        float z0 = coords[g*3+0], z1 = coords[g*3+1], z2 = coords[g*3+2];
        unsigned short h0 = f2bf(z0), h1 = f2bf(z1), h2 = f2bf(z2);
        bf16x8 pk;
        pk[0] = (short)h0; pk[1] = (short)h1; pk[2] = (short)h2; pk[3] = 0;
        pk[4] = (short)f2bf(z0 - bf2f(h0));
        pk[5] = (short)f2bf(z1 - bf2f(h1));
        pk[6] = (short)f2bf(z2 - bf2f(h2));
        pk[7] = 0;
        *(bf16x8*)&zst[w][l][0] = pk;
    }
    bf16x8 bz;
    if (kg == 0) bz = *(const bf16x8*)&zst[w][lr][0];
    else         bz = (bf16x8){0,0,0,0,0,0,0,0};

    // ---- phase B: h1 = gelu(z@w1 + pb) via MFMA, D[h][p] ------------------
    {
        f32x4 accB[8];
        #pragma unroll
        for (int m = 0; m < 8; ++m) accB[m] = (f32x4){0.f,0.f,0.f,0.f};
        #pragma unroll
        for (int m = 0; m < 8; ++m){
            bf16x8 af = *(const bf16x8*)&w1g[(m*16 + lr)*8];
            accB[m] = __builtin_amdgcn_mfma_f32_16x16x32_bf16(af, bz, accB[m], 0, 0, 0);
        }
        #pragma unroll
        for (int m = 0; m < 8; ++m){
            int c0 = m*16 + kg*4;
            float4 bb = *(const float4*)&pbg[c0];
            us4 pk4;
            pk4[0] = f2bf(gelu_f(accB[m][0] + bb.x));
            pk4[1] = f2bf(gelu_f(accB[m][1] + bb.y));
            pk4[2] = f2bf(gelu_f(accB[m][2] + bb.z));
            pk4[3] = f2bf(gelu_f(accB[m][3] + bb.w));
            *(us4*)&A1[w*16 + lr][c0] = pk4;
        }
    }
    __syncthreads();   // h1 visible to all waves

    // ---- phase C: h2pre = h1 @ w2 (MFMA, swapped -> D[c][p]) --------------
    f32x4 accC[2][4];
    #pragma unroll
    for (int mi = 0; mi < 2; ++mi)
        #pragma unroll
        for (int pt = 0; pt < 4; ++pt) accC[mi][pt] = (f32x4){0.f,0.f,0.f,0.f};
    #pragma unroll
    for (int kc = 0; kc < 4; ++kc){
        int ko = kc*32 + kg*8;
        bf16x8 a0 = *(const bf16x8*)&w2g[((2*w    )*16 + lr)*128 + ko];
        bf16x8 a1 = *(const bf16x8*)&w2g[((2*w + 1)*16 + lr)*128 + ko];
        #pragma unroll
        for (int pt = 0; pt < 4; ++pt){
            bf16x8 bb = *(const bf16x8*)&A1[pt*16 + lr][ko];
            accC[0][pt] = __builtin_amdgcn_mfma_f32_16x16x32_bf16(a0, bb, accC[0][pt], 0, 0, 0);
            accC[1][pt] = __builtin_amdgcn_mfma_f32_16x16x32_bf16(a1, bb, accC[1][pt], 0, 0, 0);
        }
    }
    __syncthreads();   // all h1 reads done -> safe to overwrite A1 with h2
    #pragma unroll
    for (int mi = 0; mi < 2; ++mi)
        #pragma unroll
        for (int pt = 0; pt < 4; ++pt){
            int c0 = (2*w + mi)*16 + kg*4;
            float4 bb = *(const float4*)&b2g[c0];
            us4 pk4;
            pk4[0] = f2bf(gelu_f(accC[mi][pt][0] + bb.x));
            pk4[1] = f2bf(gelu_f(accC[mi][pt][1] + bb.y));
            pk4[2] = f2bf(gelu_f(accC[mi][pt][2] + bb.z));
            pk4[3] = f2bf(gelu_f(accC[mi][pt][3] + bb.w));
            *(us4*)&A1[pt*16 + lr][c0] = pk4;
        }
    __syncthreads();   // h2 visible

    // ---- phase D: out = h2 @ w3 (MFMA, unswapped -> D[p][c2]) -------------
    int nD  = w & 1;
    int pt0 = (w >> 1) * 2;
    float b3v = s3b[layer*32 + nD*16 + lr];
    f32x4 c3[2];
    c3[0] = (f32x4){0.f,0.f,0.f,0.f}; c3[1] = (f32x4){0.f,0.f,0.f,0.f};
    #pragma unroll
    for (int kc = 0; kc < 4; ++kc){
        int ko = kc*32 + kg*8;
        bf16x8 bw3 = *(const bf16x8*)&w3g[(nD*16 + lr)*128 + ko];
        bf16x8 aa0 = *(const bf16x8*)&A1[(pt0    )*16 + lr][ko];
        bf16x8 aa1 = *(const bf16x8*)&A1[(pt0 + 1)*16 + lr][ko];
        c3[0] = __builtin_amdgcn_mfma_f32_16x16x32_bf16(aa0, bw3, c3[0], 0, 0, 0);
        c3[1] = __builtin_amdgcn_mfma_f32_16x16x32_bf16(aa1, bw3, c3[1], 0, 0, 0);
    }
    __syncthreads();   // all h2 reads done -> A1 free for overlay

    float* outsT = (float*)&A1[0][0];    // [32][68] fp32, transposed
    {
        int c2 = nD*16 + lr;
        #pragma unroll
        for (int q = 0; q < 2; ++q){
            int p0 = (pt0 + q)*16 + kg*4;
            float4 v4;
            v4.x = c3[q][0] + b3v; v4.y = c3[q][1] + b3v;
            v4.z = c3[q][2] + b3v; v4.w = c3[q][3] + b3v;
            *(float4*)&outsT[c2*68 + p0] = v4;
        }
    }
    float* hs   = outsT + 2176;   // [64][17]
    float* p1wS = outsT + 3264;   // [512]
    float* smB  = outsT + 3776;   // 16 b1 | 16 p2w | 1 p2b
    if (LAST){
        for (int i = tid; i < 512; i += 256) p1wS[i] = p1w[i];
        if (tid < 16){ smB[tid] = p1b[tid]; smB[16 + tid] = p2w[tid]; }
        if (tid == 32) smB[32] = p2b[0];
    }
    __syncthreads();

    // ---- rmw: xsum = xio + skip ------------------------------------------
    {
        int c  = tid >> 3;        // 0..31
        int pg = tid & 7;         // 8 floats each
        size_t prel = (g0 & (size_t)(SVT - 1)) + (size_t)pg*8;
        float* gp = xio + (((size_t)(b*32 + c)) << 18) + prel;
        float* op = &outsT[c*68 + pg*8];
        #pragma unroll
        for (int i = 0; i < 8; i += 4){
            float4 xv = *(const float4*)&gp[i];
            float4 ov = *(const float4*)&op[i];
            ov.x += xv.x; ov.y += xv.y; ov.z += xv.z; ov.w += xv.w;
            if (LAST) *(float4*)&op[i] = ov;     // keep xsum in LDS
            else      *(float4*)&gp[i] = ov;     // write back to global
        }
    }
    if (LAST){
        __syncthreads();
        {
            int p  = tid & 63;
            int jq = tid >> 6;    // 4 j's each
            float h[4];
            #pragma unroll
            for (int j = 0; j < 4; ++j) h[j] = smB[jq*4 + j];
            for (int c = 0; c < 32; ++c){
                float xv = outsT[c*68 + p];
                #pragma unroll
                for (int j = 0; j < 4; ++j) h[j] += xv * p1wS[c*16 + jq*4 + j];
            }
            #pragma unroll
            for (int j = 0; j < 4; ++j) hs[p*17 + jq*4 + j] = h[j];
        }
        __syncthreads();
        if (tid < 64){
            float acc = smB[32];
            #pragma unroll
            for (int j = 0; j < 16; ++j) acc += gelu_f(hs[tid*17 + j]) * smB[16 + j];
            out[g0 + tid] = acc;
        }
    }
}

extern "C" void kernel_launch(void* const* d_in, const int* in_sizes, int n_in,
                              void* d_out, int out_size, void* d_ws, size_t ws_size,
                              hipStream_t stream)
{
    (void)in_sizes; (void)n_in; (void)out_size; (void)ws_size;
    const float* coords = (const float*)d_in[0];
    const float* params = (const float*)d_in[1];
    const float* lift_w = (const float*)d_in[2];
    const float* lift_b = (const float*)d_in[3];
    const float* sw1    = (const float*)d_in[4];
    const float* sw2    = (const float*)d_in[5];
    const float* sw3    = (const float*)d_in[6];
    const float* sw4    = (const float*)d_in[7];
    const float* conv_w = (const float*)d_in[8];
    const float* conv_b = (const float*)d_in[9];
    const float* s1w    = (const float*)d_in[10];
    const float* s1b    = (const float*)d_in[11];
    const float* s2w    = (const float*)d_in[12];
    const float* s2b    = (const float*)d_in[13];
    const float* s3w    = (const float*)d_in[14];
    const float* s3b    = (const float*)d_in[15];
    const float* p1w    = (const float*)d_in[16];
    const float* p1b    = (const float*)d_in[17];
    const float* p2w    = (const float*)d_in[18];
    const float* p2b    = (const float*)d_in[19];
    float* out = (float*)d_out;

    char* ws = (char*)d_ws;
    float*  xA = (float*)(ws);                                    // 134,217,728
    float2* X2 = (float2*)(ws + 134217728ull);                    //  18,874,368 (also Z1)
    float2* X3 = (float2*)(ws + 153092096ull);                    //   7,077,888
    float2* Yb = (float2*)(ws + 160169984ull);                    //   7,077,888
    unsigned short* w2bf  = (unsigned short*)(ws + 167247872ull); //     131,072
    unsigned short* w3bf  = (unsigned short*)(ws + 167378944ull); //      32,768
    unsigned short* tdft  = (unsigned short*)(ws + 167411712ull); //       8,192
    unsigned short* T1h   = (unsigned short*)(ws + 167419904ull); //      16,384
    unsigned short* T1l   = (unsigned short*)(ws + 167436288ull); //      16,384
    unsigned short* T2h   = (unsigned short*)(ws + 167452672ull); //       4,096
    unsigned short* T2l   = (unsigned short*)(ws + 167456768ull); //       4,096
    float*          pbq   = (float*)(ws + 167460864ull);          //       8,192
    unsigned short* w1dup = (unsigned short*)(ws + 167469056ull); //       8,192
    unsigned short* wcvh  = (unsigned short*)(ws + 167477248ull); //       8,192
    unsigned short* wcvl  = (unsigned short*)(ws + 167485440ull); //       8,192
    // total 167,493,632 B

    k_prep<<<408, 256, 0, stream>>>(params, s1w, s1b, s2w, s3w, conv_w,
                                    w2bf, w3bf, tdft, T1h, T1l, T2h, T2l,
                                    pbq, w1dup, wcvh, wcvl);
    k_lift<<<4096, 256, 0, stream>>>(coords, params, lift_w, lift_b, xA);

    for (int l = 0; l < NLAY; ++l){
        k_fwdTV<<<8192, 256, 0, stream>>>(xA, tdft, X2);
        k_fwdS<<<1152, 256, 0, stream>>>(X2, X3);
        dim3 gmm(27, 32);
        k_modemix<<<gmm, 256, 0, stream>>>(X3, sw1, sw2, sw3, sw4, l, Yb);
        k_invS<<<1536, 256, 0, stream>>>(Yb, X2);          // Z1 overlays X2
        k_cinvVT<<<4096, 256, 0, stream>>>(xA, X2, T2h, T2l, wcvh, wcvl,
                                           conv_b, l, xA);
        if (l < NLAY - 1)
            k_skip<0><<<16384, 256, 0, stream>>>(coords, w1dup, pbq,
                w2bf, s2b, w3bf, s3b, l, xA, p1w, p1b, p2w, p2b, out);
        else
            k_skip<1><<<16384, 256, 0, stream>>>(coords, w1dup, pbq,
                w2bf, s2b, w3bf, s3b, l, xA, p1w, p1b, p2w, p2b, out);
    }
}